// Round 17
// baseline (1343.497 us; speedup 1.0000x reference)
//
#include <hip/hip_runtime.h>
#include <math.h>

#define N_TOK 3136
#define CD    256
#define NHD   8
#define DH    32
#define DFFD  1024
#define SCALE 0.17677669529663687f  /* 32^-0.5 */
#define LOG2E 1.4426950408889634f
#define QSC   (SCALE * LOG2E)

typedef __attribute__((ext_vector_type(8))) short short8v;
typedef __attribute__((ext_vector_type(4))) float f32x4;

// ---------------------------------------------------------------- utils
__device__ __forceinline__ unsigned long long sx64(unsigned long long v, int m) {
  unsigned lo = (unsigned)__shfl_xor((int)(unsigned)(v & 0xffffffffull), m, 64);
  unsigned hi = (unsigned)__shfl_xor((int)(unsigned)(v >> 32), m, 64);
  return ((unsigned long long)hi << 32) | lo;
}

__device__ __forceinline__ unsigned f2mono(float v) {
  unsigned b = __float_as_uint(v);
  return (b & 0x80000000u) ? ~b : (b | 0x80000000u);
}

// fp32 -> bf16 round-to-nearest-even
__device__ __forceinline__ short bfr(float f) {
  unsigned u = __float_as_uint(f);
  unsigned r = (u + 0x7fffu + ((u >> 16) & 1u)) >> 16;
  return (short)r;
}

__device__ __forceinline__ short8v cvt8(float4 a, float4 b) {
  short8v r;
  r[0] = bfr(a.x); r[1] = bfr(a.y); r[2] = bfr(a.z); r[3] = bfr(a.w);
  r[4] = bfr(b.x); r[5] = bfr(b.y); r[6] = bfr(b.z); r[7] = bfr(b.w);
  return r;
}

// ------------------------------------------------- transpose (32x32 tiles)
__global__ __launch_bounds__(256) void transpose_k(const float* __restrict__ in,
    float* __restrict__ out, int R, int C) {
  __shared__ float ls[32][33];
  const int c0 = blockIdx.x * 32, r0 = blockIdx.y * 32;
  const int tx = threadIdx.x & 31, ty = threadIdx.x >> 5;
#pragma unroll
  for (int j = 0; j < 4; ++j) {
    int r = ty + j * 8;
    ls[r][tx] = in[(size_t)(r0 + r) * C + c0 + tx];
  }
  __syncthreads();
#pragma unroll
  for (int j = 0; j < 4; ++j) {
    int cc = ty + j * 8;
    out[(size_t)(c0 + cc) * R + r0 + tx] = ls[tx][cc];
  }
}

// -------------------- conv1 weight transpose: WT[r][co][ci] = w[co][ci][r]
__global__ __launch_bounds__(256) void wtr_k(const float* __restrict__ w,
                                             float* __restrict__ wt) {
  const int e = blockIdx.x * 256 + threadIdx.x;   // < 9*128*256 = 294912
  const int r = e >> 15;
  const int rem = e & 32767;
  const int co = rem >> 8, ci = rem & 255;
  wt[e] = w[((size_t)co * 256 + ci) * 9 + r];
}

// -------- conv1 as direct tap-GEMM: grid (2, 98, 3), z = ky; 32-pixel tiles
__global__ __launch_bounds__(256) void conv1_k(const float* __restrict__ X,
    const float* __restrict__ WT, float* __restrict__ P) {
  __shared__ __align__(16) short As[32][40];
  __shared__ __align__(16) short Bs[64][40];
  const int n0 = blockIdx.x * 64;
  const int m0 = blockIdx.y * 32;
  const int ky = blockIdx.z;
  const int t = threadIdx.x;
  const int w = t >> 6, l = t & 63;
  const int g = l >> 4, c = l & 15;
  const int wr = w >> 1, wc = w & 1;
  const int sr = t >> 2, seg = t & 3;
  const int p = m0 + (sr & 31);
  const int y = p / 56, x = p - y * 56;
  const int yy = y + ky - 1;
  f32x4 acc[2] = {};
  for (int kx = 0; kx < 3; ++kx) {
    const int xx = x + kx - 1;
    const bool valid = (t < 128) && ((unsigned)yy < 56u) && ((unsigned)xx < 56u);
    const float* Ap = X + (size_t)(yy * 56 + xx) * CD + seg * 8;
    const float* Bp = WT + ((size_t)(ky * 3 + kx) * 128 + n0 + sr) * CD + seg * 8;
    for (int k0 = 0; k0 < CD; k0 += 32) {
      float4 a1 = make_float4(0.f, 0.f, 0.f, 0.f), a2 = a1;
      if (valid) { a1 = *(const float4*)(Ap + k0); a2 = *(const float4*)(Ap + k0 + 4); }
      const float4 b1 = *(const float4*)(Bp + k0);
      const float4 b2 = *(const float4*)(Bp + k0 + 4);
      __syncthreads();
      if (t < 128) *(short8v*)&As[sr][seg * 8] = cvt8(a1, a2);
      *(short8v*)&Bs[sr][seg * 8] = cvt8(b1, b2);
      __syncthreads();
      const short8v af = *(const short8v*)&As[wr * 16 + c][g * 8];
      const short8v bf0 = *(const short8v*)&Bs[wc * 32 + c][g * 8];
      const short8v bf1 = *(const short8v*)&Bs[wc * 32 + 16 + c][g * 8];
      acc[0] = __builtin_amdgcn_mfma_f32_16x16x32_bf16(af, bf0, acc[0], 0, 0, 0);
      acc[1] = __builtin_amdgcn_mfma_f32_16x16x32_bf16(af, bf1, acc[1], 0, 0, 0);
    }
  }
#pragma unroll
  for (int ni = 0; ni < 2; ++ni) {
    const int col = n0 + wc * 32 + ni * 16 + c;
#pragma unroll
    for (int q = 0; q < 4; ++q) {
      const int m = m0 + wr * 16 + g * 4 + q;
      P[((size_t)ky * N_TOK + m) * 128 + col] = acc[ni][q];
    }
  }
}

// ----------------------- reduce conv1 tap partials + bias + relu -> T1
__global__ __launch_bounds__(256) void convred_k(const float* __restrict__ P,
    const float* __restrict__ b, float* __restrict__ T1) {
  const int e = blockIdx.x * 256 + threadIdx.x;   // < 3136*128
  const float v = P[e] + P[401408 + e] + P[802816 + e] + b[e & 127];
  T1[e] = fmaxf(v, 0.f);
}

// ------------------ 32x64-tile bf16 MFMA GEMM NT (fp32 in, fp32 out)
template <int RELU>
__global__ __launch_bounds__(256) void gemm32_k(const float* __restrict__ A,
    const float* __restrict__ B, const float* __restrict__ bias,
    float* __restrict__ C, int N, int K) {
  __shared__ __align__(16) short As[32][40];
  __shared__ __align__(16) short Bs[64][40];
  const int n0 = blockIdx.x * 64;
  const int m0 = blockIdx.y * 32;
  const int t = threadIdx.x;
  const int w = t >> 6, l = t & 63;
  const int g = l >> 4, c = l & 15;
  const int wr = w >> 1, wc = w & 1;
  const int sr = t >> 2, seg = t & 3;
  const float* Ap = A + (size_t)(m0 + (sr & 31)) * K + seg * 8;
  const float* Bp = B + (size_t)(n0 + sr) * K + seg * 8;
  f32x4 acc[2] = {};
  for (int k0 = 0; k0 < K; k0 += 32) {
    float4 a1 = make_float4(0.f, 0.f, 0.f, 0.f), a2 = a1;
    if (t < 128) { a1 = *(const float4*)(Ap + k0); a2 = *(const float4*)(Ap + k0 + 4); }
    const float4 b1 = *(const float4*)(Bp + k0);
    const float4 b2 = *(const float4*)(Bp + k0 + 4);
    __syncthreads();
    if (t < 128) *(short8v*)&As[sr][seg * 8] = cvt8(a1, a2);
    *(short8v*)&Bs[sr][seg * 8] = cvt8(b1, b2);
    __syncthreads();
    const short8v af = *(const short8v*)&As[wr * 16 + c][g * 8];
    const short8v bf0 = *(const short8v*)&Bs[wc * 32 + c][g * 8];
    const short8v bf1 = *(const short8v*)&Bs[wc * 32 + 16 + c][g * 8];
    acc[0] = __builtin_amdgcn_mfma_f32_16x16x32_bf16(af, bf0, acc[0], 0, 0, 0);
    acc[1] = __builtin_amdgcn_mfma_f32_16x16x32_bf16(af, bf1, acc[1], 0, 0, 0);
  }
#pragma unroll
  for (int ni = 0; ni < 2; ++ni) {
    const int col = n0 + wc * 32 + ni * 16 + c;
    const float bb = bias ? bias[col] : 0.f;
#pragma unroll
    for (int q = 0; q < 4; ++q) {
      const int m = m0 + wr * 16 + g * 4 + q;
      float v = acc[ni][q] + bb;
      if (RELU) v = fmaxf(v, 0.f);
      C[(size_t)m * N + col] = v;
    }
  }
}

// ---------------- fused Q/K/V projections, 32-row tiles, bf16 outputs
// Q/K written per-head contiguous: [h][tok][32]. V^T chunk-swizzled [d][tok].
__global__ __launch_bounds__(256) void proj32_k(const float* __restrict__ QKIN,
    const float* __restrict__ X, const float* __restrict__ Wq,
    const float* __restrict__ Wk, const float* __restrict__ Wv,
    const float* __restrict__ bq, const float* __restrict__ bk,
    const float* __restrict__ bv, short* __restrict__ QB,
    short* __restrict__ KB, short* __restrict__ VT) {
  __shared__ __align__(16) short As[32][40];
  __shared__ __align__(16) short Bs[64][40];
  const int sel = blockIdx.z;
  const int n0 = blockIdx.x * 64;
  const int m0 = blockIdx.y * 32;
  const float* A = (sel < 2) ? QKIN : X;
  const float* B = (sel == 0) ? Wq : (sel == 1) ? Wk : Wv;
  const float* bias = (sel == 0) ? bq : (sel == 1) ? bk : bv;
  const int t = threadIdx.x;
  const int w = t >> 6, l = t & 63;
  const int g = l >> 4, c = l & 15;
  const int wr = w >> 1, wc = w & 1;
  const int sr = t >> 2, seg = t & 3;
  const float* Ap = A + (size_t)(m0 + (sr & 31)) * CD + seg * 8;
  const float* Bp = B + (size_t)(n0 + sr) * CD + seg * 8;
  f32x4 acc[2] = {};
  for (int k0 = 0; k0 < CD; k0 += 32) {
    float4 a1 = make_float4(0.f, 0.f, 0.f, 0.f), a2 = a1;
    if (t < 128) { a1 = *(const float4*)(Ap + k0); a2 = *(const float4*)(Ap + k0 + 4); }
    const float4 b1 = *(const float4*)(Bp + k0);
    const float4 b2 = *(const float4*)(Bp + k0 + 4);
    __syncthreads();
    if (t < 128) *(short8v*)&As[sr][seg * 8] = cvt8(a1, a2);
    *(short8v*)&Bs[sr][seg * 8] = cvt8(b1, b2);
    __syncthreads();
    const short8v af = *(const short8v*)&As[wr * 16 + c][g * 8];
    const short8v bf0 = *(const short8v*)&Bs[wc * 32 + c][g * 8];
    const short8v bf1 = *(const short8v*)&Bs[wc * 32 + 16 + c][g * 8];
    acc[0] = __builtin_amdgcn_mfma_f32_16x16x32_bf16(af, bf0, acc[0], 0, 0, 0);
    acc[1] = __builtin_amdgcn_mfma_f32_16x16x32_bf16(af, bf1, acc[1], 0, 0, 0);
  }
#pragma unroll
  for (int ni = 0; ni < 2; ++ni) {
    const int col = n0 + wc * 32 + ni * 16 + c;
    const float bb = bias[col];
    if (sel == 2) {
      const int mb = m0 + wr * 16 + g * 4;
      const int pidx = (mb & ~31) + ((mb >> 4) & 1) * 4 + ((mb >> 2) & 3) * 8;
      uint2 pk;
      const float v0 = acc[ni][0] + bb, v1 = acc[ni][1] + bb;
      const float v2 = acc[ni][2] + bb, v3 = acc[ni][3] + bb;
      pk.x = (unsigned)(unsigned short)bfr(v0) | ((unsigned)(unsigned short)bfr(v1) << 16);
      pk.y = (unsigned)(unsigned short)bfr(v2) | ((unsigned)(unsigned short)bfr(v3) << 16);
      *(uint2*)&VT[(size_t)col * N_TOK + pidx] = pk;
    } else {
      short* Ct = (sel == 0) ? QB : KB;
      const float qs = (sel == 0) ? QSC : 1.f;
      const int hh = col >> 5, dd = col & 31;
#pragma unroll
      for (int q = 0; q < 4; ++q) {
        const int m = m0 + wr * 16 + g * 4 + q;
        Ct[((size_t)hh * N_TOK + m) * 32 + dd] = bfr((acc[ni][q] + bb) * qs);
      }
    }
  }
}

// --------------- X -> bf16 hi/lo planes + row ||x||^2 (prologue only)
__global__ __launch_bounds__(256) void xsplit_k(const float* __restrict__ X,
    short* __restrict__ XH, short* __restrict__ XL, float* __restrict__ sq) {
  __shared__ float red[4];
  const int i = blockIdx.x, t = threadIdx.x;
  const size_t e = (size_t)i * CD + t;
  const float v = X[e];
  const unsigned ui = __float_as_uint(v);
  XH[e] = (short)(ui >> 16);
  const float hf = __uint_as_float(ui & 0xffff0000u);
  XL[e] = (short)(__float_as_uint(v - hf) >> 16);
  float s = v * v;
#pragma unroll
  for (int m = 1; m < 64; m <<= 1) s += __shfl_xor(s, m, 64);
  if ((t & 63) == 0) red[t >> 6] = s;
  __syncthreads();
  if (t == 0) sq[i] = red[0] + red[1] + red[2] + red[3];
}

// ---- Gram G = X X^T: LDS-staged (coalesced) from precomputed hi/lo planes
__global__ __launch_bounds__(256) void gemm_syr4_k(const short* __restrict__ XH,
    const short* __restrict__ XL, float* __restrict__ C) {
  __shared__ __align__(16) short AsH[64][40];
  __shared__ __align__(16) short AsL[64][40];
  __shared__ __align__(16) short BsH[64][40];
  __shared__ __align__(16) short BsL[64][40];
  int bid = blockIdx.x;
  int bi = (int)((sqrtf(8.f * (float)bid + 1.f) - 1.f) * 0.5f);
  while ((bi + 1) * (bi + 2) / 2 <= bid) ++bi;
  while (bi * (bi + 1) / 2 > bid) --bi;
  const int bj = bid - bi * (bi + 1) / 2;
  const int m0 = bi * 64, n0 = bj * 64;
  const int t = threadIdx.x;
  const int w = t >> 6, l = t & 63;
  const int g = l >> 4, c = l & 15;
  const int wr = w >> 1, wc = w & 1;
  const int sr = t >> 2, seg = t & 3;
  const size_t arow = (size_t)(m0 + sr) * CD + seg * 8;
  const size_t brow = (size_t)(n0 + sr) * CD + seg * 8;
  f32x4 acc[2][2] = {};
  for (int k0 = 0; k0 < CD; k0 += 32) {
    const short8v ah = *(const short8v*)&XH[arow + k0];
    const short8v al = *(const short8v*)&XL[arow + k0];
    const short8v bh = *(const short8v*)&XH[brow + k0];
    const short8v bl = *(const short8v*)&XL[brow + k0];
    __syncthreads();
    *(short8v*)&AsH[sr][seg * 8] = ah;
    *(short8v*)&AsL[sr][seg * 8] = al;
    *(short8v*)&BsH[sr][seg * 8] = bh;
    *(short8v*)&BsL[sr][seg * 8] = bl;
    __syncthreads();
    short8v afH[2], afL[2], bfH[2], bfL[2];
#pragma unroll
    for (int mi = 0; mi < 2; ++mi) {
      afH[mi] = *(const short8v*)&AsH[wr * 32 + mi * 16 + c][g * 8];
      afL[mi] = *(const short8v*)&AsL[wr * 32 + mi * 16 + c][g * 8];
    }
#pragma unroll
    for (int ni = 0; ni < 2; ++ni) {
      bfH[ni] = *(const short8v*)&BsH[wc * 32 + ni * 16 + c][g * 8];
      bfL[ni] = *(const short8v*)&BsL[wc * 32 + ni * 16 + c][g * 8];
    }
#pragma unroll
    for (int mi = 0; mi < 2; ++mi)
#pragma unroll
      for (int ni = 0; ni < 2; ++ni) {
        acc[mi][ni] = __builtin_amdgcn_mfma_f32_16x16x32_bf16(afH[mi], bfH[ni], acc[mi][ni], 0, 0, 0);
        acc[mi][ni] = __builtin_amdgcn_mfma_f32_16x16x32_bf16(afH[mi], bfL[ni], acc[mi][ni], 0, 0, 0);
        acc[mi][ni] = __builtin_amdgcn_mfma_f32_16x16x32_bf16(afL[mi], bfH[ni], acc[mi][ni], 0, 0, 0);
      }
  }
#pragma unroll
  for (int mi = 0; mi < 2; ++mi)
#pragma unroll
    for (int ni = 0; ni < 2; ++ni) {
      const int col = n0 + wc * 32 + ni * 16 + c;
#pragma unroll
      for (int q = 0; q < 4; ++q) {
        const int m = m0 + wr * 32 + mi * 16 + g * 4 + q;
        const float v = acc[mi][ni][q];
        C[(size_t)m * N_TOK + col] = v;
        C[(size_t)col * N_TOK + m] = v;
      }
    }
}

// ------------------- conv2 (8ch) -> writes gpT [8][N_TOK] * log2e directly
__global__ __launch_bounds__(256) void conv2_k(const float* __restrict__ t1,
    const float* __restrict__ w, const float* __restrict__ b,
    float* __restrict__ gpT) {
  __shared__ float ws3[9 * 8 * 132];
  const int t = threadIdx.x;
  for (int e = t; e < 9216; e += 256) {
    int r = e >> 10;
    int rem = e & 1023;
    int co = rem >> 7;
    int ci = rem & 127;
    ws3[(r * 8 + co) * 132 + ci] = w[((size_t)co * 128 + ci) * 9 + r];
  }
  __syncthreads();
  const int pix = blockIdx.x * 32 + (t >> 3);
  const int co = t & 7;
  const int y = pix / 56, x = pix - y * 56;
  float acc = b[co];
  for (int ky = 0; ky < 3; ++ky) {
    int yy = y + ky - 1;
    if (yy < 0 || yy >= 56) continue;
    for (int kx = 0; kx < 3; ++kx) {
      int xx = x + kx - 1;
      if (xx < 0 || xx >= 56) continue;
      const float4* tp = (const float4*)&t1[(size_t)(yy * 56 + xx) * 128];
      const float* wp = &ws3[((ky * 3 + kx) * 8 + co) * 132];
#pragma unroll
      for (int c4 = 0; c4 < 32; ++c4) {
        const float4 tv = tp[c4];
        const float4 wv = *(const float4*)&wp[c4 * 4];
        acc += tv.x * wv.x + tv.y * wv.y + tv.z * wv.z + tv.w * wv.w;
      }
    }
  }
  gpT[co * N_TOK + pix] = LOG2E / (1.f + expf(-acc));
}

// ---- top-16 NN + in-degree, v5: one wave/row, INCREMENTAL candidates.
// Each lane caches only (bestv, beste); per round the single winning lane
// rescans its 49 values (L1/L2-hot reads, cannot be hoisted: under branch)
// with a killed-bitmask. Exact lex top_k semantics (ties -> smaller j).
__global__ __launch_bounds__(64) void topk_k(const float* __restrict__ G,
    const float* __restrict__ sq, int* __restrict__ near) {
  const int i = blockIdx.x;
  const int t = threadIdx.x;            // lane 0..63
  const float sqi = sq[i];
  const float* __restrict__ Grow = G + (size_t)i * N_TOK;
  // initial per-lane min over its 49 keys (strict < keeps smallest e = j)
  unsigned bestv = 0xffffffffu;
  int beste = 0;
#pragma unroll
  for (int e = 0; e < 49; ++e) {
    const int j = t + (e << 6);         // 49*64 = 3136 exactly
    const unsigned v = f2mono((sqi - 2.f * Grow[j]) + sq[j]);
    const bool ok = v < bestv;
    beste = ok ? e : beste;
    bestv = ok ? v : bestv;
  }
  unsigned long long killed = 0ull;
#pragma unroll 1
  for (int r = 0; r < 16; ++r) {
    const unsigned long long mine =
        ((unsigned long long)bestv << 32) | (unsigned)(t + (beste << 6));
    unsigned long long best = mine;
#pragma unroll
    for (int m = 1; m < 64; m <<= 1) {
      const unsigned long long o = sx64(best, m);
      best = (o < best) ? o : best;
    }
    if (t == 0) atomicAdd(&near[(unsigned)(best & 0xffffffffu)], 1);
    // only the winning lane refreshes its candidate (exactly one: j unique)
    if (mine == best && r < 15) {
      killed |= 1ull << beste;
      bestv = 0xffffffffu;
      beste = 0;
#pragma unroll
      for (int e = 0; e < 49; ++e) {
        const int j = t + (e << 6);
        const unsigned v = f2mono((sqi - 2.f * Grow[j]) + sq[j]);
        const bool ok = (((killed >> e) & 1ull) == 0ull) && (v < bestv);
        beste = ok ? e : beste;
        bestv = ok ? v : bestv;
      }
    }
  }
}

// ------------- fused max(near) + qk_in = x + emb[ni(near)] (one row/block)
__global__ __launch_bounds__(256) void nearqk_k(const float* __restrict__ x,
    const int* __restrict__ near, const float* __restrict__ emb,
    float* __restrict__ qkin) {
  __shared__ int sm[4];
  const int i = blockIdx.x, t = threadIdx.x;
  int m = 0;
  for (int j = t; j < N_TOK; j += 256) m = max(m, near[j]);
#pragma unroll
  for (int s = 1; s < 64; s <<= 1) m = max(m, __shfl_xor(m, s, 64));
  if ((t & 63) == 0) sm[t >> 6] = m;
  __syncthreads();
  const int mv = max(max(sm[0], sm[1]), max(sm[2], sm[3]));
  const int ni = (int)((float)near[i] / (float)mv * 9.0f);
  qkin[(size_t)i * CD + t] = x[(size_t)i * CD + t] + emb[ni * CD + t];
}

// ---- flash attention v7: 64 queries/wave (4 groups), per-head Q/K layout
// grid (49, 8): block = 64 queries, 4 j-quarter waves; in-block combine.
__global__ __launch_bounds__(256) void attn_v7_k(const short* __restrict__ Qb,
    const short* __restrict__ Kb, const short* __restrict__ Vt,
    const float* __restrict__ gpT, float* __restrict__ O1) {
  __shared__ float o_l[4][64][36];
  __shared__ float ml_l[4][64][2];
  const int h = blockIdx.y;
  const int qb = blockIdx.x * 64;
  const int t = threadIdx.x;
  const int w = t >> 6, l = t & 63;
  const int g = l >> 4, c = l & 15;
  const size_t hR = (size_t)h * N_TOK;      // per-head row base (Q/K/gpT)
  const size_t hoff = (size_t)h * DH;       // VT d-row base
  short8v qf[4];
  float gpi[4];
#pragma unroll
  for (int gr = 0; gr < 4; ++gr) {
    qf[gr] = *(const short8v*)&Qb[(hR + qb + gr * 16 + c) * 32 + g * 8];
    gpi[gr] = gpT[hR + qb + gr * 16 + c];
  }
  const int jt0 = w ? (13 + 12 * (w - 1)) : 0;
  const int jt1 = jt0 + (w ? 12 : 13);
  float mr[4] = {-INFINITY, -INFINITY, -INFINITY, -INFINITY};
  float lp[4] = {0.f, 0.f, 0.f, 0.f};
  f32x4 oa[4][2] = {};
  const f32x4 zz = {0.f, 0.f, 0.f, 0.f};

#pragma unroll 1
  for (int jt = jt0; jt < jt1; ++jt) {
    const int j0 = jt * 64;
    short8v kf[4], vf[4];
    float4 gj[4];
#pragma unroll
    for (int sub = 0; sub < 4; ++sub)
      kf[sub] = *(const short8v*)&Kb[(hR + j0 + sub * 16 + c) * 32 + g * 8];
#pragma unroll
    for (int ch = 0; ch < 2; ++ch)
#pragma unroll
      for (int ds = 0; ds < 2; ++ds)
        vf[ch * 2 + ds] = *(const short8v*)&Vt[(hoff + ds * 16 + c) * (size_t)N_TOK + j0 + ch * 32 + g * 8];
#pragma unroll
    for (int sub = 0; sub < 4; ++sub)
      gj[sub] = *(const float4*)&gpT[hR + j0 + sub * 16 + g * 4];
#pragma unroll
    for (int gr = 0; gr < 4; ++gr) {
      f32x4 sacc[4];
#pragma unroll
      for (int sub = 0; sub < 4; ++sub)
        sacc[sub] = __builtin_amdgcn_mfma_f32_16x16x32_bf16(kf[sub], qf[gr], zz, 0, 0, 0);
      float sv[16];
#pragma unroll
      for (int sub = 0; sub < 4; ++sub) {
        sv[sub * 4 + 0] = sacc[sub][0] + fabsf(gpi[gr] - gj[sub].x);
        sv[sub * 4 + 1] = sacc[sub][1] + fabsf(gpi[gr] - gj[sub].y);
        sv[sub * 4 + 2] = sacc[sub][2] + fabsf(gpi[gr] - gj[sub].z);
        sv[sub * 4 + 3] = sacc[sub][3] + fabsf(gpi[gr] - gj[sub].w);
      }
      float a0 = fmaxf(sv[0], sv[1]),  a1 = fmaxf(sv[2], sv[3]);
      float a2 = fmaxf(sv[4], sv[5]),  a3 = fmaxf(sv[6], sv[7]);
      float a4 = fmaxf(sv[8], sv[9]),  a5 = fmaxf(sv[10], sv[11]);
      float a6 = fmaxf(sv[12], sv[13]), a7 = fmaxf(sv[14], sv[15]);
      const float mx = fmaxf(fmaxf(fmaxf(a0, a1), fmaxf(a2, a3)),
                             fmaxf(fmaxf(a4, a5), fmaxf(a6, a7)));
      if (!__all(mx - mr[gr] <= 11.f)) {
        float mn = mx;
        mn = fmaxf(mn, __shfl_xor(mn, 16, 64));
        mn = fmaxf(mn, __shfl_xor(mn, 32, 64));
        mn = fmaxf(mn, mr[gr]);
        const float sc = __builtin_amdgcn_exp2f(mr[gr] - mn);
        oa[gr][0][0] *= sc; oa[gr][0][1] *= sc; oa[gr][0][2] *= sc; oa[gr][0][3] *= sc;
        oa[gr][1][0] *= sc; oa[gr][1][1] *= sc; oa[gr][1][2] *= sc; oa[gr][1][3] *= sc;
        lp[gr] *= sc;
        mr[gr] = mn;
      }
      float p[16];
#pragma unroll
      for (int e = 0; e < 16; ++e) p[e] = __builtin_amdgcn_exp2f(sv[e] - mr[gr]);
      const float ps0 = (p[0] + p[1]) + (p[2] + p[3]);
      const float ps1 = (p[4] + p[5]) + (p[6] + p[7]);
      const float ps2 = (p[8] + p[9]) + (p[10] + p[11]);
      const float ps3 = (p[12] + p[13]) + (p[14] + p[15]);
      lp[gr] += (ps0 + ps1) + (ps2 + ps3);
      union { unsigned u[4]; short8v s; } pf0, pf1;
#pragma unroll
      for (int sub = 0; sub < 2; ++sub) {
        pf0.u[2 * sub + 0] = __builtin_amdgcn_perm(__float_as_uint(p[4 * sub + 1]),
                                                   __float_as_uint(p[4 * sub + 0]), 0x07060302u);
        pf0.u[2 * sub + 1] = __builtin_amdgcn_perm(__float_as_uint(p[4 * sub + 3]),
                                                   __float_as_uint(p[4 * sub + 2]), 0x07060302u);
        pf1.u[2 * sub + 0] = __builtin_amdgcn_perm(__float_as_uint(p[8 + 4 * sub + 1]),
                                                   __float_as_uint(p[8 + 4 * sub + 0]), 0x07060302u);
        pf1.u[2 * sub + 1] = __builtin_amdgcn_perm(__float_as_uint(p[8 + 4 * sub + 3]),
                                                   __float_as_uint(p[8 + 4 * sub + 2]), 0x07060302u);
      }
      oa[gr][0] = __builtin_amdgcn_mfma_f32_16x16x32_bf16(vf[0], pf0.s, oa[gr][0], 0, 0, 0);
      oa[gr][1] = __builtin_amdgcn_mfma_f32_16x16x32_bf16(vf[1], pf0.s, oa[gr][1], 0, 0, 0);
      oa[gr][0] = __builtin_amdgcn_mfma_f32_16x16x32_bf16(vf[2], pf1.s, oa[gr][0], 0, 0, 0);
      oa[gr][1] = __builtin_amdgcn_mfma_f32_16x16x32_bf16(vf[3], pf1.s, oa[gr][1], 0, 0, 0);
    }
  }
#pragma unroll
  for (int gr = 0; gr < 4; ++gr) {
    lp[gr] += __shfl_xor(lp[gr], 16, 64);
    lp[gr] += __shfl_xor(lp[gr], 32, 64);
#pragma unroll
    for (int ds = 0; ds < 2; ++ds)
      *(f32x4*)&o_l[w][gr * 16 + c][ds * 16 + g * 4] = oa[gr][ds];
    if (g == 0) {
      ml_l[w][gr * 16 + c][0] = mr[gr];
      ml_l[w][gr * 16 + c][1] = lp[gr];
    }
  }
  __syncthreads();
  const int q = t >> 2, d0 = (t & 3) * 8;
  const float M = fmaxf(fmaxf(ml_l[0][q][0], ml_l[1][q][0]),
                        fmaxf(ml_l[2][q][0], ml_l[3][q][0]));
  float den = 0.f;
  f32x4 numA = {0.f, 0.f, 0.f, 0.f};
  f32x4 numB = {0.f, 0.f, 0.f, 0.f};
#pragma unroll
  for (int sp = 0; sp < 4; ++sp) {
    const float wg = __builtin_amdgcn_exp2f(ml_l[sp][q][0] - M);
    den += wg * ml_l[sp][q][1];
    const f32x4 oA = *(const f32x4*)&o_l[sp][q][d0];
    const f32x4 oB = *(const f32x4*)&o_l[sp][q][d0 + 4];
    numA[0] += wg * oA[0]; numA[1] += wg * oA[1];
    numA[2] += wg * oA[2]; numA[3] += wg * oA[3];
    numB[0] += wg * oB[0]; numB[1] += wg * oB[1];
    numB[2] += wg * oB[2]; numB[3] += wg * oB[3];
  }
  const float inv = 1.f / den;
  f32x4 rA = {numA[0] * inv, numA[1] * inv, numA[2] * inv, numA[3] * inv};
  f32x4 rB = {numB[0] * inv, numB[1] * inv, numB[2] * inv, numB[3] * inv};
  *(f32x4*)&O1[(size_t)(qb + q) * CD + hoff + d0] = rA;
  *(f32x4*)&O1[(size_t)(qb + q) * CD + hoff + d0 + 4] = rB;
}

// ------ LayerNorm (+residual); SPLIT=1 also emits XH/XL planes + row-sq
template <int SPLIT>
__global__ __launch_bounds__(256) void ln_k(const float* __restrict__ xin,
    const float* __restrict__ add, const float* __restrict__ g,
    const float* __restrict__ b, float* __restrict__ xout,
    float* __restrict__ sqout, short* __restrict__ XH, short* __restrict__ XL) {
  __shared__ float red1[4];
  __shared__ float red2[4];
  const int i = blockIdx.x, t = threadIdx.x;
  const size_t e = (size_t)i * CD + t;
  float v = xin[e];
  if (add) v += add[e];
  float s = v;
#pragma unroll
  for (int m = 1; m < 64; m <<= 1) s += __shfl_xor(s, m, 64);
  if ((t & 63) == 0) red1[t >> 6] = s;
  __syncthreads();
  const float mean = (red1[0] + red1[1] + red1[2] + red1[3]) * (1.f / 256.f);
  const float d = v - mean;
  float s2 = d * d;
#pragma unroll
  for (int m = 1; m < 64; m <<= 1) s2 += __shfl_xor(s2, m, 64);
  if ((t & 63) == 0) red2[t >> 6] = s2;
  __syncthreads();
  const float var = (red2[0] + red2[1] + red2[2] + red2[3]) * (1.f / 256.f);
  const float xo = d * rsqrtf(var + 1e-5f) * g[t] + b[t];
  xout[e] = xo;
  if (SPLIT) {
    const unsigned ui = __float_as_uint(xo);
    XH[e] = (short)(ui >> 16);
    const float hf = __uint_as_float(ui & 0xffff0000u);
    XL[e] = (short)(__float_as_uint(xo - hf) >> 16);
    float s3 = xo * xo;
#pragma unroll
    for (int m = 1; m < 64; m <<= 1) s3 += __shfl_xor(s3, m, 64);
    __syncthreads();
    if ((t & 63) == 0) red1[t >> 6] = s3;
    __syncthreads();
    if (t == 0) sqout[i] = red1[0] + red1[1] + red1[2] + red1[3];
  }
}

// ---------------------------------------------------------------- launch
extern "C" void kernel_launch(void* const* d_in, const int* in_sizes, int n_in,
                              void* d_out, int out_size, void* d_ws, size_t ws_size,
                              hipStream_t stream) {
  const float* src  = (const float*)d_in[0];
  const float* c1w  = (const float*)d_in[1];
  const float* c1b  = (const float*)d_in[2];
  const float* c2w  = (const float*)d_in[3];
  const float* c2b  = (const float*)d_in[4];
  const float* nemb = (const float*)d_in[5];
  const float* Wq   = (const float*)d_in[6];
  const float* bq   = (const float*)d_in[7];
  const float* Wk   = (const float*)d_in[8];
  const float* bk   = (const float*)d_in[9];
  const float* Wv   = (const float*)d_in[10];
  const float* bv   = (const float*)d_in[11];
  const float* Wo   = (const float*)d_in[12];
  const float* bo   = (const float*)d_in[13];
  const float* W1   = (const float*)d_in[14];
  const float* b1   = (const float*)d_in[15];
  const float* W2   = (const float*)d_in[16];
  const float* b2   = (const float*)d_in[17];
  const float* ln1g = (const float*)d_in[18];
  const float* ln1b = (const float*)d_in[19];
  const float* ln2g = (const float*)d_in[20];
  const float* ln2b = (const float*)d_in[21];
  const float* ng   = (const float*)d_in[22];
  const float* nb   = (const float*)d_in[23];

  float* ws = (float*)d_ws;
  const size_t NC = (size_t)N_TOK * CD;          // 802816
  float* X    = ws;
  float* QKIN = X + NC;
  float* O1   = QKIN + NC;
  float* TMP  = O1 + NC;
  float* FF1  = TMP + NC;                        // 3136*1024
  float* G    = FF1 + (size_t)N_TOK * DFFD;      // 3136*3136 (also conv1 partials)
  float* T1   = G + (size_t)N_TOK * N_TOK;       // 3136*128
  float* GPT  = T1 + (size_t)N_TOK * 128;        // 8*3136
  float* SQF  = GPT + (size_t)N_TOK * NHD;       // 3136
  short* QB16 = (short*)(SQF + N_TOK);
  short* KB16 = QB16 + NC;
  short* VT16 = KB16 + NC;
  short* XH   = VT16 + NC;                       // bf16 hi plane
  short* XL   = XH + NC;                         // bf16 lo plane
  float* WTC  = (float*)(XL + NC);               // 9*128*256 = 294912
  int*   NEAR = (int*)(WTC + 294912);            // 4 * 3136 ints

  // tokens + conv positional encoder (direct conv, no im2col)
  transpose_k<<<dim3(98, 8), 256, 0, stream>>>(src, X, 256, N_TOK);
  wtr_k<<<1152, 256, 0, stream>>>(c1w, WTC);
  conv1_k<<<dim3(2, 98, 3), 256, 0, stream>>>(X, WTC, G);
  convred_k<<<1568, 256, 0, stream>>>(G, c1b, T1);
  conv2_k<<<98, 256, 0, stream>>>(T1, c2w, c2b, GPT);
  xsplit_k<<<N_TOK, 256, 0, stream>>>(X, XH, XL, SQF);
  (void)hipMemsetAsync(NEAR, 0, 4 * N_TOK * sizeof(int), stream);

  for (int l = 0; l < 4; ++l) {
    int* NEAR_l = NEAR + l * N_TOK;
    // ---- kNN graph -> near counts (hi/lo bf16 MFMA Gram, LDS-staged)
    gemm_syr4_k<<<1225, 256, 0, stream>>>(XH, XL, G);
    topk_k<<<N_TOK, 64, 0, stream>>>(G, SQF, NEAR_l);
    nearqk_k<<<N_TOK, 256, 0, stream>>>(X, NEAR_l, nemb, QKIN);
    // ---- fused Q/K/V projections (32-row tiles, per-head Q/K layout)
    proj32_k<<<dim3(4, 98, 3), 256, 0, stream>>>(QKIN, X,
        Wq + (size_t)l * 65536, Wk + (size_t)l * 65536, Wv + (size_t)l * 65536,
        bq + l * 256, bk + l * 256, bv + l * 256, QB16, KB16, VT16);
    // ---- attention (64 q/wave, halved load count, in-block combine)
    attn_v7_k<<<dim3(49, 8), 256, 0, stream>>>(QB16, KB16, VT16, GPT, O1);
    gemm32_k<0><<<dim3(4, 98), 256, 0, stream>>>(O1, Wo + (size_t)l * 65536, bo + l * 256, TMP, 256, 256);
    ln_k<0><<<N_TOK, 256, 0, stream>>>(X, TMP, ln1g + l * 256, ln1b + l * 256, X, nullptr, nullptr, nullptr);
    // ---- FFN
    gemm32_k<1><<<dim3(16, 98), 256, 0, stream>>>(X, W1 + (size_t)l * 262144, b1 + l * 1024, FF1, 1024, 256);
    gemm32_k<0><<<dim3(4, 98), 256, 0, stream>>>(FF1, W2 + (size_t)l * 262144, b2 + l * 256, TMP, 256, 1024);
    // ln2 fused with X hi/lo split + row-sq (feeds next layer's Gram/topk)
    ln_k<1><<<N_TOK, 256, 0, stream>>>(X, TMP, ln2g + l * 256, ln2b + l * 256, X, SQF, XH, XL);
  }
  // final LN + transpose to [1,C,H,W]
  ln_k<0><<<N_TOK, 256, 0, stream>>>(X, nullptr, ng, nb, TMP, nullptr, nullptr, nullptr);
  transpose_k<<<dim3(8, 98), 256, 0, stream>>>(TMP, (float*)d_out, N_TOK, 256);
}

// Round 18
// 657.099 us; speedup vs baseline: 2.0446x; 2.0446x over previous
//
#include <hip/hip_runtime.h>
#include <math.h>

#define N_TOK 3136
#define CD    256
#define NHD   8
#define DH    32
#define DFFD  1024
#define SCALE 0.17677669529663687f  /* 32^-0.5 */
#define LOG2E 1.4426950408889634f
#define QSC   (SCALE * LOG2E)

typedef __attribute__((ext_vector_type(8))) short short8v;
typedef __attribute__((ext_vector_type(4))) float f32x4;

// ---------------------------------------------------------------- utils
__device__ __forceinline__ unsigned long long sx64(unsigned long long v, int m) {
  unsigned lo = (unsigned)__shfl_xor((int)(unsigned)(v & 0xffffffffull), m, 64);
  unsigned hi = (unsigned)__shfl_xor((int)(unsigned)(v >> 32), m, 64);
  return ((unsigned long long)hi << 32) | lo;
}

__device__ __forceinline__ unsigned f2mono(float v) {
  unsigned b = __float_as_uint(v);
  return (b & 0x80000000u) ? ~b : (b | 0x80000000u);
}

// fp32 -> bf16 round-to-nearest-even
__device__ __forceinline__ short bfr(float f) {
  unsigned u = __float_as_uint(f);
  unsigned r = (u + 0x7fffu + ((u >> 16) & 1u)) >> 16;
  return (short)r;
}

__device__ __forceinline__ short8v cvt8(float4 a, float4 b) {
  short8v r;
  r[0] = bfr(a.x); r[1] = bfr(a.y); r[2] = bfr(a.z); r[3] = bfr(a.w);
  r[4] = bfr(b.x); r[5] = bfr(b.y); r[6] = bfr(b.z); r[7] = bfr(b.w);
  return r;
}

// ------------------------------------------------- transpose (32x32 tiles)
__global__ __launch_bounds__(256) void transpose_k(const float* __restrict__ in,
    float* __restrict__ out, int R, int C) {
  __shared__ float ls[32][33];
  const int c0 = blockIdx.x * 32, r0 = blockIdx.y * 32;
  const int tx = threadIdx.x & 31, ty = threadIdx.x >> 5;
#pragma unroll
  for (int j = 0; j < 4; ++j) {
    int r = ty + j * 8;
    ls[r][tx] = in[(size_t)(r0 + r) * C + c0 + tx];
  }
  __syncthreads();
#pragma unroll
  for (int j = 0; j < 4; ++j) {
    int cc = ty + j * 8;
    out[(size_t)(c0 + cc) * R + r0 + tx] = ls[tx][cc];
  }
}

// -------------------- conv1 weight transpose: WT[r][co][ci] = w[co][ci][r]
__global__ __launch_bounds__(256) void wtr_k(const float* __restrict__ w,
                                             float* __restrict__ wt) {
  const int e = blockIdx.x * 256 + threadIdx.x;   // < 9*128*256 = 294912
  const int r = e >> 15;
  const int rem = e & 32767;
  const int co = rem >> 8, ci = rem & 255;
  wt[e] = w[((size_t)co * 256 + ci) * 9 + r];
}

// -------- conv1 as direct tap-GEMM: grid (2, 98, 3), z = ky; 32-pixel tiles
__global__ __launch_bounds__(256) void conv1_k(const float* __restrict__ X,
    const float* __restrict__ WT, float* __restrict__ P) {
  __shared__ __align__(16) short As[32][40];
  __shared__ __align__(16) short Bs[64][40];
  const int n0 = blockIdx.x * 64;
  const int m0 = blockIdx.y * 32;
  const int ky = blockIdx.z;
  const int t = threadIdx.x;
  const int w = t >> 6, l = t & 63;
  const int g = l >> 4, c = l & 15;
  const int wr = w >> 1, wc = w & 1;
  const int sr = t >> 2, seg = t & 3;
  const int p = m0 + (sr & 31);
  const int y = p / 56, x = p - y * 56;
  const int yy = y + ky - 1;
  f32x4 acc[2] = {};
  for (int kx = 0; kx < 3; ++kx) {
    const int xx = x + kx - 1;
    const bool valid = (t < 128) && ((unsigned)yy < 56u) && ((unsigned)xx < 56u);
    const float* Ap = X + (size_t)(yy * 56 + xx) * CD + seg * 8;
    const float* Bp = WT + ((size_t)(ky * 3 + kx) * 128 + n0 + sr) * CD + seg * 8;
    for (int k0 = 0; k0 < CD; k0 += 32) {
      float4 a1 = make_float4(0.f, 0.f, 0.f, 0.f), a2 = a1;
      if (valid) { a1 = *(const float4*)(Ap + k0); a2 = *(const float4*)(Ap + k0 + 4); }
      const float4 b1 = *(const float4*)(Bp + k0);
      const float4 b2 = *(const float4*)(Bp + k0 + 4);
      __syncthreads();
      if (t < 128) *(short8v*)&As[sr][seg * 8] = cvt8(a1, a2);
      *(short8v*)&Bs[sr][seg * 8] = cvt8(b1, b2);
      __syncthreads();
      const short8v af = *(const short8v*)&As[wr * 16 + c][g * 8];
      const short8v bf0 = *(const short8v*)&Bs[wc * 32 + c][g * 8];
      const short8v bf1 = *(const short8v*)&Bs[wc * 32 + 16 + c][g * 8];
      acc[0] = __builtin_amdgcn_mfma_f32_16x16x32_bf16(af, bf0, acc[0], 0, 0, 0);
      acc[1] = __builtin_amdgcn_mfma_f32_16x16x32_bf16(af, bf1, acc[1], 0, 0, 0);
    }
  }
#pragma unroll
  for (int ni = 0; ni < 2; ++ni) {
    const int col = n0 + wc * 32 + ni * 16 + c;
#pragma unroll
    for (int q = 0; q < 4; ++q) {
      const int m = m0 + wr * 16 + g * 4 + q;
      P[((size_t)ky * N_TOK + m) * 128 + col] = acc[ni][q];
    }
  }
}

// ----------------------- reduce conv1 tap partials + bias + relu -> T1
__global__ __launch_bounds__(256) void convred_k(const float* __restrict__ P,
    const float* __restrict__ b, float* __restrict__ T1) {
  const int e = blockIdx.x * 256 + threadIdx.x;   // < 3136*128
  const float v = P[e] + P[401408 + e] + P[802816 + e] + b[e & 127];
  T1[e] = fmaxf(v, 0.f);
}

// ------------------ 32x64-tile bf16 MFMA GEMM NT (fp32 in, fp32 out)
template <int RELU>
__global__ __launch_bounds__(256) void gemm32_k(const float* __restrict__ A,
    const float* __restrict__ B, const float* __restrict__ bias,
    float* __restrict__ C, int N, int K) {
  __shared__ __align__(16) short As[32][40];
  __shared__ __align__(16) short Bs[64][40];
  const int n0 = blockIdx.x * 64;
  const int m0 = blockIdx.y * 32;
  const int t = threadIdx.x;
  const int w = t >> 6, l = t & 63;
  const int g = l >> 4, c = l & 15;
  const int wr = w >> 1, wc = w & 1;
  const int sr = t >> 2, seg = t & 3;
  const float* Ap = A + (size_t)(m0 + (sr & 31)) * K + seg * 8;
  const float* Bp = B + (size_t)(n0 + sr) * K + seg * 8;
  f32x4 acc[2] = {};
  for (int k0 = 0; k0 < K; k0 += 32) {
    float4 a1 = make_float4(0.f, 0.f, 0.f, 0.f), a2 = a1;
    if (t < 128) { a1 = *(const float4*)(Ap + k0); a2 = *(const float4*)(Ap + k0 + 4); }
    const float4 b1 = *(const float4*)(Bp + k0);
    const float4 b2 = *(const float4*)(Bp + k0 + 4);
    __syncthreads();
    if (t < 128) *(short8v*)&As[sr][seg * 8] = cvt8(a1, a2);
    *(short8v*)&Bs[sr][seg * 8] = cvt8(b1, b2);
    __syncthreads();
    const short8v af = *(const short8v*)&As[wr * 16 + c][g * 8];
    const short8v bf0 = *(const short8v*)&Bs[wc * 32 + c][g * 8];
    const short8v bf1 = *(const short8v*)&Bs[wc * 32 + 16 + c][g * 8];
    acc[0] = __builtin_amdgcn_mfma_f32_16x16x32_bf16(af, bf0, acc[0], 0, 0, 0);
    acc[1] = __builtin_amdgcn_mfma_f32_16x16x32_bf16(af, bf1, acc[1], 0, 0, 0);
  }
#pragma unroll
  for (int ni = 0; ni < 2; ++ni) {
    const int col = n0 + wc * 32 + ni * 16 + c;
    const float bb = bias ? bias[col] : 0.f;
#pragma unroll
    for (int q = 0; q < 4; ++q) {
      const int m = m0 + wr * 16 + g * 4 + q;
      float v = acc[ni][q] + bb;
      if (RELU) v = fmaxf(v, 0.f);
      C[(size_t)m * N + col] = v;
    }
  }
}

// ---------------- fused Q/K/V projections, 32-row tiles, bf16 outputs
// Q/K written per-head contiguous: [h][tok][32]. V^T chunk-swizzled [d][tok].
__global__ __launch_bounds__(256) void proj32_k(const float* __restrict__ QKIN,
    const float* __restrict__ X, const float* __restrict__ Wq,
    const float* __restrict__ Wk, const float* __restrict__ Wv,
    const float* __restrict__ bq, const float* __restrict__ bk,
    const float* __restrict__ bv, short* __restrict__ QB,
    short* __restrict__ KB, short* __restrict__ VT) {
  __shared__ __align__(16) short As[32][40];
  __shared__ __align__(16) short Bs[64][40];
  const int sel = blockIdx.z;
  const int n0 = blockIdx.x * 64;
  const int m0 = blockIdx.y * 32;
  const float* A = (sel < 2) ? QKIN : X;
  const float* B = (sel == 0) ? Wq : (sel == 1) ? Wk : Wv;
  const float* bias = (sel == 0) ? bq : (sel == 1) ? bk : bv;
  const int t = threadIdx.x;
  const int w = t >> 6, l = t & 63;
  const int g = l >> 4, c = l & 15;
  const int wr = w >> 1, wc = w & 1;
  const int sr = t >> 2, seg = t & 3;
  const float* Ap = A + (size_t)(m0 + (sr & 31)) * CD + seg * 8;
  const float* Bp = B + (size_t)(n0 + sr) * CD + seg * 8;
  f32x4 acc[2] = {};
  for (int k0 = 0; k0 < CD; k0 += 32) {
    float4 a1 = make_float4(0.f, 0.f, 0.f, 0.f), a2 = a1;
    if (t < 128) { a1 = *(const float4*)(Ap + k0); a2 = *(const float4*)(Ap + k0 + 4); }
    const float4 b1 = *(const float4*)(Bp + k0);
    const float4 b2 = *(const float4*)(Bp + k0 + 4);
    __syncthreads();
    if (t < 128) *(short8v*)&As[sr][seg * 8] = cvt8(a1, a2);
    *(short8v*)&Bs[sr][seg * 8] = cvt8(b1, b2);
    __syncthreads();
    const short8v af = *(const short8v*)&As[wr * 16 + c][g * 8];
    const short8v bf0 = *(const short8v*)&Bs[wc * 32 + c][g * 8];
    const short8v bf1 = *(const short8v*)&Bs[wc * 32 + 16 + c][g * 8];
    acc[0] = __builtin_amdgcn_mfma_f32_16x16x32_bf16(af, bf0, acc[0], 0, 0, 0);
    acc[1] = __builtin_amdgcn_mfma_f32_16x16x32_bf16(af, bf1, acc[1], 0, 0, 0);
  }
#pragma unroll
  for (int ni = 0; ni < 2; ++ni) {
    const int col = n0 + wc * 32 + ni * 16 + c;
    const float bb = bias[col];
    if (sel == 2) {
      const int mb = m0 + wr * 16 + g * 4;
      const int pidx = (mb & ~31) + ((mb >> 4) & 1) * 4 + ((mb >> 2) & 3) * 8;
      uint2 pk;
      const float v0 = acc[ni][0] + bb, v1 = acc[ni][1] + bb;
      const float v2 = acc[ni][2] + bb, v3 = acc[ni][3] + bb;
      pk.x = (unsigned)(unsigned short)bfr(v0) | ((unsigned)(unsigned short)bfr(v1) << 16);
      pk.y = (unsigned)(unsigned short)bfr(v2) | ((unsigned)(unsigned short)bfr(v3) << 16);
      *(uint2*)&VT[(size_t)col * N_TOK + pidx] = pk;
    } else {
      short* Ct = (sel == 0) ? QB : KB;
      const float qs = (sel == 0) ? QSC : 1.f;
      const int hh = col >> 5, dd = col & 31;
#pragma unroll
      for (int q = 0; q < 4; ++q) {
        const int m = m0 + wr * 16 + g * 4 + q;
        Ct[((size_t)hh * N_TOK + m) * 32 + dd] = bfr((acc[ni][q] + bb) * qs);
      }
    }
  }
}

// --------------- X -> bf16 hi/lo planes + row ||x||^2 (prologue only)
__global__ __launch_bounds__(256) void xsplit_k(const float* __restrict__ X,
    short* __restrict__ XH, short* __restrict__ XL, float* __restrict__ sq) {
  __shared__ float red[4];
  const int i = blockIdx.x, t = threadIdx.x;
  const size_t e = (size_t)i * CD + t;
  const float v = X[e];
  const unsigned ui = __float_as_uint(v);
  XH[e] = (short)(ui >> 16);
  const float hf = __uint_as_float(ui & 0xffff0000u);
  XL[e] = (short)(__float_as_uint(v - hf) >> 16);
  float s = v * v;
#pragma unroll
  for (int m = 1; m < 64; m <<= 1) s += __shfl_xor(s, m, 64);
  if ((t & 63) == 0) red[t >> 6] = s;
  __syncthreads();
  if (t == 0) sq[i] = red[0] + red[1] + red[2] + red[3];
}

// ---- Gram G = X X^T: LDS-staged (coalesced) from precomputed hi/lo planes
__global__ __launch_bounds__(256) void gemm_syr4_k(const short* __restrict__ XH,
    const short* __restrict__ XL, float* __restrict__ C) {
  __shared__ __align__(16) short AsH[64][40];
  __shared__ __align__(16) short AsL[64][40];
  __shared__ __align__(16) short BsH[64][40];
  __shared__ __align__(16) short BsL[64][40];
  int bid = blockIdx.x;
  int bi = (int)((sqrtf(8.f * (float)bid + 1.f) - 1.f) * 0.5f);
  while ((bi + 1) * (bi + 2) / 2 <= bid) ++bi;
  while (bi * (bi + 1) / 2 > bid) --bi;
  const int bj = bid - bi * (bi + 1) / 2;
  const int m0 = bi * 64, n0 = bj * 64;
  const int t = threadIdx.x;
  const int w = t >> 6, l = t & 63;
  const int g = l >> 4, c = l & 15;
  const int wr = w >> 1, wc = w & 1;
  const int sr = t >> 2, seg = t & 3;
  const size_t arow = (size_t)(m0 + sr) * CD + seg * 8;
  const size_t brow = (size_t)(n0 + sr) * CD + seg * 8;
  f32x4 acc[2][2] = {};
  for (int k0 = 0; k0 < CD; k0 += 32) {
    const short8v ah = *(const short8v*)&XH[arow + k0];
    const short8v al = *(const short8v*)&XL[arow + k0];
    const short8v bh = *(const short8v*)&XH[brow + k0];
    const short8v bl = *(const short8v*)&XL[brow + k0];
    __syncthreads();
    *(short8v*)&AsH[sr][seg * 8] = ah;
    *(short8v*)&AsL[sr][seg * 8] = al;
    *(short8v*)&BsH[sr][seg * 8] = bh;
    *(short8v*)&BsL[sr][seg * 8] = bl;
    __syncthreads();
    short8v afH[2], afL[2], bfH[2], bfL[2];
#pragma unroll
    for (int mi = 0; mi < 2; ++mi) {
      afH[mi] = *(const short8v*)&AsH[wr * 32 + mi * 16 + c][g * 8];
      afL[mi] = *(const short8v*)&AsL[wr * 32 + mi * 16 + c][g * 8];
    }
#pragma unroll
    for (int ni = 0; ni < 2; ++ni) {
      bfH[ni] = *(const short8v*)&BsH[wc * 32 + ni * 16 + c][g * 8];
      bfL[ni] = *(const short8v*)&BsL[wc * 32 + ni * 16 + c][g * 8];
    }
#pragma unroll
    for (int mi = 0; mi < 2; ++mi)
#pragma unroll
      for (int ni = 0; ni < 2; ++ni) {
        acc[mi][ni] = __builtin_amdgcn_mfma_f32_16x16x32_bf16(afH[mi], bfH[ni], acc[mi][ni], 0, 0, 0);
        acc[mi][ni] = __builtin_amdgcn_mfma_f32_16x16x32_bf16(afH[mi], bfL[ni], acc[mi][ni], 0, 0, 0);
        acc[mi][ni] = __builtin_amdgcn_mfma_f32_16x16x32_bf16(afL[mi], bfH[ni], acc[mi][ni], 0, 0, 0);
      }
  }
#pragma unroll
  for (int mi = 0; mi < 2; ++mi)
#pragma unroll
    for (int ni = 0; ni < 2; ++ni) {
      const int col = n0 + wc * 32 + ni * 16 + c;
#pragma unroll
      for (int q = 0; q < 4; ++q) {
        const int m = m0 + wr * 32 + mi * 16 + g * 4 + q;
        const float v = acc[mi][ni][q];
        C[(size_t)m * N_TOK + col] = v;
        C[(size_t)col * N_TOK + m] = v;
      }
    }
}

// ------------------- conv2 (8ch) -> writes gpT [8][N_TOK] * log2e directly
__global__ __launch_bounds__(256) void conv2_k(const float* __restrict__ t1,
    const float* __restrict__ w, const float* __restrict__ b,
    float* __restrict__ gpT) {
  __shared__ float ws3[9 * 8 * 132];
  const int t = threadIdx.x;
  for (int e = t; e < 9216; e += 256) {
    int r = e >> 10;
    int rem = e & 1023;
    int co = rem >> 7;
    int ci = rem & 127;
    ws3[(r * 8 + co) * 132 + ci] = w[((size_t)co * 128 + ci) * 9 + r];
  }
  __syncthreads();
  const int pix = blockIdx.x * 32 + (t >> 3);
  const int co = t & 7;
  const int y = pix / 56, x = pix - y * 56;
  float acc = b[co];
  for (int ky = 0; ky < 3; ++ky) {
    int yy = y + ky - 1;
    if (yy < 0 || yy >= 56) continue;
    for (int kx = 0; kx < 3; ++kx) {
      int xx = x + kx - 1;
      if (xx < 0 || xx >= 56) continue;
      const float4* tp = (const float4*)&t1[(size_t)(yy * 56 + xx) * 128];
      const float* wp = &ws3[((ky * 3 + kx) * 8 + co) * 132];
#pragma unroll
      for (int c4 = 0; c4 < 32; ++c4) {
        const float4 tv = tp[c4];
        const float4 wv = *(const float4*)&wp[c4 * 4];
        acc += tv.x * wv.x + tv.y * wv.y + tv.z * wv.z + tv.w * wv.w;
      }
    }
  }
  gpT[co * N_TOK + pix] = LOG2E / (1.f + expf(-acc));
}

// ---- top-16 NN + in-degree, v6: one wave/row, per-lane TOP-4 cache.
// Initial scan keeps a sorted 4-candidate list (loop-carried scalars ->
// register-resident). Per round: butterfly, winner promotes from cache.
// Divergent rescan only when one lane supplied 4 winners (~0.7% of rows).
// Bit-exact lex top_k (ties -> smaller j).
__global__ __launch_bounds__(64) void topk_k(const float* __restrict__ G,
    const float* __restrict__ sq, int* __restrict__ near) {
  const int i = blockIdx.x;
  const int t = threadIdx.x;            // lane 0..63
  const float sqi = sq[i];
  const float* __restrict__ Grow = G + (size_t)i * N_TOK;
  unsigned cv0 = 0xffffffffu, cv1 = 0xffffffffu, cv2 = 0xffffffffu, cv3 = 0xffffffffu;
  int ce0 = 0, ce1 = 0, ce2 = 0, ce3 = 0;
#pragma unroll
  for (int e = 0; e < 49; ++e) {
    const int j = t + (e << 6);         // 49*64 = 3136 exactly
    const unsigned v = f2mono((sqi - 2.f * Grow[j]) + sq[j]);
    const bool i0 = v < cv0, i1 = v < cv1, i2 = v < cv2, i3 = v < cv3;
    cv3 = i2 ? cv2 : (i3 ? v : cv3);  ce3 = i2 ? ce2 : (i3 ? e : ce3);
    cv2 = i1 ? cv1 : (i2 ? v : cv2);  ce2 = i1 ? ce1 : (i2 ? e : ce2);
    cv1 = i0 ? cv0 : (i1 ? v : cv1);  ce1 = i0 ? ce0 : (i1 ? e : ce1);
    cv0 = i0 ? v : cv0;               ce0 = i0 ? e : ce0;
  }
  unsigned long long killed = 0ull;
#pragma unroll 1
  for (int r = 0; r < 16; ++r) {
    const unsigned long long mine =
        ((unsigned long long)cv0 << 32) | (unsigned)(t + (ce0 << 6));
    unsigned long long best = mine;
#pragma unroll
    for (int m = 1; m < 64; m <<= 1) {
      const unsigned long long o = sx64(best, m);
      best = (o < best) ? o : best;
    }
    if (t == 0) atomicAdd(&near[(unsigned)(best & 0xffffffffu)], 1);
    if (mine == best && r < 15) {
      killed |= 1ull << ce0;
      cv0 = cv1; ce0 = ce1;
      cv1 = cv2; ce1 = ce2;
      cv2 = cv3; ce2 = ce3;
      cv3 = 0xffffffffu; ce3 = 0;
      if (cv0 == 0xffffffffu) {
        // rare refill: rescan excluding killed (exact)
#pragma unroll
        for (int e = 0; e < 49; ++e) {
          const int j = t + (e << 6);
          unsigned v = f2mono((sqi - 2.f * Grow[j]) + sq[j]);
          v = (((killed >> e) & 1ull) != 0ull) ? 0xffffffffu : v;
          const bool i0 = v < cv0, i1 = v < cv1, i2 = v < cv2, i3 = v < cv3;
          cv3 = i2 ? cv2 : (i3 ? v : cv3);  ce3 = i2 ? ce2 : (i3 ? e : ce3);
          cv2 = i1 ? cv1 : (i2 ? v : cv2);  ce2 = i1 ? ce1 : (i2 ? e : ce2);
          cv1 = i0 ? cv0 : (i1 ? v : cv1);  ce1 = i0 ? ce0 : (i1 ? e : ce1);
          cv0 = i0 ? v : cv0;               ce0 = i0 ? e : ce0;
        }
      }
    }
  }
}

// ------------- fused max(near) + qk_in = x + emb[ni(near)] (one row/block)
__global__ __launch_bounds__(256) void nearqk_k(const float* __restrict__ x,
    const int* __restrict__ near, const float* __restrict__ emb,
    float* __restrict__ qkin) {
  __shared__ int sm[4];
  const int i = blockIdx.x, t = threadIdx.x;
  int m = 0;
  for (int j = t; j < N_TOK; j += 256) m = max(m, near[j]);
#pragma unroll
  for (int s = 1; s < 64; s <<= 1) m = max(m, __shfl_xor(m, s, 64));
  if ((t & 63) == 0) sm[t >> 6] = m;
  __syncthreads();
  const int mv = max(max(sm[0], sm[1]), max(sm[2], sm[3]));
  const int ni = (int)((float)near[i] / (float)mv * 9.0f);
  qkin[(size_t)i * CD + t] = x[(size_t)i * CD + t] + emb[ni * CD + t];
}

// ---- flash attention v7: 64 queries/wave (4 groups), per-head Q/K layout
// grid (49, 8): block = 64 queries, 4 j-quarter waves; in-block combine.
__global__ __launch_bounds__(256) void attn_v7_k(const short* __restrict__ Qb,
    const short* __restrict__ Kb, const short* __restrict__ Vt,
    const float* __restrict__ gpT, float* __restrict__ O1) {
  __shared__ float o_l[4][64][36];
  __shared__ float ml_l[4][64][2];
  const int h = blockIdx.y;
  const int qb = blockIdx.x * 64;
  const int t = threadIdx.x;
  const int w = t >> 6, l = t & 63;
  const int g = l >> 4, c = l & 15;
  const size_t hR = (size_t)h * N_TOK;      // per-head row base (Q/K/gpT)
  const size_t hoff = (size_t)h * DH;       // VT d-row base
  short8v qf[4];
  float gpi[4];
#pragma unroll
  for (int gr = 0; gr < 4; ++gr) {
    qf[gr] = *(const short8v*)&Qb[(hR + qb + gr * 16 + c) * 32 + g * 8];
    gpi[gr] = gpT[hR + qb + gr * 16 + c];
  }
  const int jt0 = w ? (13 + 12 * (w - 1)) : 0;
  const int jt1 = jt0 + (w ? 12 : 13);
  float mr[4] = {-INFINITY, -INFINITY, -INFINITY, -INFINITY};
  float lp[4] = {0.f, 0.f, 0.f, 0.f};
  f32x4 oa[4][2] = {};
  const f32x4 zz = {0.f, 0.f, 0.f, 0.f};

#pragma unroll 1
  for (int jt = jt0; jt < jt1; ++jt) {
    const int j0 = jt * 64;
    short8v kf[4], vf[4];
    float4 gj[4];
#pragma unroll
    for (int sub = 0; sub < 4; ++sub)
      kf[sub] = *(const short8v*)&Kb[(hR + j0 + sub * 16 + c) * 32 + g * 8];
#pragma unroll
    for (int ch = 0; ch < 2; ++ch)
#pragma unroll
      for (int ds = 0; ds < 2; ++ds)
        vf[ch * 2 + ds] = *(const short8v*)&Vt[(hoff + ds * 16 + c) * (size_t)N_TOK + j0 + ch * 32 + g * 8];
#pragma unroll
    for (int sub = 0; sub < 4; ++sub)
      gj[sub] = *(const float4*)&gpT[hR + j0 + sub * 16 + g * 4];
#pragma unroll
    for (int gr = 0; gr < 4; ++gr) {
      f32x4 sacc[4];
#pragma unroll
      for (int sub = 0; sub < 4; ++sub)
        sacc[sub] = __builtin_amdgcn_mfma_f32_16x16x32_bf16(kf[sub], qf[gr], zz, 0, 0, 0);
      float sv[16];
#pragma unroll
      for (int sub = 0; sub < 4; ++sub) {
        sv[sub * 4 + 0] = sacc[sub][0] + fabsf(gpi[gr] - gj[sub].x);
        sv[sub * 4 + 1] = sacc[sub][1] + fabsf(gpi[gr] - gj[sub].y);
        sv[sub * 4 + 2] = sacc[sub][2] + fabsf(gpi[gr] - gj[sub].z);
        sv[sub * 4 + 3] = sacc[sub][3] + fabsf(gpi[gr] - gj[sub].w);
      }
      float a0 = fmaxf(sv[0], sv[1]),  a1 = fmaxf(sv[2], sv[3]);
      float a2 = fmaxf(sv[4], sv[5]),  a3 = fmaxf(sv[6], sv[7]);
      float a4 = fmaxf(sv[8], sv[9]),  a5 = fmaxf(sv[10], sv[11]);
      float a6 = fmaxf(sv[12], sv[13]), a7 = fmaxf(sv[14], sv[15]);
      const float mx = fmaxf(fmaxf(fmaxf(a0, a1), fmaxf(a2, a3)),
                             fmaxf(fmaxf(a4, a5), fmaxf(a6, a7)));
      if (!__all(mx - mr[gr] <= 11.f)) {
        float mn = mx;
        mn = fmaxf(mn, __shfl_xor(mn, 16, 64));
        mn = fmaxf(mn, __shfl_xor(mn, 32, 64));
        mn = fmaxf(mn, mr[gr]);
        const float sc = __builtin_amdgcn_exp2f(mr[gr] - mn);
        oa[gr][0][0] *= sc; oa[gr][0][1] *= sc; oa[gr][0][2] *= sc; oa[gr][0][3] *= sc;
        oa[gr][1][0] *= sc; oa[gr][1][1] *= sc; oa[gr][1][2] *= sc; oa[gr][1][3] *= sc;
        lp[gr] *= sc;
        mr[gr] = mn;
      }
      float p[16];
#pragma unroll
      for (int e = 0; e < 16; ++e) p[e] = __builtin_amdgcn_exp2f(sv[e] - mr[gr]);
      const float ps0 = (p[0] + p[1]) + (p[2] + p[3]);
      const float ps1 = (p[4] + p[5]) + (p[6] + p[7]);
      const float ps2 = (p[8] + p[9]) + (p[10] + p[11]);
      const float ps3 = (p[12] + p[13]) + (p[14] + p[15]);
      lp[gr] += (ps0 + ps1) + (ps2 + ps3);
      union { unsigned u[4]; short8v s; } pf0, pf1;
#pragma unroll
      for (int sub = 0; sub < 2; ++sub) {
        pf0.u[2 * sub + 0] = __builtin_amdgcn_perm(__float_as_uint(p[4 * sub + 1]),
                                                   __float_as_uint(p[4 * sub + 0]), 0x07060302u);
        pf0.u[2 * sub + 1] = __builtin_amdgcn_perm(__float_as_uint(p[4 * sub + 3]),
                                                   __float_as_uint(p[4 * sub + 2]), 0x07060302u);
        pf1.u[2 * sub + 0] = __builtin_amdgcn_perm(__float_as_uint(p[8 + 4 * sub + 1]),
                                                   __float_as_uint(p[8 + 4 * sub + 0]), 0x07060302u);
        pf1.u[2 * sub + 1] = __builtin_amdgcn_perm(__float_as_uint(p[8 + 4 * sub + 3]),
                                                   __float_as_uint(p[8 + 4 * sub + 2]), 0x07060302u);
      }
      oa[gr][0] = __builtin_amdgcn_mfma_f32_16x16x32_bf16(vf[0], pf0.s, oa[gr][0], 0, 0, 0);
      oa[gr][1] = __builtin_amdgcn_mfma_f32_16x16x32_bf16(vf[1], pf0.s, oa[gr][1], 0, 0, 0);
      oa[gr][0] = __builtin_amdgcn_mfma_f32_16x16x32_bf16(vf[2], pf1.s, oa[gr][0], 0, 0, 0);
      oa[gr][1] = __builtin_amdgcn_mfma_f32_16x16x32_bf16(vf[3], pf1.s, oa[gr][1], 0, 0, 0);
    }
  }
#pragma unroll
  for (int gr = 0; gr < 4; ++gr) {
    lp[gr] += __shfl_xor(lp[gr], 16, 64);
    lp[gr] += __shfl_xor(lp[gr], 32, 64);
#pragma unroll
    for (int ds = 0; ds < 2; ++ds)
      *(f32x4*)&o_l[w][gr * 16 + c][ds * 16 + g * 4] = oa[gr][ds];
    if (g == 0) {
      ml_l[w][gr * 16 + c][0] = mr[gr];
      ml_l[w][gr * 16 + c][1] = lp[gr];
    }
  }
  __syncthreads();
  const int q = t >> 2, d0 = (t & 3) * 8;
  const float M = fmaxf(fmaxf(ml_l[0][q][0], ml_l[1][q][0]),
                        fmaxf(ml_l[2][q][0], ml_l[3][q][0]));
  float den = 0.f;
  f32x4 numA = {0.f, 0.f, 0.f, 0.f};
  f32x4 numB = {0.f, 0.f, 0.f, 0.f};
#pragma unroll
  for (int sp = 0; sp < 4; ++sp) {
    const float wg = __builtin_amdgcn_exp2f(ml_l[sp][q][0] - M);
    den += wg * ml_l[sp][q][1];
    const f32x4 oA = *(const f32x4*)&o_l[sp][q][d0];
    const f32x4 oB = *(const f32x4*)&o_l[sp][q][d0 + 4];
    numA[0] += wg * oA[0]; numA[1] += wg * oA[1];
    numA[2] += wg * oA[2]; numA[3] += wg * oA[3];
    numB[0] += wg * oB[0]; numB[1] += wg * oB[1];
    numB[2] += wg * oB[2]; numB[3] += wg * oB[3];
  }
  const float inv = 1.f / den;
  f32x4 rA = {numA[0] * inv, numA[1] * inv, numA[2] * inv, numA[3] * inv};
  f32x4 rB = {numB[0] * inv, numB[1] * inv, numB[2] * inv, numB[3] * inv};
  *(f32x4*)&O1[(size_t)(qb + q) * CD + hoff + d0] = rA;
  *(f32x4*)&O1[(size_t)(qb + q) * CD + hoff + d0 + 4] = rB;
}

// ------ LayerNorm (+residual); SPLIT=1 also emits XH/XL planes + row-sq
template <int SPLIT>
__global__ __launch_bounds__(256) void ln_k(const float* __restrict__ xin,
    const float* __restrict__ add, const float* __restrict__ g,
    const float* __restrict__ b, float* __restrict__ xout,
    float* __restrict__ sqout, short* __restrict__ XH, short* __restrict__ XL) {
  __shared__ float red1[4];
  __shared__ float red2[4];
  const int i = blockIdx.x, t = threadIdx.x;
  const size_t e = (size_t)i * CD + t;
  float v = xin[e];
  if (add) v += add[e];
  float s = v;
#pragma unroll
  for (int m = 1; m < 64; m <<= 1) s += __shfl_xor(s, m, 64);
  if ((t & 63) == 0) red1[t >> 6] = s;
  __syncthreads();
  const float mean = (red1[0] + red1[1] + red1[2] + red1[3]) * (1.f / 256.f);
  const float d = v - mean;
  float s2 = d * d;
#pragma unroll
  for (int m = 1; m < 64; m <<= 1) s2 += __shfl_xor(s2, m, 64);
  if ((t & 63) == 0) red2[t >> 6] = s2;
  __syncthreads();
  const float var = (red2[0] + red2[1] + red2[2] + red2[3]) * (1.f / 256.f);
  const float xo = d * rsqrtf(var + 1e-5f) * g[t] + b[t];
  xout[e] = xo;
  if (SPLIT) {
    const unsigned ui = __float_as_uint(xo);
    XH[e] = (short)(ui >> 16);
    const float hf = __uint_as_float(ui & 0xffff0000u);
    XL[e] = (short)(__float_as_uint(xo - hf) >> 16);
    float s3 = xo * xo;
#pragma unroll
    for (int m = 1; m < 64; m <<= 1) s3 += __shfl_xor(s3, m, 64);
    __syncthreads();
    if ((t & 63) == 0) red1[t >> 6] = s3;
    __syncthreads();
    if (t == 0) sqout[i] = red1[0] + red1[1] + red1[2] + red1[3];
  }
}

// ---------------------------------------------------------------- launch
extern "C" void kernel_launch(void* const* d_in, const int* in_sizes, int n_in,
                              void* d_out, int out_size, void* d_ws, size_t ws_size,
                              hipStream_t stream) {
  const float* src  = (const float*)d_in[0];
  const float* c1w  = (const float*)d_in[1];
  const float* c1b  = (const float*)d_in[2];
  const float* c2w  = (const float*)d_in[3];
  const float* c2b  = (const float*)d_in[4];
  const float* nemb = (const float*)d_in[5];
  const float* Wq   = (const float*)d_in[6];
  const float* bq   = (const float*)d_in[7];
  const float* Wk   = (const float*)d_in[8];
  const float* bk   = (const float*)d_in[9];
  const float* Wv   = (const float*)d_in[10];
  const float* bv   = (const float*)d_in[11];
  const float* Wo   = (const float*)d_in[12];
  const float* bo   = (const float*)d_in[13];
  const float* W1   = (const float*)d_in[14];
  const float* b1   = (const float*)d_in[15];
  const float* W2   = (const float*)d_in[16];
  const float* b2   = (const float*)d_in[17];
  const float* ln1g = (const float*)d_in[18];
  const float* ln1b = (const float*)d_in[19];
  const float* ln2g = (const float*)d_in[20];
  const float* ln2b = (const float*)d_in[21];
  const float* ng   = (const float*)d_in[22];
  const float* nb   = (const float*)d_in[23];

  float* ws = (float*)d_ws;
  const size_t NC = (size_t)N_TOK * CD;          // 802816
  float* X    = ws;
  float* QKIN = X + NC;
  float* O1   = QKIN + NC;
  float* TMP  = O1 + NC;
  float* FF1  = TMP + NC;                        // 3136*1024
  float* G    = FF1 + (size_t)N_TOK * DFFD;      // 3136*3136 (also conv1 partials)
  float* T1   = G + (size_t)N_TOK * N_TOK;       // 3136*128
  float* GPT  = T1 + (size_t)N_TOK * 128;        // 8*3136
  float* SQF  = GPT + (size_t)N_TOK * NHD;       // 3136
  short* QB16 = (short*)(SQF + N_TOK);
  short* KB16 = QB16 + NC;
  short* VT16 = KB16 + NC;
  short* XH   = VT16 + NC;                       // bf16 hi plane
  short* XL   = XH + NC;                         // bf16 lo plane
  float* WTC  = (float*)(XL + NC);               // 9*128*256 = 294912
  int*   NEAR = (int*)(WTC + 294912);            // 4 * 3136 ints

  // tokens + conv positional encoder (direct conv, no im2col)
  transpose_k<<<dim3(98, 8), 256, 0, stream>>>(src, X, 256, N_TOK);
  wtr_k<<<1152, 256, 0, stream>>>(c1w, WTC);
  conv1_k<<<dim3(2, 98, 3), 256, 0, stream>>>(X, WTC, G);
  convred_k<<<1568, 256, 0, stream>>>(G, c1b, T1);
  conv2_k<<<98, 256, 0, stream>>>(T1, c2w, c2b, GPT);
  xsplit_k<<<N_TOK, 256, 0, stream>>>(X, XH, XL, SQF);
  (void)hipMemsetAsync(NEAR, 0, 4 * N_TOK * sizeof(int), stream);

  for (int l = 0; l < 4; ++l) {
    int* NEAR_l = NEAR + l * N_TOK;
    // ---- kNN graph -> near counts (hi/lo bf16 MFMA Gram, LDS-staged)
    gemm_syr4_k<<<1225, 256, 0, stream>>>(XH, XL, G);
    topk_k<<<N_TOK, 64, 0, stream>>>(G, SQF, NEAR_l);
    nearqk_k<<<N_TOK, 256, 0, stream>>>(X, NEAR_l, nemb, QKIN);
    // ---- fused Q/K/V projections (32-row tiles, per-head Q/K layout)
    proj32_k<<<dim3(4, 98, 3), 256, 0, stream>>>(QKIN, X,
        Wq + (size_t)l * 65536, Wk + (size_t)l * 65536, Wv + (size_t)l * 65536,
        bq + l * 256, bk + l * 256, bv + l * 256, QB16, KB16, VT16);
    // ---- attention (64 q/wave, halved load count, in-block combine)
    attn_v7_k<<<dim3(49, 8), 256, 0, stream>>>(QB16, KB16, VT16, GPT, O1);
    gemm32_k<0><<<dim3(4, 98), 256, 0, stream>>>(O1, Wo + (size_t)l * 65536, bo + l * 256, TMP, 256, 256);
    ln_k<0><<<N_TOK, 256, 0, stream>>>(X, TMP, ln1g + l * 256, ln1b + l * 256, X, nullptr, nullptr, nullptr);
    // ---- FFN
    gemm32_k<1><<<dim3(16, 98), 256, 0, stream>>>(X, W1 + (size_t)l * 262144, b1 + l * 1024, FF1, 1024, 256);
    gemm32_k<0><<<dim3(4, 98), 256, 0, stream>>>(FF1, W2 + (size_t)l * 262144, b2 + l * 256, TMP, 256, 1024);
    // ln2 fused with X hi/lo split + row-sq (feeds next layer's Gram/topk)
    ln_k<1><<<N_TOK, 256, 0, stream>>>(X, TMP, ln2g + l * 256, ln2b + l * 256, X, SQF, XH, XL);
  }
  // final LN + transpose to [1,C,H,W]
  ln_k<0><<<N_TOK, 256, 0, stream>>>(X, nullptr, ng, nb, TMP, nullptr, nullptr, nullptr);
  transpose_k<<<dim3(8, 98), 256, 0, stream>>>(TMP, (float*)d_out, N_TOK, 256);
}

// Round 19
// 641.119 us; speedup vs baseline: 2.0955x; 1.0249x over previous
//
#include <hip/hip_runtime.h>
#include <math.h>

#define N_TOK 3136
#define CD    256
#define NHD   8
#define DH    32
#define DFFD  1024
#define SCALE 0.17677669529663687f  /* 32^-0.5 */
#define LOG2E 1.4426950408889634f
#define QSC   (SCALE * LOG2E)

typedef __attribute__((ext_vector_type(8))) short short8v;
typedef __attribute__((ext_vector_type(4))) float f32x4;

// ---------------------------------------------------------------- utils
__device__ __forceinline__ unsigned long long sx64(unsigned long long v, int m) {
  unsigned lo = (unsigned)__shfl_xor((int)(unsigned)(v & 0xffffffffull), m, 64);
  unsigned hi = (unsigned)__shfl_xor((int)(unsigned)(v >> 32), m, 64);
  return ((unsigned long long)hi << 32) | lo;
}

__device__ __forceinline__ unsigned f2mono(float v) {
  unsigned b = __float_as_uint(v);
  return (b & 0x80000000u) ? ~b : (b | 0x80000000u);
}

// fp32 -> bf16 round-to-nearest-even
__device__ __forceinline__ short bfr(float f) {
  unsigned u = __float_as_uint(f);
  unsigned r = (u + 0x7fffu + ((u >> 16) & 1u)) >> 16;
  return (short)r;
}

__device__ __forceinline__ short8v cvt8(float4 a, float4 b) {
  short8v r;
  r[0] = bfr(a.x); r[1] = bfr(a.y); r[2] = bfr(a.z); r[3] = bfr(a.w);
  r[4] = bfr(b.x); r[5] = bfr(b.y); r[6] = bfr(b.z); r[7] = bfr(b.w);
  return r;
}

// ------------------------------------------------- transpose (32x32 tiles)
__global__ __launch_bounds__(256) void transpose_k(const float* __restrict__ in,
    float* __restrict__ out, int R, int C) {
  __shared__ float ls[32][33];
  const int c0 = blockIdx.x * 32, r0 = blockIdx.y * 32;
  const int tx = threadIdx.x & 31, ty = threadIdx.x >> 5;
#pragma unroll
  for (int j = 0; j < 4; ++j) {
    int r = ty + j * 8;
    ls[r][tx] = in[(size_t)(r0 + r) * C + c0 + tx];
  }
  __syncthreads();
#pragma unroll
  for (int j = 0; j < 4; ++j) {
    int cc = ty + j * 8;
    out[(size_t)(c0 + cc) * R + r0 + tx] = ls[tx][cc];
  }
}

// -------------------- conv1 weight transpose: WT[r][co][ci] = w[co][ci][r]
__global__ __launch_bounds__(256) void wtr_k(const float* __restrict__ w,
                                             float* __restrict__ wt) {
  const int e = blockIdx.x * 256 + threadIdx.x;   // < 9*128*256 = 294912
  const int r = e >> 15;
  const int rem = e & 32767;
  const int co = rem >> 8, ci = rem & 255;
  wt[e] = w[((size_t)co * 256 + ci) * 9 + r];
}

// -------- conv1 as direct tap-GEMM: grid (2, 98, 3), z = ky; 32-pixel tiles
__global__ __launch_bounds__(256) void conv1_k(const float* __restrict__ X,
    const float* __restrict__ WT, float* __restrict__ P) {
  __shared__ __align__(16) short As[32][40];
  __shared__ __align__(16) short Bs[64][40];
  const int n0 = blockIdx.x * 64;
  const int m0 = blockIdx.y * 32;
  const int ky = blockIdx.z;
  const int t = threadIdx.x;
  const int w = t >> 6, l = t & 63;
  const int g = l >> 4, c = l & 15;
  const int wr = w >> 1, wc = w & 1;
  const int sr = t >> 2, seg = t & 3;
  const int p = m0 + (sr & 31);
  const int y = p / 56, x = p - y * 56;
  const int yy = y + ky - 1;
  f32x4 acc[2] = {};
  for (int kx = 0; kx < 3; ++kx) {
    const int xx = x + kx - 1;
    const bool valid = (t < 128) && ((unsigned)yy < 56u) && ((unsigned)xx < 56u);
    const float* Ap = X + (size_t)(yy * 56 + xx) * CD + seg * 8;
    const float* Bp = WT + ((size_t)(ky * 3 + kx) * 128 + n0 + sr) * CD + seg * 8;
    for (int k0 = 0; k0 < CD; k0 += 32) {
      float4 a1 = make_float4(0.f, 0.f, 0.f, 0.f), a2 = a1;
      if (valid) { a1 = *(const float4*)(Ap + k0); a2 = *(const float4*)(Ap + k0 + 4); }
      const float4 b1 = *(const float4*)(Bp + k0);
      const float4 b2 = *(const float4*)(Bp + k0 + 4);
      __syncthreads();
      if (t < 128) *(short8v*)&As[sr][seg * 8] = cvt8(a1, a2);
      *(short8v*)&Bs[sr][seg * 8] = cvt8(b1, b2);
      __syncthreads();
      const short8v af = *(const short8v*)&As[wr * 16 + c][g * 8];
      const short8v bf0 = *(const short8v*)&Bs[wc * 32 + c][g * 8];
      const short8v bf1 = *(const short8v*)&Bs[wc * 32 + 16 + c][g * 8];
      acc[0] = __builtin_amdgcn_mfma_f32_16x16x32_bf16(af, bf0, acc[0], 0, 0, 0);
      acc[1] = __builtin_amdgcn_mfma_f32_16x16x32_bf16(af, bf1, acc[1], 0, 0, 0);
    }
  }
#pragma unroll
  for (int ni = 0; ni < 2; ++ni) {
    const int col = n0 + wc * 32 + ni * 16 + c;
#pragma unroll
    for (int q = 0; q < 4; ++q) {
      const int m = m0 + wr * 16 + g * 4 + q;
      P[((size_t)ky * N_TOK + m) * 128 + col] = acc[ni][q];
    }
  }
}

// ----------------------- reduce conv1 tap partials + bias + relu -> T1
__global__ __launch_bounds__(256) void convred_k(const float* __restrict__ P,
    const float* __restrict__ b, float* __restrict__ T1) {
  const int e = blockIdx.x * 256 + threadIdx.x;   // < 3136*128
  const float v = P[e] + P[401408 + e] + P[802816 + e] + b[e & 127];
  T1[e] = fmaxf(v, 0.f);
}

// ------------------ 32x64-tile bf16 MFMA GEMM NT (fp32 in, fp32 out)
template <int RELU>
__global__ __launch_bounds__(256) void gemm32_k(const float* __restrict__ A,
    const float* __restrict__ B, const float* __restrict__ bias,
    float* __restrict__ C, int N, int K) {
  __shared__ __align__(16) short As[32][40];
  __shared__ __align__(16) short Bs[64][40];
  const int n0 = blockIdx.x * 64;
  const int m0 = blockIdx.y * 32;
  const int t = threadIdx.x;
  const int w = t >> 6, l = t & 63;
  const int g = l >> 4, c = l & 15;
  const int wr = w >> 1, wc = w & 1;
  const int sr = t >> 2, seg = t & 3;
  const float* Ap = A + (size_t)(m0 + (sr & 31)) * K + seg * 8;
  const float* Bp = B + (size_t)(n0 + sr) * K + seg * 8;
  f32x4 acc[2] = {};
  for (int k0 = 0; k0 < K; k0 += 32) {
    float4 a1 = make_float4(0.f, 0.f, 0.f, 0.f), a2 = a1;
    if (t < 128) { a1 = *(const float4*)(Ap + k0); a2 = *(const float4*)(Ap + k0 + 4); }
    const float4 b1 = *(const float4*)(Bp + k0);
    const float4 b2 = *(const float4*)(Bp + k0 + 4);
    __syncthreads();
    if (t < 128) *(short8v*)&As[sr][seg * 8] = cvt8(a1, a2);
    *(short8v*)&Bs[sr][seg * 8] = cvt8(b1, b2);
    __syncthreads();
    const short8v af = *(const short8v*)&As[wr * 16 + c][g * 8];
    const short8v bf0 = *(const short8v*)&Bs[wc * 32 + c][g * 8];
    const short8v bf1 = *(const short8v*)&Bs[wc * 32 + 16 + c][g * 8];
    acc[0] = __builtin_amdgcn_mfma_f32_16x16x32_bf16(af, bf0, acc[0], 0, 0, 0);
    acc[1] = __builtin_amdgcn_mfma_f32_16x16x32_bf16(af, bf1, acc[1], 0, 0, 0);
  }
#pragma unroll
  for (int ni = 0; ni < 2; ++ni) {
    const int col = n0 + wc * 32 + ni * 16 + c;
    const float bb = bias ? bias[col] : 0.f;
#pragma unroll
    for (int q = 0; q < 4; ++q) {
      const int m = m0 + wr * 16 + g * 4 + q;
      float v = acc[ni][q] + bb;
      if (RELU) v = fmaxf(v, 0.f);
      C[(size_t)m * N + col] = v;
    }
  }
}

// ---------------- fused Q/K/V projections, 32-row tiles, bf16 outputs
// Q/K written per-head contiguous: [h][tok][32]. V^T chunk-swizzled [d][tok].
__global__ __launch_bounds__(256) void proj32_k(const float* __restrict__ QKIN,
    const float* __restrict__ X, const float* __restrict__ Wq,
    const float* __restrict__ Wk, const float* __restrict__ Wv,
    const float* __restrict__ bq, const float* __restrict__ bk,
    const float* __restrict__ bv, short* __restrict__ QB,
    short* __restrict__ KB, short* __restrict__ VT) {
  __shared__ __align__(16) short As[32][40];
  __shared__ __align__(16) short Bs[64][40];
  const int sel = blockIdx.z;
  const int n0 = blockIdx.x * 64;
  const int m0 = blockIdx.y * 32;
  const float* A = (sel < 2) ? QKIN : X;
  const float* B = (sel == 0) ? Wq : (sel == 1) ? Wk : Wv;
  const float* bias = (sel == 0) ? bq : (sel == 1) ? bk : bv;
  const int t = threadIdx.x;
  const int w = t >> 6, l = t & 63;
  const int g = l >> 4, c = l & 15;
  const int wr = w >> 1, wc = w & 1;
  const int sr = t >> 2, seg = t & 3;
  const float* Ap = A + (size_t)(m0 + (sr & 31)) * CD + seg * 8;
  const float* Bp = B + (size_t)(n0 + sr) * CD + seg * 8;
  f32x4 acc[2] = {};
  for (int k0 = 0; k0 < CD; k0 += 32) {
    float4 a1 = make_float4(0.f, 0.f, 0.f, 0.f), a2 = a1;
    if (t < 128) { a1 = *(const float4*)(Ap + k0); a2 = *(const float4*)(Ap + k0 + 4); }
    const float4 b1 = *(const float4*)(Bp + k0);
    const float4 b2 = *(const float4*)(Bp + k0 + 4);
    __syncthreads();
    if (t < 128) *(short8v*)&As[sr][seg * 8] = cvt8(a1, a2);
    *(short8v*)&Bs[sr][seg * 8] = cvt8(b1, b2);
    __syncthreads();
    const short8v af = *(const short8v*)&As[wr * 16 + c][g * 8];
    const short8v bf0 = *(const short8v*)&Bs[wc * 32 + c][g * 8];
    const short8v bf1 = *(const short8v*)&Bs[wc * 32 + 16 + c][g * 8];
    acc[0] = __builtin_amdgcn_mfma_f32_16x16x32_bf16(af, bf0, acc[0], 0, 0, 0);
    acc[1] = __builtin_amdgcn_mfma_f32_16x16x32_bf16(af, bf1, acc[1], 0, 0, 0);
  }
#pragma unroll
  for (int ni = 0; ni < 2; ++ni) {
    const int col = n0 + wc * 32 + ni * 16 + c;
    const float bb = bias[col];
    if (sel == 2) {
      const int mb = m0 + wr * 16 + g * 4;
      const int pidx = (mb & ~31) + ((mb >> 4) & 1) * 4 + ((mb >> 2) & 3) * 8;
      uint2 pk;
      const float v0 = acc[ni][0] + bb, v1 = acc[ni][1] + bb;
      const float v2 = acc[ni][2] + bb, v3 = acc[ni][3] + bb;
      pk.x = (unsigned)(unsigned short)bfr(v0) | ((unsigned)(unsigned short)bfr(v1) << 16);
      pk.y = (unsigned)(unsigned short)bfr(v2) | ((unsigned)(unsigned short)bfr(v3) << 16);
      *(uint2*)&VT[(size_t)col * N_TOK + pidx] = pk;
    } else {
      short* Ct = (sel == 0) ? QB : KB;
      const float qs = (sel == 0) ? QSC : 1.f;
      const int hh = col >> 5, dd = col & 31;
#pragma unroll
      for (int q = 0; q < 4; ++q) {
        const int m = m0 + wr * 16 + g * 4 + q;
        Ct[((size_t)hh * N_TOK + m) * 32 + dd] = bfr((acc[ni][q] + bb) * qs);
      }
    }
  }
}

// --------------- X -> bf16 hi/lo planes + row ||x||^2 (prologue only)
__global__ __launch_bounds__(256) void xsplit_k(const float* __restrict__ X,
    short* __restrict__ XH, short* __restrict__ XL, float* __restrict__ sq) {
  __shared__ float red[4];
  const int i = blockIdx.x, t = threadIdx.x;
  const size_t e = (size_t)i * CD + t;
  const float v = X[e];
  const unsigned ui = __float_as_uint(v);
  XH[e] = (short)(ui >> 16);
  const float hf = __uint_as_float(ui & 0xffff0000u);
  XL[e] = (short)(__float_as_uint(v - hf) >> 16);
  float s = v * v;
#pragma unroll
  for (int m = 1; m < 64; m <<= 1) s += __shfl_xor(s, m, 64);
  if ((t & 63) == 0) red[t >> 6] = s;
  __syncthreads();
  if (t == 0) sq[i] = red[0] + red[1] + red[2] + red[3];
}

// ---- Gram, key-fused: computes d2 mono-keys for BOTH mirror entries in
// the epilogue and stores u32 keys (topk consumes keys directly).
// d2(i,j) = (sq[i] - 2v) + sq[j], matching per-row fp32 order bit-exactly.
__global__ __launch_bounds__(256) void gemm_syr4_k(const short* __restrict__ XH,
    const short* __restrict__ XL, const float* __restrict__ SQ,
    unsigned* __restrict__ Ck) {
  __shared__ __align__(16) short AsH[64][40];
  __shared__ __align__(16) short AsL[64][40];
  __shared__ __align__(16) short BsH[64][40];
  __shared__ __align__(16) short BsL[64][40];
  int bid = blockIdx.x;
  int bi = (int)((sqrtf(8.f * (float)bid + 1.f) - 1.f) * 0.5f);
  while ((bi + 1) * (bi + 2) / 2 <= bid) ++bi;
  while (bi * (bi + 1) / 2 > bid) --bi;
  const int bj = bid - bi * (bi + 1) / 2;
  const int m0 = bi * 64, n0 = bj * 64;
  const int t = threadIdx.x;
  const int w = t >> 6, l = t & 63;
  const int g = l >> 4, c = l & 15;
  const int wr = w >> 1, wc = w & 1;
  const int sr = t >> 2, seg = t & 3;
  const size_t arow = (size_t)(m0 + sr) * CD + seg * 8;
  const size_t brow = (size_t)(n0 + sr) * CD + seg * 8;
  f32x4 acc[2][2] = {};
  for (int k0 = 0; k0 < CD; k0 += 32) {
    const short8v ah = *(const short8v*)&XH[arow + k0];
    const short8v al = *(const short8v*)&XL[arow + k0];
    const short8v bh = *(const short8v*)&XH[brow + k0];
    const short8v bl = *(const short8v*)&XL[brow + k0];
    __syncthreads();
    *(short8v*)&AsH[sr][seg * 8] = ah;
    *(short8v*)&AsL[sr][seg * 8] = al;
    *(short8v*)&BsH[sr][seg * 8] = bh;
    *(short8v*)&BsL[sr][seg * 8] = bl;
    __syncthreads();
    short8v afH[2], afL[2], bfH[2], bfL[2];
#pragma unroll
    for (int mi = 0; mi < 2; ++mi) {
      afH[mi] = *(const short8v*)&AsH[wr * 32 + mi * 16 + c][g * 8];
      afL[mi] = *(const short8v*)&AsL[wr * 32 + mi * 16 + c][g * 8];
    }
#pragma unroll
    for (int ni = 0; ni < 2; ++ni) {
      bfH[ni] = *(const short8v*)&BsH[wc * 32 + ni * 16 + c][g * 8];
      bfL[ni] = *(const short8v*)&BsL[wc * 32 + ni * 16 + c][g * 8];
    }
#pragma unroll
    for (int mi = 0; mi < 2; ++mi)
#pragma unroll
      for (int ni = 0; ni < 2; ++ni) {
        acc[mi][ni] = __builtin_amdgcn_mfma_f32_16x16x32_bf16(afH[mi], bfH[ni], acc[mi][ni], 0, 0, 0);
        acc[mi][ni] = __builtin_amdgcn_mfma_f32_16x16x32_bf16(afH[mi], bfL[ni], acc[mi][ni], 0, 0, 0);
        acc[mi][ni] = __builtin_amdgcn_mfma_f32_16x16x32_bf16(afL[mi], bfH[ni], acc[mi][ni], 0, 0, 0);
      }
  }
#pragma unroll
  for (int mi = 0; mi < 2; ++mi)
#pragma unroll
    for (int ni = 0; ni < 2; ++ni) {
      const int col = n0 + wc * 32 + ni * 16 + c;
      const float sqc = SQ[col];
#pragma unroll
      for (int q = 0; q < 4; ++q) {
        const int m = m0 + wr * 32 + mi * 16 + g * 4 + q;
        const float v = acc[mi][ni][q];
        const float sqm = SQ[m];
        Ck[(size_t)m * N_TOK + col] = f2mono((sqm - 2.f * v) + sqc);
        Ck[(size_t)col * N_TOK + m] = f2mono((sqc - 2.f * v) + sqm);
      }
    }
}

// ------------------- conv2 (8ch) -> writes gpT [8][N_TOK] * log2e directly
__global__ __launch_bounds__(256) void conv2_k(const float* __restrict__ t1,
    const float* __restrict__ w, const float* __restrict__ b,
    float* __restrict__ gpT) {
  __shared__ float ws3[9 * 8 * 132];
  const int t = threadIdx.x;
  for (int e = t; e < 9216; e += 256) {
    int r = e >> 10;
    int rem = e & 1023;
    int co = rem >> 7;
    int ci = rem & 127;
    ws3[(r * 8 + co) * 132 + ci] = w[((size_t)co * 128 + ci) * 9 + r];
  }
  __syncthreads();
  const int pix = blockIdx.x * 32 + (t >> 3);
  const int co = t & 7;
  const int y = pix / 56, x = pix - y * 56;
  float acc = b[co];
  for (int ky = 0; ky < 3; ++ky) {
    int yy = y + ky - 1;
    if (yy < 0 || yy >= 56) continue;
    for (int kx = 0; kx < 3; ++kx) {
      int xx = x + kx - 1;
      if (xx < 0 || xx >= 56) continue;
      const float4* tp = (const float4*)&t1[(size_t)(yy * 56 + xx) * 128];
      const float* wp = &ws3[((ky * 3 + kx) * 8 + co) * 132];
#pragma unroll
      for (int c4 = 0; c4 < 32; ++c4) {
        const float4 tv = tp[c4];
        const float4 wv = *(const float4*)&wp[c4 * 4];
        acc += tv.x * wv.x + tv.y * wv.y + tv.z * wv.z + tv.w * wv.w;
      }
    }
  }
  gpT[co * N_TOK + pix] = LOG2E / (1.f + expf(-acc));
}

// ---- top-16 NN + in-degree, v7: one wave/row, per-lane TOP-4 cache over
// PRECOMPUTED mono keys (u32 loads only in the scan). Per round: butterfly,
// winner promotes from cache; rare rescan when one lane supplied 4 winners.
// Bit-exact lex top_k (ties -> smaller j).
__global__ __launch_bounds__(64) void topk_k(const unsigned* __restrict__ Gk,
    int* __restrict__ near) {
  const int i = blockIdx.x;
  const int t = threadIdx.x;            // lane 0..63
  const unsigned* __restrict__ Krow = Gk + (size_t)i * N_TOK;
  unsigned cv0 = 0xffffffffu, cv1 = 0xffffffffu, cv2 = 0xffffffffu, cv3 = 0xffffffffu;
  int ce0 = 0, ce1 = 0, ce2 = 0, ce3 = 0;
#pragma unroll
  for (int e = 0; e < 49; ++e) {
    const unsigned v = Krow[t + (e << 6)];    // 49*64 = 3136 exactly
    const bool i0 = v < cv0, i1 = v < cv1, i2 = v < cv2, i3 = v < cv3;
    cv3 = i2 ? cv2 : (i3 ? v : cv3);  ce3 = i2 ? ce2 : (i3 ? e : ce3);
    cv2 = i1 ? cv1 : (i2 ? v : cv2);  ce2 = i1 ? ce1 : (i2 ? e : ce2);
    cv1 = i0 ? cv0 : (i1 ? v : cv1);  ce1 = i0 ? ce0 : (i1 ? e : ce1);
    cv0 = i0 ? v : cv0;               ce0 = i0 ? e : ce0;
  }
  unsigned long long killed = 0ull;
#pragma unroll 1
  for (int r = 0; r < 16; ++r) {
    const unsigned long long mine =
        ((unsigned long long)cv0 << 32) | (unsigned)(t + (ce0 << 6));
    unsigned long long best = mine;
#pragma unroll
    for (int m = 1; m < 64; m <<= 1) {
      const unsigned long long o = sx64(best, m);
      best = (o < best) ? o : best;
    }
    if (t == 0) atomicAdd(&near[(unsigned)(best & 0xffffffffu)], 1);
    if (mine == best && r < 15) {
      killed |= 1ull << ce0;
      cv0 = cv1; ce0 = ce1;
      cv1 = cv2; ce1 = ce2;
      cv2 = cv3; ce2 = ce3;
      cv3 = 0xffffffffu; ce3 = 0;
      if (cv0 == 0xffffffffu) {
        // rare refill: rescan excluding killed (exact)
#pragma unroll
        for (int e = 0; e < 49; ++e) {
          unsigned v = Krow[t + (e << 6)];
          v = (((killed >> e) & 1ull) != 0ull) ? 0xffffffffu : v;
          const bool i0 = v < cv0, i1 = v < cv1, i2 = v < cv2, i3 = v < cv3;
          cv3 = i2 ? cv2 : (i3 ? v : cv3);  ce3 = i2 ? ce2 : (i3 ? e : ce3);
          cv2 = i1 ? cv1 : (i2 ? v : cv2);  ce2 = i1 ? ce1 : (i2 ? e : ce2);
          cv1 = i0 ? cv0 : (i1 ? v : cv1);  ce1 = i0 ? ce0 : (i1 ? e : ce1);
          cv0 = i0 ? v : cv0;               ce0 = i0 ? e : ce0;
        }
      }
    }
  }
}

// ------------- fused max(near) + qk_in = x + emb[ni(near)] (one row/block)
__global__ __launch_bounds__(256) void nearqk_k(const float* __restrict__ x,
    const int* __restrict__ near, const float* __restrict__ emb,
    float* __restrict__ qkin) {
  __shared__ int sm[4];
  const int i = blockIdx.x, t = threadIdx.x;
  int m = 0;
  for (int j = t; j < N_TOK; j += 256) m = max(m, near[j]);
#pragma unroll
  for (int s = 1; s < 64; s <<= 1) m = max(m, __shfl_xor(m, s, 64));
  if ((t & 63) == 0) sm[t >> 6] = m;
  __syncthreads();
  const int mv = max(max(sm[0], sm[1]), max(sm[2], sm[3]));
  const int ni = (int)((float)near[i] / (float)mv * 9.0f);
  qkin[(size_t)i * CD + t] = x[(size_t)i * CD + t] + emb[ni * CD + t];
}

// ---- flash attention v8: 8 waves/block (512 thr), 64 queries/wave,
// j-eighths per wave; per-head Q/K layout; in-block 8-way combine.
__global__ __launch_bounds__(512) void attn_v8_k(const short* __restrict__ Qb,
    const short* __restrict__ Kb, const short* __restrict__ Vt,
    const float* __restrict__ gpT, float* __restrict__ O1) {
  __shared__ float o_l[8][64][36];
  __shared__ float ml_l[8][64][2];
  const int h = blockIdx.y;
  const int qb = blockIdx.x * 64;
  const int t = threadIdx.x;
  const int w = t >> 6, l = t & 63;
  const int g = l >> 4, c = l & 15;
  const size_t hR = (size_t)h * N_TOK;      // per-head row base (Q/K/gpT)
  const size_t hoff = (size_t)h * DH;       // VT d-row base
  short8v qf[4];
  float gpi[4];
#pragma unroll
  for (int gr = 0; gr < 4; ++gr) {
    qf[gr] = *(const short8v*)&Qb[(hR + qb + gr * 16 + c) * 32 + g * 8];
    gpi[gr] = gpT[hR + qb + gr * 16 + c];
  }
  const int jt0 = w ? (7 + 6 * (w - 1)) : 0;   // {7,6,6,6,6,6,6,6} = 49
  const int jt1 = jt0 + (w ? 6 : 7);
  float mr[4] = {-INFINITY, -INFINITY, -INFINITY, -INFINITY};
  float lp[4] = {0.f, 0.f, 0.f, 0.f};
  f32x4 oa[4][2] = {};
  const f32x4 zz = {0.f, 0.f, 0.f, 0.f};

#pragma unroll 1
  for (int jt = jt0; jt < jt1; ++jt) {
    const int j0 = jt * 64;
    short8v kf[4], vf[4];
    float4 gj[4];
#pragma unroll
    for (int sub = 0; sub < 4; ++sub)
      kf[sub] = *(const short8v*)&Kb[(hR + j0 + sub * 16 + c) * 32 + g * 8];
#pragma unroll
    for (int ch = 0; ch < 2; ++ch)
#pragma unroll
      for (int ds = 0; ds < 2; ++ds)
        vf[ch * 2 + ds] = *(const short8v*)&Vt[(hoff + ds * 16 + c) * (size_t)N_TOK + j0 + ch * 32 + g * 8];
#pragma unroll
    for (int sub = 0; sub < 4; ++sub)
      gj[sub] = *(const float4*)&gpT[hR + j0 + sub * 16 + g * 4];
#pragma unroll
    for (int gr = 0; gr < 4; ++gr) {
      f32x4 sacc[4];
#pragma unroll
      for (int sub = 0; sub < 4; ++sub)
        sacc[sub] = __builtin_amdgcn_mfma_f32_16x16x32_bf16(kf[sub], qf[gr], zz, 0, 0, 0);
      float sv[16];
#pragma unroll
      for (int sub = 0; sub < 4; ++sub) {
        sv[sub * 4 + 0] = sacc[sub][0] + fabsf(gpi[gr] - gj[sub].x);
        sv[sub * 4 + 1] = sacc[sub][1] + fabsf(gpi[gr] - gj[sub].y);
        sv[sub * 4 + 2] = sacc[sub][2] + fabsf(gpi[gr] - gj[sub].z);
        sv[sub * 4 + 3] = sacc[sub][3] + fabsf(gpi[gr] - gj[sub].w);
      }
      float a0 = fmaxf(sv[0], sv[1]),  a1 = fmaxf(sv[2], sv[3]);
      float a2 = fmaxf(sv[4], sv[5]),  a3 = fmaxf(sv[6], sv[7]);
      float a4 = fmaxf(sv[8], sv[9]),  a5 = fmaxf(sv[10], sv[11]);
      float a6 = fmaxf(sv[12], sv[13]), a7 = fmaxf(sv[14], sv[15]);
      const float mx = fmaxf(fmaxf(fmaxf(a0, a1), fmaxf(a2, a3)),
                             fmaxf(fmaxf(a4, a5), fmaxf(a6, a7)));
      if (!__all(mx - mr[gr] <= 11.f)) {
        float mn = mx;
        mn = fmaxf(mn, __shfl_xor(mn, 16, 64));
        mn = fmaxf(mn, __shfl_xor(mn, 32, 64));
        mn = fmaxf(mn, mr[gr]);
        const float sc = __builtin_amdgcn_exp2f(mr[gr] - mn);
        oa[gr][0][0] *= sc; oa[gr][0][1] *= sc; oa[gr][0][2] *= sc; oa[gr][0][3] *= sc;
        oa[gr][1][0] *= sc; oa[gr][1][1] *= sc; oa[gr][1][2] *= sc; oa[gr][1][3] *= sc;
        lp[gr] *= sc;
        mr[gr] = mn;
      }
      float p[16];
#pragma unroll
      for (int e = 0; e < 16; ++e) p[e] = __builtin_amdgcn_exp2f(sv[e] - mr[gr]);
      const float ps0 = (p[0] + p[1]) + (p[2] + p[3]);
      const float ps1 = (p[4] + p[5]) + (p[6] + p[7]);
      const float ps2 = (p[8] + p[9]) + (p[10] + p[11]);
      const float ps3 = (p[12] + p[13]) + (p[14] + p[15]);
      lp[gr] += (ps0 + ps1) + (ps2 + ps3);
      union { unsigned u[4]; short8v s; } pf0, pf1;
#pragma unroll
      for (int sub = 0; sub < 2; ++sub) {
        pf0.u[2 * sub + 0] = __builtin_amdgcn_perm(__float_as_uint(p[4 * sub + 1]),
                                                   __float_as_uint(p[4 * sub + 0]), 0x07060302u);
        pf0.u[2 * sub + 1] = __builtin_amdgcn_perm(__float_as_uint(p[4 * sub + 3]),
                                                   __float_as_uint(p[4 * sub + 2]), 0x07060302u);
        pf1.u[2 * sub + 0] = __builtin_amdgcn_perm(__float_as_uint(p[8 + 4 * sub + 1]),
                                                   __float_as_uint(p[8 + 4 * sub + 0]), 0x07060302u);
        pf1.u[2 * sub + 1] = __builtin_amdgcn_perm(__float_as_uint(p[8 + 4 * sub + 3]),
                                                   __float_as_uint(p[8 + 4 * sub + 2]), 0x07060302u);
      }
      oa[gr][0] = __builtin_amdgcn_mfma_f32_16x16x32_bf16(vf[0], pf0.s, oa[gr][0], 0, 0, 0);
      oa[gr][1] = __builtin_amdgcn_mfma_f32_16x16x32_bf16(vf[1], pf0.s, oa[gr][1], 0, 0, 0);
      oa[gr][0] = __builtin_amdgcn_mfma_f32_16x16x32_bf16(vf[2], pf1.s, oa[gr][0], 0, 0, 0);
      oa[gr][1] = __builtin_amdgcn_mfma_f32_16x16x32_bf16(vf[3], pf1.s, oa[gr][1], 0, 0, 0);
    }
  }
#pragma unroll
  for (int gr = 0; gr < 4; ++gr) {
    lp[gr] += __shfl_xor(lp[gr], 16, 64);
    lp[gr] += __shfl_xor(lp[gr], 32, 64);
#pragma unroll
    for (int ds = 0; ds < 2; ++ds)
      *(f32x4*)&o_l[w][gr * 16 + c][ds * 16 + g * 4] = oa[gr][ds];
    if (g == 0) {
      ml_l[w][gr * 16 + c][0] = mr[gr];
      ml_l[w][gr * 16 + c][1] = lp[gr];
    }
  }
  __syncthreads();
  // ---- combine 8 partials: thread -> (q = t>>3, d0 = (t&7)*4)
  const int q = t >> 3, d0 = (t & 7) * 4;
  float M = -INFINITY;
#pragma unroll
  for (int sp = 0; sp < 8; ++sp) M = fmaxf(M, ml_l[sp][q][0]);
  float den = 0.f;
  f32x4 num = {0.f, 0.f, 0.f, 0.f};
#pragma unroll
  for (int sp = 0; sp < 8; ++sp) {
    const float wg = __builtin_amdgcn_exp2f(ml_l[sp][q][0] - M);
    den += wg * ml_l[sp][q][1];
    const f32x4 ov = *(const f32x4*)&o_l[sp][q][d0];
    num[0] += wg * ov[0]; num[1] += wg * ov[1];
    num[2] += wg * ov[2]; num[3] += wg * ov[3];
  }
  const float inv = 1.f / den;
  f32x4 r = {num[0] * inv, num[1] * inv, num[2] * inv, num[3] * inv};
  *(f32x4*)&O1[(size_t)(qb + q) * CD + hoff + d0] = r;
}

// ------ LayerNorm (+residual); SPLIT=1 also emits XH/XL planes + row-sq
template <int SPLIT>
__global__ __launch_bounds__(256) void ln_k(const float* __restrict__ xin,
    const float* __restrict__ add, const float* __restrict__ g,
    const float* __restrict__ b, float* __restrict__ xout,
    float* __restrict__ sqout, short* __restrict__ XH, short* __restrict__ XL) {
  __shared__ float red1[4];
  __shared__ float red2[4];
  const int i = blockIdx.x, t = threadIdx.x;
  const size_t e = (size_t)i * CD + t;
  float v = xin[e];
  if (add) v += add[e];
  float s = v;
#pragma unroll
  for (int m = 1; m < 64; m <<= 1) s += __shfl_xor(s, m, 64);
  if ((t & 63) == 0) red1[t >> 6] = s;
  __syncthreads();
  const float mean = (red1[0] + red1[1] + red1[2] + red1[3]) * (1.f / 256.f);
  const float d = v - mean;
  float s2 = d * d;
#pragma unroll
  for (int m = 1; m < 64; m <<= 1) s2 += __shfl_xor(s2, m, 64);
  if ((t & 63) == 0) red2[t >> 6] = s2;
  __syncthreads();
  const float var = (red2[0] + red2[1] + red2[2] + red2[3]) * (1.f / 256.f);
  const float xo = d * rsqrtf(var + 1e-5f) * g[t] + b[t];
  xout[e] = xo;
  if (SPLIT) {
    const unsigned ui = __float_as_uint(xo);
    XH[e] = (short)(ui >> 16);
    const float hf = __uint_as_float(ui & 0xffff0000u);
    XL[e] = (short)(__float_as_uint(xo - hf) >> 16);
    float s3 = xo * xo;
#pragma unroll
    for (int m = 1; m < 64; m <<= 1) s3 += __shfl_xor(s3, m, 64);
    __syncthreads();
    if ((t & 63) == 0) red1[t >> 6] = s3;
    __syncthreads();
    if (t == 0) sqout[i] = red1[0] + red1[1] + red1[2] + red1[3];
  }
}

// ---------------------------------------------------------------- launch
extern "C" void kernel_launch(void* const* d_in, const int* in_sizes, int n_in,
                              void* d_out, int out_size, void* d_ws, size_t ws_size,
                              hipStream_t stream) {
  const float* src  = (const float*)d_in[0];
  const float* c1w  = (const float*)d_in[1];
  const float* c1b  = (const float*)d_in[2];
  const float* c2w  = (const float*)d_in[3];
  const float* c2b  = (const float*)d_in[4];
  const float* nemb = (const float*)d_in[5];
  const float* Wq   = (const float*)d_in[6];
  const float* bq   = (const float*)d_in[7];
  const float* Wk   = (const float*)d_in[8];
  const float* bk   = (const float*)d_in[9];
  const float* Wv   = (const float*)d_in[10];
  const float* bv   = (const float*)d_in[11];
  const float* Wo   = (const float*)d_in[12];
  const float* bo   = (const float*)d_in[13];
  const float* W1   = (const float*)d_in[14];
  const float* b1   = (const float*)d_in[15];
  const float* W2   = (const float*)d_in[16];
  const float* b2   = (const float*)d_in[17];
  const float* ln1g = (const float*)d_in[18];
  const float* ln1b = (const float*)d_in[19];
  const float* ln2g = (const float*)d_in[20];
  const float* ln2b = (const float*)d_in[21];
  const float* ng   = (const float*)d_in[22];
  const float* nb   = (const float*)d_in[23];

  float* ws = (float*)d_ws;
  const size_t NC = (size_t)N_TOK * CD;          // 802816
  float* X    = ws;
  float* QKIN = X + NC;
  float* O1   = QKIN + NC;
  float* TMP  = O1 + NC;
  float* FF1  = TMP + NC;                        // 3136*1024
  float* G    = FF1 + (size_t)N_TOK * DFFD;      // 3136*3136 (keys / conv1 partials)
  float* T1   = G + (size_t)N_TOK * N_TOK;       // 3136*128
  float* GPT  = T1 + (size_t)N_TOK * 128;        // 8*3136
  float* SQF  = GPT + (size_t)N_TOK * NHD;       // 3136
  short* QB16 = (short*)(SQF + N_TOK);
  short* KB16 = QB16 + NC;
  short* VT16 = KB16 + NC;
  short* XH   = VT16 + NC;                       // bf16 hi plane
  short* XL   = XH + NC;                         // bf16 lo plane
  float* WTC  = (float*)(XL + NC);               // 9*128*256 = 294912
  int*   NEAR = (int*)(WTC + 294912);            // 4 * 3136 ints

  // tokens + conv positional encoder (direct conv, no im2col)
  transpose_k<<<dim3(98, 8), 256, 0, stream>>>(src, X, 256, N_TOK);
  wtr_k<<<1152, 256, 0, stream>>>(c1w, WTC);
  conv1_k<<<dim3(2, 98, 3), 256, 0, stream>>>(X, WTC, G);
  convred_k<<<1568, 256, 0, stream>>>(G, c1b, T1);
  conv2_k<<<98, 256, 0, stream>>>(T1, c2w, c2b, GPT);
  xsplit_k<<<N_TOK, 256, 0, stream>>>(X, XH, XL, SQF);
  (void)hipMemsetAsync(NEAR, 0, 4 * N_TOK * sizeof(int), stream);

  for (int l = 0; l < 4; ++l) {
    int* NEAR_l = NEAR + l * N_TOK;
    // ---- kNN graph -> near counts (hi/lo bf16 MFMA Gram, key-fused)
    gemm_syr4_k<<<1225, 256, 0, stream>>>(XH, XL, SQF, (unsigned*)G);
    topk_k<<<N_TOK, 64, 0, stream>>>((const unsigned*)G, NEAR_l);
    nearqk_k<<<N_TOK, 256, 0, stream>>>(X, NEAR_l, nemb, QKIN);
    // ---- fused Q/K/V projections (32-row tiles, per-head Q/K layout)
    proj32_k<<<dim3(4, 98, 3), 256, 0, stream>>>(QKIN, X,
        Wq + (size_t)l * 65536, Wk + (size_t)l * 65536, Wv + (size_t)l * 65536,
        bq + l * 256, bk + l * 256, bv + l * 256, QB16, KB16, VT16);
    // ---- attention (8 waves/block, j-eighths, in-block combine)
    attn_v8_k<<<dim3(49, 8), 512, 0, stream>>>(QB16, KB16, VT16, GPT, O1);
    gemm32_k<0><<<dim3(4, 98), 256, 0, stream>>>(O1, Wo + (size_t)l * 65536, bo + l * 256, TMP, 256, 256);
    ln_k<0><<<N_TOK, 256, 0, stream>>>(X, TMP, ln1g + l * 256, ln1b + l * 256, X, nullptr, nullptr, nullptr);
    // ---- FFN
    gemm32_k<1><<<dim3(16, 98), 256, 0, stream>>>(X, W1 + (size_t)l * 262144, b1 + l * 1024, FF1, 1024, 256);
    gemm32_k<0><<<dim3(4, 98), 256, 0, stream>>>(FF1, W2 + (size_t)l * 262144, b2 + l * 256, TMP, 256, 1024);
    // ln2 fused with X hi/lo split + row-sq (feeds next layer's Gram/topk)
    ln_k<1><<<N_TOK, 256, 0, stream>>>(X, TMP, ln2g + l * 256, ln2b + l * 256, X, SQF, XH, XL);
  }
  // final LN + transpose to [1,C,H,W]
  ln_k<0><<<N_TOK, 256, 0, stream>>>(X, nullptr, ng, nb, TMP, nullptr, nullptr, nullptr);
  transpose_k<<<dim3(8, 98), 256, 0, stream>>>(TMP, (float*)d_out, N_TOK, 256);
}

// Round 20
// 624.648 us; speedup vs baseline: 2.1508x; 1.0264x over previous
//
#include <hip/hip_runtime.h>
#include <math.h>

#define N_TOK 3136
#define CD    256
#define NHD   8
#define DH    32
#define DFFD  1024
#define SCALE 0.17677669529663687f  /* 32^-0.5 */
#define LOG2E 1.4426950408889634f
#define QSC   (SCALE * LOG2E)

typedef __attribute__((ext_vector_type(8))) short short8v;
typedef __attribute__((ext_vector_type(4))) float f32x4;

// ---------------------------------------------------------------- utils
__device__ __forceinline__ unsigned long long sx64(unsigned long long v, int m) {
  unsigned lo = (unsigned)__shfl_xor((int)(unsigned)(v & 0xffffffffull), m, 64);
  unsigned hi = (unsigned)__shfl_xor((int)(unsigned)(v >> 32), m, 64);
  return ((unsigned long long)hi << 32) | lo;
}

__device__ __forceinline__ unsigned f2mono(float v) {
  unsigned b = __float_as_uint(v);
  return (b & 0x80000000u) ? ~b : (b | 0x80000000u);
}

// fp32 -> bf16 round-to-nearest-even
__device__ __forceinline__ short bfr(float f) {
  unsigned u = __float_as_uint(f);
  unsigned r = (u + 0x7fffu + ((u >> 16) & 1u)) >> 16;
  return (short)r;
}

__device__ __forceinline__ short8v cvt8(float4 a, float4 b) {
  short8v r;
  r[0] = bfr(a.x); r[1] = bfr(a.y); r[2] = bfr(a.z); r[3] = bfr(a.w);
  r[4] = bfr(b.x); r[5] = bfr(b.y); r[6] = bfr(b.z); r[7] = bfr(b.w);
  return r;
}

// -------------------------------------------- fp32 -> bf16 (grid-stride)
__global__ __launch_bounds__(256) void cvt_k(const float* __restrict__ in,
    short* __restrict__ out, int n) {
  for (int i = blockIdx.x * 256 + threadIdx.x; i < n; i += gridDim.x * 256)
    out[i] = bfr(in[i]);
}

// ------------------------------------------------- transpose (32x32 tiles)
__global__ __launch_bounds__(256) void transpose_k(const float* __restrict__ in,
    float* __restrict__ out, int R, int C) {
  __shared__ float ls[32][33];
  const int c0 = blockIdx.x * 32, r0 = blockIdx.y * 32;
  const int tx = threadIdx.x & 31, ty = threadIdx.x >> 5;
#pragma unroll
  for (int j = 0; j < 4; ++j) {
    int r = ty + j * 8;
    ls[r][tx] = in[(size_t)(r0 + r) * C + c0 + tx];
  }
  __syncthreads();
#pragma unroll
  for (int j = 0; j < 4; ++j) {
    int cc = ty + j * 8;
    out[(size_t)(c0 + cc) * R + r0 + tx] = ls[tx][cc];
  }
}

// ------------- conv1 weight transpose -> bf16: WT[r][co][ci] = w[co][ci][r]
__global__ __launch_bounds__(256) void wtr_k(const float* __restrict__ w,
                                             short* __restrict__ wt) {
  const int e = blockIdx.x * 256 + threadIdx.x;   // < 9*128*256 = 294912
  const int r = e >> 15;
  const int rem = e & 32767;
  const int co = rem >> 8, ci = rem & 255;
  wt[e] = bfr(w[((size_t)co * 256 + ci) * 9 + r]);
}

// -------- conv1 as direct tap-GEMM: grid (2, 98, 3), z = ky; bf16 weights
__global__ __launch_bounds__(256) void conv1_k(const float* __restrict__ X,
    const short* __restrict__ WT, float* __restrict__ P) {
  __shared__ __align__(16) short As[32][40];
  __shared__ __align__(16) short Bs[64][40];
  const int n0 = blockIdx.x * 64;
  const int m0 = blockIdx.y * 32;
  const int ky = blockIdx.z;
  const int t = threadIdx.x;
  const int w = t >> 6, l = t & 63;
  const int g = l >> 4, c = l & 15;
  const int wr = w >> 1, wc = w & 1;
  const int sr = t >> 2, seg = t & 3;
  const int p = m0 + (sr & 31);
  const int y = p / 56, x = p - y * 56;
  const int yy = y + ky - 1;
  f32x4 acc[2] = {};
  for (int kx = 0; kx < 3; ++kx) {
    const int xx = x + kx - 1;
    const bool valid = (t < 128) && ((unsigned)yy < 56u) && ((unsigned)xx < 56u);
    const float* Ap = X + (size_t)(yy * 56 + xx) * CD + seg * 8;
    const short* Bp = WT + ((size_t)(ky * 3 + kx) * 128 + n0 + sr) * CD + seg * 8;
    for (int k0 = 0; k0 < CD; k0 += 32) {
      float4 a1 = make_float4(0.f, 0.f, 0.f, 0.f), a2 = a1;
      if (valid) { a1 = *(const float4*)(Ap + k0); a2 = *(const float4*)(Ap + k0 + 4); }
      const short8v bv = *(const short8v*)(Bp + k0);
      __syncthreads();
      if (t < 128) *(short8v*)&As[sr][seg * 8] = cvt8(a1, a2);
      *(short8v*)&Bs[sr][seg * 8] = bv;
      __syncthreads();
      const short8v af = *(const short8v*)&As[wr * 16 + c][g * 8];
      const short8v bf0 = *(const short8v*)&Bs[wc * 32 + c][g * 8];
      const short8v bf1 = *(const short8v*)&Bs[wc * 32 + 16 + c][g * 8];
      acc[0] = __builtin_amdgcn_mfma_f32_16x16x32_bf16(af, bf0, acc[0], 0, 0, 0);
      acc[1] = __builtin_amdgcn_mfma_f32_16x16x32_bf16(af, bf1, acc[1], 0, 0, 0);
    }
  }
#pragma unroll
  for (int ni = 0; ni < 2; ++ni) {
    const int col = n0 + wc * 32 + ni * 16 + c;
#pragma unroll
    for (int q = 0; q < 4; ++q) {
      const int m = m0 + wr * 16 + g * 4 + q;
      P[((size_t)ky * N_TOK + m) * 128 + col] = acc[ni][q];
    }
  }
}

// ----------------------- reduce conv1 tap partials + bias + relu -> T1
__global__ __launch_bounds__(256) void convred_k(const float* __restrict__ P,
    const float* __restrict__ b, float* __restrict__ T1) {
  const int e = blockIdx.x * 256 + threadIdx.x;   // < 3136*128
  const float v = P[e] + P[401408 + e] + P[802816 + e] + b[e & 127];
  T1[e] = fmaxf(v, 0.f);
}

// ---- 32x64-tile bf16 MFMA GEMM NT; A16: A already bf16; O16: bf16 out.
// B is always bf16 (pre-converted weights).
template <int RELU, int A16, int O16>
__global__ __launch_bounds__(256) void gemm32_k(const void* __restrict__ Av,
    const short* __restrict__ Bw, const float* __restrict__ bias,
    void* __restrict__ Cv, int N, int K) {
  __shared__ __align__(16) short As[32][40];
  __shared__ __align__(16) short Bs[64][40];
  const int n0 = blockIdx.x * 64;
  const int m0 = blockIdx.y * 32;
  const int t = threadIdx.x;
  const int w = t >> 6, l = t & 63;
  const int g = l >> 4, c = l & 15;
  const int wr = w >> 1, wc = w & 1;
  const int sr = t >> 2, seg = t & 3;
  const float* Apf = (const float*)Av + (size_t)(m0 + (sr & 31)) * K + seg * 8;
  const short* Aps = (const short*)Av + (size_t)(m0 + (sr & 31)) * K + seg * 8;
  const short* Bp = Bw + (size_t)(n0 + sr) * K + seg * 8;
  f32x4 acc[2] = {};
  for (int k0 = 0; k0 < K; k0 += 32) {
    short8v a8;
    if (A16) {
      if (t < 128) a8 = *(const short8v*)(Aps + k0);
    } else {
      float4 a1 = make_float4(0.f, 0.f, 0.f, 0.f), a2 = a1;
      if (t < 128) { a1 = *(const float4*)(Apf + k0); a2 = *(const float4*)(Apf + k0 + 4); }
      a8 = cvt8(a1, a2);
    }
    const short8v bv = *(const short8v*)(Bp + k0);
    __syncthreads();
    if (t < 128) *(short8v*)&As[sr][seg * 8] = a8;
    *(short8v*)&Bs[sr][seg * 8] = bv;
    __syncthreads();
    const short8v af = *(const short8v*)&As[wr * 16 + c][g * 8];
    const short8v bf0 = *(const short8v*)&Bs[wc * 32 + c][g * 8];
    const short8v bf1 = *(const short8v*)&Bs[wc * 32 + 16 + c][g * 8];
    acc[0] = __builtin_amdgcn_mfma_f32_16x16x32_bf16(af, bf0, acc[0], 0, 0, 0);
    acc[1] = __builtin_amdgcn_mfma_f32_16x16x32_bf16(af, bf1, acc[1], 0, 0, 0);
  }
#pragma unroll
  for (int ni = 0; ni < 2; ++ni) {
    const int col = n0 + wc * 32 + ni * 16 + c;
    const float bb = bias ? bias[col] : 0.f;
#pragma unroll
    for (int q = 0; q < 4; ++q) {
      const int m = m0 + wr * 16 + g * 4 + q;
      float v = acc[ni][q] + bb;
      if (RELU) v = fmaxf(v, 0.f);
      if (O16) ((short*)Cv)[(size_t)m * N + col] = bfr(v);
      else ((float*)Cv)[(size_t)m * N + col] = v;
    }
  }
}

// ---------------- fused Q/K/V projections, bf16 weights, bf16 outputs
// Q/K per-head contiguous [h][tok][32]; V^T chunk-swizzled [d][tok].
__global__ __launch_bounds__(256) void proj32_k(const float* __restrict__ QKIN,
    const float* __restrict__ X, const short* __restrict__ Wq,
    const short* __restrict__ Wk, const short* __restrict__ Wv,
    const float* __restrict__ bq, const float* __restrict__ bk,
    const float* __restrict__ bv, short* __restrict__ QB,
    short* __restrict__ KB, short* __restrict__ VT) {
  __shared__ __align__(16) short As[32][40];
  __shared__ __align__(16) short Bs[64][40];
  const int sel = blockIdx.z;
  const int n0 = blockIdx.x * 64;
  const int m0 = blockIdx.y * 32;
  const float* A = (sel < 2) ? QKIN : X;
  const short* B = (sel == 0) ? Wq : (sel == 1) ? Wk : Wv;
  const float* bias = (sel == 0) ? bq : (sel == 1) ? bk : bv;
  const int t = threadIdx.x;
  const int w = t >> 6, l = t & 63;
  const int g = l >> 4, c = l & 15;
  const int wr = w >> 1, wc = w & 1;
  const int sr = t >> 2, seg = t & 3;
  const float* Ap = A + (size_t)(m0 + (sr & 31)) * CD + seg * 8;
  const short* Bp = B + (size_t)(n0 + sr) * CD + seg * 8;
  f32x4 acc[2] = {};
  for (int k0 = 0; k0 < CD; k0 += 32) {
    float4 a1 = make_float4(0.f, 0.f, 0.f, 0.f), a2 = a1;
    if (t < 128) { a1 = *(const float4*)(Ap + k0); a2 = *(const float4*)(Ap + k0 + 4); }
    const short8v bv8 = *(const short8v*)(Bp + k0);
    __syncthreads();
    if (t < 128) *(short8v*)&As[sr][seg * 8] = cvt8(a1, a2);
    *(short8v*)&Bs[sr][seg * 8] = bv8;
    __syncthreads();
    const short8v af = *(const short8v*)&As[wr * 16 + c][g * 8];
    const short8v bf0 = *(const short8v*)&Bs[wc * 32 + c][g * 8];
    const short8v bf1 = *(const short8v*)&Bs[wc * 32 + 16 + c][g * 8];
    acc[0] = __builtin_amdgcn_mfma_f32_16x16x32_bf16(af, bf0, acc[0], 0, 0, 0);
    acc[1] = __builtin_amdgcn_mfma_f32_16x16x32_bf16(af, bf1, acc[1], 0, 0, 0);
  }
#pragma unroll
  for (int ni = 0; ni < 2; ++ni) {
    const int col = n0 + wc * 32 + ni * 16 + c;
    const float bb = bias[col];
    if (sel == 2) {
      const int mb = m0 + wr * 16 + g * 4;
      const int pidx = (mb & ~31) + ((mb >> 4) & 1) * 4 + ((mb >> 2) & 3) * 8;
      uint2 pk;
      const float v0 = acc[ni][0] + bb, v1 = acc[ni][1] + bb;
      const float v2 = acc[ni][2] + bb, v3 = acc[ni][3] + bb;
      pk.x = (unsigned)(unsigned short)bfr(v0) | ((unsigned)(unsigned short)bfr(v1) << 16);
      pk.y = (unsigned)(unsigned short)bfr(v2) | ((unsigned)(unsigned short)bfr(v3) << 16);
      *(uint2*)&VT[(size_t)col * N_TOK + pidx] = pk;
    } else {
      short* Ct = (sel == 0) ? QB : KB;
      const float qs = (sel == 0) ? QSC : 1.f;
      const int hh = col >> 5, dd = col & 31;
#pragma unroll
      for (int q = 0; q < 4; ++q) {
        const int m = m0 + wr * 16 + g * 4 + q;
        Ct[((size_t)hh * N_TOK + m) * 32 + dd] = bfr((acc[ni][q] + bb) * qs);
      }
    }
  }
}

// --------------- X -> bf16 hi/lo planes + row ||x||^2 (prologue only)
__global__ __launch_bounds__(256) void xsplit_k(const float* __restrict__ X,
    short* __restrict__ XH, short* __restrict__ XL, float* __restrict__ sq) {
  __shared__ float red[4];
  const int i = blockIdx.x, t = threadIdx.x;
  const size_t e = (size_t)i * CD + t;
  const float v = X[e];
  const unsigned ui = __float_as_uint(v);
  XH[e] = (short)(ui >> 16);
  const float hf = __uint_as_float(ui & 0xffff0000u);
  XL[e] = (short)(__float_as_uint(v - hf) >> 16);
  float s = v * v;
#pragma unroll
  for (int m = 1; m < 64; m <<= 1) s += __shfl_xor(s, m, 64);
  if ((t & 63) == 0) red[t >> 6] = s;
  __syncthreads();
  if (t == 0) sq[i] = red[0] + red[1] + red[2] + red[3];
}

// ---- Gram, key-fused: stores u32 mono keys for both mirror entries.
__global__ __launch_bounds__(256) void gemm_syr4_k(const short* __restrict__ XH,
    const short* __restrict__ XL, const float* __restrict__ SQ,
    unsigned* __restrict__ Ck) {
  __shared__ __align__(16) short AsH[64][40];
  __shared__ __align__(16) short AsL[64][40];
  __shared__ __align__(16) short BsH[64][40];
  __shared__ __align__(16) short BsL[64][40];
  int bid = blockIdx.x;
  int bi = (int)((sqrtf(8.f * (float)bid + 1.f) - 1.f) * 0.5f);
  while ((bi + 1) * (bi + 2) / 2 <= bid) ++bi;
  while (bi * (bi + 1) / 2 > bid) --bi;
  const int bj = bid - bi * (bi + 1) / 2;
  const int m0 = bi * 64, n0 = bj * 64;
  const int t = threadIdx.x;
  const int w = t >> 6, l = t & 63;
  const int g = l >> 4, c = l & 15;
  const int wr = w >> 1, wc = w & 1;
  const int sr = t >> 2, seg = t & 3;
  const size_t arow = (size_t)(m0 + sr) * CD + seg * 8;
  const size_t brow = (size_t)(n0 + sr) * CD + seg * 8;
  f32x4 acc[2][2] = {};
  for (int k0 = 0; k0 < CD; k0 += 32) {
    const short8v ah = *(const short8v*)&XH[arow + k0];
    const short8v al = *(const short8v*)&XL[arow + k0];
    const short8v bh = *(const short8v*)&XH[brow + k0];
    const short8v bl = *(const short8v*)&XL[brow + k0];
    __syncthreads();
    *(short8v*)&AsH[sr][seg * 8] = ah;
    *(short8v*)&AsL[sr][seg * 8] = al;
    *(short8v*)&BsH[sr][seg * 8] = bh;
    *(short8v*)&BsL[sr][seg * 8] = bl;
    __syncthreads();
    short8v afH[2], afL[2], bfH[2], bfL[2];
#pragma unroll
    for (int mi = 0; mi < 2; ++mi) {
      afH[mi] = *(const short8v*)&AsH[wr * 32 + mi * 16 + c][g * 8];
      afL[mi] = *(const short8v*)&AsL[wr * 32 + mi * 16 + c][g * 8];
    }
#pragma unroll
    for (int ni = 0; ni < 2; ++ni) {
      bfH[ni] = *(const short8v*)&BsH[wc * 32 + ni * 16 + c][g * 8];
      bfL[ni] = *(const short8v*)&BsL[wc * 32 + ni * 16 + c][g * 8];
    }
#pragma unroll
    for (int mi = 0; mi < 2; ++mi)
#pragma unroll
      for (int ni = 0; ni < 2; ++ni) {
        acc[mi][ni] = __builtin_amdgcn_mfma_f32_16x16x32_bf16(afH[mi], bfH[ni], acc[mi][ni], 0, 0, 0);
        acc[mi][ni] = __builtin_amdgcn_mfma_f32_16x16x32_bf16(afH[mi], bfL[ni], acc[mi][ni], 0, 0, 0);
        acc[mi][ni] = __builtin_amdgcn_mfma_f32_16x16x32_bf16(afL[mi], bfH[ni], acc[mi][ni], 0, 0, 0);
      }
  }
#pragma unroll
  for (int mi = 0; mi < 2; ++mi)
#pragma unroll
    for (int ni = 0; ni < 2; ++ni) {
      const int col = n0 + wc * 32 + ni * 16 + c;
      const float sqc = SQ[col];
#pragma unroll
      for (int q = 0; q < 4; ++q) {
        const int m = m0 + wr * 32 + mi * 16 + g * 4 + q;
        const float v = acc[mi][ni][q];
        const float sqm = SQ[m];
        Ck[(size_t)m * N_TOK + col] = f2mono((sqm - 2.f * v) + sqc);
        Ck[(size_t)col * N_TOK + m] = f2mono((sqc - 2.f * v) + sqm);
      }
    }
}

// ------------------- conv2 (8ch) -> writes gpT [8][N_TOK] * log2e directly
__global__ __launch_bounds__(256) void conv2_k(const float* __restrict__ t1,
    const float* __restrict__ w, const float* __restrict__ b,
    float* __restrict__ gpT) {
  __shared__ float ws3[9 * 8 * 132];
  const int t = threadIdx.x;
  for (int e = t; e < 9216; e += 256) {
    int r = e >> 10;
    int rem = e & 1023;
    int co = rem >> 7;
    int ci = rem & 127;
    ws3[(r * 8 + co) * 132 + ci] = w[((size_t)co * 128 + ci) * 9 + r];
  }
  __syncthreads();
  const int pix = blockIdx.x * 32 + (t >> 3);
  const int co = t & 7;
  const int y = pix / 56, x = pix - y * 56;
  float acc = b[co];
  for (int ky = 0; ky < 3; ++ky) {
    int yy = y + ky - 1;
    if (yy < 0 || yy >= 56) continue;
    for (int kx = 0; kx < 3; ++kx) {
      int xx = x + kx - 1;
      if (xx < 0 || xx >= 56) continue;
      const float4* tp = (const float4*)&t1[(size_t)(yy * 56 + xx) * 128];
      const float* wp = &ws3[((ky * 3 + kx) * 8 + co) * 132];
#pragma unroll
      for (int c4 = 0; c4 < 32; ++c4) {
        const float4 tv = tp[c4];
        const float4 wv = *(const float4*)&wp[c4 * 4];
        acc += tv.x * wv.x + tv.y * wv.y + tv.z * wv.z + tv.w * wv.w;
      }
    }
  }
  gpT[co * N_TOK + pix] = LOG2E / (1.f + expf(-acc));
}

// ---- top-16 NN + in-degree, v7: one wave/row, per-lane TOP-4 cache over
// precomputed mono keys; rare refill. Bit-exact lex top_k.
__global__ __launch_bounds__(64) void topk_k(const unsigned* __restrict__ Gk,
    int* __restrict__ near) {
  const int i = blockIdx.x;
  const int t = threadIdx.x;            // lane 0..63
  const unsigned* __restrict__ Krow = Gk + (size_t)i * N_TOK;
  unsigned cv0 = 0xffffffffu, cv1 = 0xffffffffu, cv2 = 0xffffffffu, cv3 = 0xffffffffu;
  int ce0 = 0, ce1 = 0, ce2 = 0, ce3 = 0;
#pragma unroll
  for (int e = 0; e < 49; ++e) {
    const unsigned v = Krow[t + (e << 6)];    // 49*64 = 3136 exactly
    const bool i0 = v < cv0, i1 = v < cv1, i2 = v < cv2, i3 = v < cv3;
    cv3 = i2 ? cv2 : (i3 ? v : cv3);  ce3 = i2 ? ce2 : (i3 ? e : ce3);
    cv2 = i1 ? cv1 : (i2 ? v : cv2);  ce2 = i1 ? ce1 : (i2 ? e : ce2);
    cv1 = i0 ? cv0 : (i1 ? v : cv1);  ce1 = i0 ? ce0 : (i1 ? e : ce1);
    cv0 = i0 ? v : cv0;               ce0 = i0 ? e : ce0;
  }
  unsigned long long killed = 0ull;
#pragma unroll 1
  for (int r = 0; r < 16; ++r) {
    const unsigned long long mine =
        ((unsigned long long)cv0 << 32) | (unsigned)(t + (ce0 << 6));
    unsigned long long best = mine;
#pragma unroll
    for (int m = 1; m < 64; m <<= 1) {
      const unsigned long long o = sx64(best, m);
      best = (o < best) ? o : best;
    }
    if (t == 0) atomicAdd(&near[(unsigned)(best & 0xffffffffu)], 1);
    if (mine == best && r < 15) {
      killed |= 1ull << ce0;
      cv0 = cv1; ce0 = ce1;
      cv1 = cv2; ce1 = ce2;
      cv2 = cv3; ce2 = ce3;
      cv3 = 0xffffffffu; ce3 = 0;
      if (cv0 == 0xffffffffu) {
#pragma unroll
        for (int e = 0; e < 49; ++e) {
          unsigned v = Krow[t + (e << 6)];
          v = (((killed >> e) & 1ull) != 0ull) ? 0xffffffffu : v;
          const bool i0 = v < cv0, i1 = v < cv1, i2 = v < cv2, i3 = v < cv3;
          cv3 = i2 ? cv2 : (i3 ? v : cv3);  ce3 = i2 ? ce2 : (i3 ? e : ce3);
          cv2 = i1 ? cv1 : (i2 ? v : cv2);  ce2 = i1 ? ce1 : (i2 ? e : ce2);
          cv1 = i0 ? cv0 : (i1 ? v : cv1);  ce1 = i0 ? ce0 : (i1 ? e : ce1);
          cv0 = i0 ? v : cv0;               ce0 = i0 ? e : ce0;
        }
      }
    }
  }
}

// ------------- fused max(near) + qk_in = x + emb[ni(near)] (one row/block)
__global__ __launch_bounds__(256) void nearqk_k(const float* __restrict__ x,
    const int* __restrict__ near, const float* __restrict__ emb,
    float* __restrict__ qkin) {
  __shared__ int sm[4];
  const int i = blockIdx.x, t = threadIdx.x;
  int m = 0;
  for (int j = t; j < N_TOK; j += 256) m = max(m, near[j]);
#pragma unroll
  for (int s = 1; s < 64; s <<= 1) m = max(m, __shfl_xor(m, s, 64));
  if ((t & 63) == 0) sm[t >> 6] = m;
  __syncthreads();
  const int mv = max(max(sm[0], sm[1]), max(sm[2], sm[3]));
  const int ni = (int)((float)near[i] / (float)mv * 9.0f);
  qkin[(size_t)i * CD + t] = x[(size_t)i * CD + t] + emb[ni * CD + t];
}

// ---- flash attention v8: 8 waves/block (512 thr), 64 queries/wave,
// j-eighths per wave; per-head Q/K layout; in-block 8-way combine.
__global__ __launch_bounds__(512) void attn_v8_k(const short* __restrict__ Qb,
    const short* __restrict__ Kb, const short* __restrict__ Vt,
    const float* __restrict__ gpT, float* __restrict__ O1) {
  __shared__ float o_l[8][64][36];
  __shared__ float ml_l[8][64][2];
  const int h = blockIdx.y;
  const int qb = blockIdx.x * 64;
  const int t = threadIdx.x;
  const int w = t >> 6, l = t & 63;
  const int g = l >> 4, c = l & 15;
  const size_t hR = (size_t)h * N_TOK;      // per-head row base (Q/K/gpT)
  const size_t hoff = (size_t)h * DH;       // VT d-row base
  short8v qf[4];
  float gpi[4];
#pragma unroll
  for (int gr = 0; gr < 4; ++gr) {
    qf[gr] = *(const short8v*)&Qb[(hR + qb + gr * 16 + c) * 32 + g * 8];
    gpi[gr] = gpT[hR + qb + gr * 16 + c];
  }
  const int jt0 = w ? (7 + 6 * (w - 1)) : 0;   // {7,6,6,6,6,6,6,6} = 49
  const int jt1 = jt0 + (w ? 6 : 7);
  float mr[4] = {-INFINITY, -INFINITY, -INFINITY, -INFINITY};
  float lp[4] = {0.f, 0.f, 0.f, 0.f};
  f32x4 oa[4][2] = {};
  const f32x4 zz = {0.f, 0.f, 0.f, 0.f};

#pragma unroll 1
  for (int jt = jt0; jt < jt1; ++jt) {
    const int j0 = jt * 64;
    short8v kf[4], vf[4];
    float4 gj[4];
#pragma unroll
    for (int sub = 0; sub < 4; ++sub)
      kf[sub] = *(const short8v*)&Kb[(hR + j0 + sub * 16 + c) * 32 + g * 8];
#pragma unroll
    for (int ch = 0; ch < 2; ++ch)
#pragma unroll
      for (int ds = 0; ds < 2; ++ds)
        vf[ch * 2 + ds] = *(const short8v*)&Vt[(hoff + ds * 16 + c) * (size_t)N_TOK + j0 + ch * 32 + g * 8];
#pragma unroll
    for (int sub = 0; sub < 4; ++sub)
      gj[sub] = *(const float4*)&gpT[hR + j0 + sub * 16 + g * 4];
#pragma unroll
    for (int gr = 0; gr < 4; ++gr) {
      f32x4 sacc[4];
#pragma unroll
      for (int sub = 0; sub < 4; ++sub)
        sacc[sub] = __builtin_amdgcn_mfma_f32_16x16x32_bf16(kf[sub], qf[gr], zz, 0, 0, 0);
      float sv[16];
#pragma unroll
      for (int sub = 0; sub < 4; ++sub) {
        sv[sub * 4 + 0] = sacc[sub][0] + fabsf(gpi[gr] - gj[sub].x);
        sv[sub * 4 + 1] = sacc[sub][1] + fabsf(gpi[gr] - gj[sub].y);
        sv[sub * 4 + 2] = sacc[sub][2] + fabsf(gpi[gr] - gj[sub].z);
        sv[sub * 4 + 3] = sacc[sub][3] + fabsf(gpi[gr] - gj[sub].w);
      }
      float a0 = fmaxf(sv[0], sv[1]),  a1 = fmaxf(sv[2], sv[3]);
      float a2 = fmaxf(sv[4], sv[5]),  a3 = fmaxf(sv[6], sv[7]);
      float a4 = fmaxf(sv[8], sv[9]),  a5 = fmaxf(sv[10], sv[11]);
      float a6 = fmaxf(sv[12], sv[13]), a7 = fmaxf(sv[14], sv[15]);
      const float mx = fmaxf(fmaxf(fmaxf(a0, a1), fmaxf(a2, a3)),
                             fmaxf(fmaxf(a4, a5), fmaxf(a6, a7)));
      if (!__all(mx - mr[gr] <= 11.f)) {
        float mn = mx;
        mn = fmaxf(mn, __shfl_xor(mn, 16, 64));
        mn = fmaxf(mn, __shfl_xor(mn, 32, 64));
        mn = fmaxf(mn, mr[gr]);
        const float sc = __builtin_amdgcn_exp2f(mr[gr] - mn);
        oa[gr][0][0] *= sc; oa[gr][0][1] *= sc; oa[gr][0][2] *= sc; oa[gr][0][3] *= sc;
        oa[gr][1][0] *= sc; oa[gr][1][1] *= sc; oa[gr][1][2] *= sc; oa[gr][1][3] *= sc;
        lp[gr] *= sc;
        mr[gr] = mn;
      }
      float p[16];
#pragma unroll
      for (int e = 0; e < 16; ++e) p[e] = __builtin_amdgcn_exp2f(sv[e] - mr[gr]);
      const float ps0 = (p[0] + p[1]) + (p[2] + p[3]);
      const float ps1 = (p[4] + p[5]) + (p[6] + p[7]);
      const float ps2 = (p[8] + p[9]) + (p[10] + p[11]);
      const float ps3 = (p[12] + p[13]) + (p[14] + p[15]);
      lp[gr] += (ps0 + ps1) + (ps2 + ps3);
      union { unsigned u[4]; short8v s; } pf0, pf1;
#pragma unroll
      for (int sub = 0; sub < 2; ++sub) {
        pf0.u[2 * sub + 0] = __builtin_amdgcn_perm(__float_as_uint(p[4 * sub + 1]),
                                                   __float_as_uint(p[4 * sub + 0]), 0x07060302u);
        pf0.u[2 * sub + 1] = __builtin_amdgcn_perm(__float_as_uint(p[4 * sub + 3]),
                                                   __float_as_uint(p[4 * sub + 2]), 0x07060302u);
        pf1.u[2 * sub + 0] = __builtin_amdgcn_perm(__float_as_uint(p[8 + 4 * sub + 1]),
                                                   __float_as_uint(p[8 + 4 * sub + 0]), 0x07060302u);
        pf1.u[2 * sub + 1] = __builtin_amdgcn_perm(__float_as_uint(p[8 + 4 * sub + 3]),
                                                   __float_as_uint(p[8 + 4 * sub + 2]), 0x07060302u);
      }
      oa[gr][0] = __builtin_amdgcn_mfma_f32_16x16x32_bf16(vf[0], pf0.s, oa[gr][0], 0, 0, 0);
      oa[gr][1] = __builtin_amdgcn_mfma_f32_16x16x32_bf16(vf[1], pf0.s, oa[gr][1], 0, 0, 0);
      oa[gr][0] = __builtin_amdgcn_mfma_f32_16x16x32_bf16(vf[2], pf1.s, oa[gr][0], 0, 0, 0);
      oa[gr][1] = __builtin_amdgcn_mfma_f32_16x16x32_bf16(vf[3], pf1.s, oa[gr][1], 0, 0, 0);
    }
  }
#pragma unroll
  for (int gr = 0; gr < 4; ++gr) {
    lp[gr] += __shfl_xor(lp[gr], 16, 64);
    lp[gr] += __shfl_xor(lp[gr], 32, 64);
#pragma unroll
    for (int ds = 0; ds < 2; ++ds)
      *(f32x4*)&o_l[w][gr * 16 + c][ds * 16 + g * 4] = oa[gr][ds];
    if (g == 0) {
      ml_l[w][gr * 16 + c][0] = mr[gr];
      ml_l[w][gr * 16 + c][1] = lp[gr];
    }
  }
  __syncthreads();
  // ---- combine 8 partials: thread -> (q = t>>3, d0 = (t&7)*4)
  const int q = t >> 3, d0 = (t & 7) * 4;
  float M = -INFINITY;
#pragma unroll
  for (int sp = 0; sp < 8; ++sp) M = fmaxf(M, ml_l[sp][q][0]);
  float den = 0.f;
  f32x4 num = {0.f, 0.f, 0.f, 0.f};
#pragma unroll
  for (int sp = 0; sp < 8; ++sp) {
    const float wg = __builtin_amdgcn_exp2f(ml_l[sp][q][0] - M);
    den += wg * ml_l[sp][q][1];
    const f32x4 ov = *(const f32x4*)&o_l[sp][q][d0];
    num[0] += wg * ov[0]; num[1] += wg * ov[1];
    num[2] += wg * ov[2]; num[3] += wg * ov[3];
  }
  const float inv = 1.f / den;
  f32x4 r = {num[0] * inv, num[1] * inv, num[2] * inv, num[3] * inv};
  *(f32x4*)&O1[(size_t)(qb + q) * CD + hoff + d0] = r;
}

// ------ LayerNorm (+residual); SPLIT=1 also emits XH/XL planes + row-sq
template <int SPLIT>
__global__ __launch_bounds__(256) void ln_k(const float* __restrict__ xin,
    const float* __restrict__ add, const float* __restrict__ g,
    const float* __restrict__ b, float* __restrict__ xout,
    float* __restrict__ sqout, short* __restrict__ XH, short* __restrict__ XL) {
  __shared__ float red1[4];
  __shared__ float red2[4];
  const int i = blockIdx.x, t = threadIdx.x;
  const size_t e = (size_t)i * CD + t;
  float v = xin[e];
  if (add) v += add[e];
  float s = v;
#pragma unroll
  for (int m = 1; m < 64; m <<= 1) s += __shfl_xor(s, m, 64);
  if ((t & 63) == 0) red1[t >> 6] = s;
  __syncthreads();
  const float mean = (red1[0] + red1[1] + red1[2] + red1[3]) * (1.f / 256.f);
  const float d = v - mean;
  float s2 = d * d;
#pragma unroll
  for (int m = 1; m < 64; m <<= 1) s2 += __shfl_xor(s2, m, 64);
  if ((t & 63) == 0) red2[t >> 6] = s2;
  __syncthreads();
  const float var = (red2[0] + red2[1] + red2[2] + red2[3]) * (1.f / 256.f);
  const float xo = d * rsqrtf(var + 1e-5f) * g[t] + b[t];
  xout[e] = xo;
  if (SPLIT) {
    const unsigned ui = __float_as_uint(xo);
    XH[e] = (short)(ui >> 16);
    const float hf = __uint_as_float(ui & 0xffff0000u);
    XL[e] = (short)(__float_as_uint(xo - hf) >> 16);
    float s3 = xo * xo;
#pragma unroll
    for (int m = 1; m < 64; m <<= 1) s3 += __shfl_xor(s3, m, 64);
    __syncthreads();
    if ((t & 63) == 0) red1[t >> 6] = s3;
    __syncthreads();
    if (t == 0) sqout[i] = red1[0] + red1[1] + red1[2] + red1[3];
  }
}

// ---------------------------------------------------------------- launch
extern "C" void kernel_launch(void* const* d_in, const int* in_sizes, int n_in,
                              void* d_out, int out_size, void* d_ws, size_t ws_size,
                              hipStream_t stream) {
  const float* src  = (const float*)d_in[0];
  const float* c1w  = (const float*)d_in[1];
  const float* c1b  = (const float*)d_in[2];
  const float* c2w  = (const float*)d_in[3];
  const float* c2b  = (const float*)d_in[4];
  const float* nemb = (const float*)d_in[5];
  const float* Wq   = (const float*)d_in[6];
  const float* bq   = (const float*)d_in[7];
  const float* Wk   = (const float*)d_in[8];
  const float* bk   = (const float*)d_in[9];
  const float* Wv   = (const float*)d_in[10];
  const float* bv   = (const float*)d_in[11];
  const float* Wo   = (const float*)d_in[12];
  const float* bo   = (const float*)d_in[13];
  const float* W1   = (const float*)d_in[14];
  const float* b1   = (const float*)d_in[15];
  const float* W2   = (const float*)d_in[16];
  const float* b2   = (const float*)d_in[17];
  const float* ln1g = (const float*)d_in[18];
  const float* ln1b = (const float*)d_in[19];
  const float* ln2g = (const float*)d_in[20];
  const float* ln2b = (const float*)d_in[21];
  const float* ng   = (const float*)d_in[22];
  const float* nb   = (const float*)d_in[23];

  float* ws = (float*)d_ws;
  const size_t NC = (size_t)N_TOK * CD;          // 802816
  float* X    = ws;
  float* QKIN = X + NC;
  float* O1   = QKIN + NC;
  float* TMP  = O1 + NC;
  float* FF1  = TMP + NC;                        // bf16 FF1 lives here (short*)
  float* G    = FF1 + (size_t)N_TOK * DFFD;      // 3136*3136 (keys / conv1 partials)
  float* T1   = G + (size_t)N_TOK * N_TOK;       // 3136*128
  float* GPT  = T1 + (size_t)N_TOK * 128;        // 8*3136
  float* SQF  = GPT + (size_t)N_TOK * NHD;       // 3136
  short* QB16 = (short*)(SQF + N_TOK);
  short* KB16 = QB16 + NC;
  short* VT16 = KB16 + NC;
  short* XH   = VT16 + NC;                       // bf16 hi plane
  short* XL   = XH + NC;                         // bf16 lo plane
  short* WTC  = XL + NC;                         // conv1 wt bf16: 294912
  short* WQ16 = WTC + 294912;                    // 4*65536
  short* WK16 = WQ16 + 262144;
  short* WV16 = WK16 + 262144;
  short* WO16 = WV16 + 262144;
  short* W116 = WO16 + 262144;                   // 4*262144
  short* W216 = W116 + 1048576;
  int*   NEAR = (int*)(W216 + 1048576);          // 4 * 3136 ints
  short* FF1B = (short*)FF1;                     // bf16 FF1 view

  // prologue: weights -> bf16 (RNE; identical to previous stage-side cvt)
  cvt_k<<<512, 256, 0, stream>>>(Wq, WQ16, 262144);
  cvt_k<<<512, 256, 0, stream>>>(Wk, WK16, 262144);
  cvt_k<<<512, 256, 0, stream>>>(Wv, WV16, 262144);
  cvt_k<<<512, 256, 0, stream>>>(Wo, WO16, 262144);
  cvt_k<<<1024, 256, 0, stream>>>(W1, W116, 1048576);
  cvt_k<<<1024, 256, 0, stream>>>(W2, W216, 1048576);

  // tokens + conv positional encoder (direct conv, no im2col)
  transpose_k<<<dim3(98, 8), 256, 0, stream>>>(src, X, 256, N_TOK);
  wtr_k<<<1152, 256, 0, stream>>>(c1w, WTC);
  conv1_k<<<dim3(2, 98, 3), 256, 0, stream>>>(X, WTC, G);
  convred_k<<<1568, 256, 0, stream>>>(G, c1b, T1);
  conv2_k<<<98, 256, 0, stream>>>(T1, c2w, c2b, GPT);
  xsplit_k<<<N_TOK, 256, 0, stream>>>(X, XH, XL, SQF);
  (void)hipMemsetAsync(NEAR, 0, 4 * N_TOK * sizeof(int), stream);

  for (int l = 0; l < 4; ++l) {
    int* NEAR_l = NEAR + l * N_TOK;
    // ---- kNN graph -> near counts (hi/lo bf16 MFMA Gram, key-fused)
    gemm_syr4_k<<<1225, 256, 0, stream>>>(XH, XL, SQF, (unsigned*)G);
    topk_k<<<N_TOK, 64, 0, stream>>>((const unsigned*)G, NEAR_l);
    nearqk_k<<<N_TOK, 256, 0, stream>>>(X, NEAR_l, nemb, QKIN);
    // ---- fused Q/K/V projections (bf16 weights)
    proj32_k<<<dim3(4, 98, 3), 256, 0, stream>>>(QKIN, X,
        WQ16 + (size_t)l * 65536, WK16 + (size_t)l * 65536, WV16 + (size_t)l * 65536,
        bq + l * 256, bk + l * 256, bv + l * 256, QB16, KB16, VT16);
    // ---- attention (8 waves/block, j-eighths, in-block combine)
    attn_v8_k<<<dim3(49, 8), 512, 0, stream>>>(QB16, KB16, VT16, GPT, O1);
    gemm32_k<0, 0, 0><<<dim3(4, 98), 256, 0, stream>>>(O1, WO16 + (size_t)l * 65536, bo + l * 256, TMP, 256, 256);
    ln_k<0><<<N_TOK, 256, 0, stream>>>(X, TMP, ln1g + l * 256, ln1b + l * 256, X, nullptr, nullptr, nullptr);
    // ---- FFN (bf16 weights; bf16 intermediate)
    gemm32_k<1, 0, 1><<<dim3(16, 98), 256, 0, stream>>>(X, W116 + (size_t)l * 262144, b1 + l * 1024, FF1B, 1024, 256);
    gemm32_k<0, 1, 0><<<dim3(4, 98), 256, 0, stream>>>(FF1B, W216 + (size_t)l * 262144, b2 + l * 256, TMP, 256, 1024);
    // ln2 fused with X hi/lo split + row-sq (feeds next layer's Gram/topk)
    ln_k<1><<<N_TOK, 256, 0, stream>>>(X, TMP, ln2g + l * 256, ln2b + l * 256, X, SQF, XH, XL);
  }
  // final LN + transpose to [1,C,H,W]
  ln_k<0><<<N_TOK, 256, 0, stream>>>(X, nullptr, ng, nb, TMP, nullptr, nullptr, nullptr);
  transpose_k<<<dim3(8, 98), 256, 0, stream>>>(TMP, (float*)d_out, N_TOK, 256);
}

// Round 21
// 586.601 us; speedup vs baseline: 2.2903x; 1.0649x over previous
//
#include <hip/hip_runtime.h>
#include <math.h>

#define N_TOK 3136
#define CD    256
#define NHD   8
#define DH    32
#define DFFD  1024
#define SCALE 0.17677669529663687f  /* 32^-0.5 */
#define LOG2E 1.4426950408889634f
#define QSC   (SCALE * LOG2E)

typedef __attribute__((ext_vector_type(8))) short short8v;
typedef __attribute__((ext_vector_type(4))) float f32x4;

// ---------------------------------------------------------------- utils
__device__ __forceinline__ unsigned long long sx64(unsigned long long v, int m) {
  unsigned lo = (unsigned)__shfl_xor((int)(unsigned)(v & 0xffffffffull), m, 64);
  unsigned hi = (unsigned)__shfl_xor((int)(unsigned)(v >> 32), m, 64);
  return ((unsigned long long)hi << 32) | lo;
}

__device__ __forceinline__ unsigned f2mono(float v) {
  unsigned b = __float_as_uint(v);
  return (b & 0x80000000u) ? ~b : (b | 0x80000000u);
}

// fp32 -> bf16 round-to-nearest-even
__device__ __forceinline__ short bfr(float f) {
  unsigned u = __float_as_uint(f);
  unsigned r = (u + 0x7fffu + ((u >> 16) & 1u)) >> 16;
  return (short)r;
}

__device__ __forceinline__ short8v cvt8(float4 a, float4 b) {
  short8v r;
  r[0] = bfr(a.x); r[1] = bfr(a.y); r[2] = bfr(a.z); r[3] = bfr(a.w);
  r[4] = bfr(b.x); r[5] = bfr(b.y); r[6] = bfr(b.z); r[7] = bfr(b.w);
  return r;
}

// ------------- all weights -> bf16 in one dispatch (contiguous arena)
__global__ __launch_bounds__(256) void cvtall_k(const float* __restrict__ Wq,
    const float* __restrict__ Wk, const float* __restrict__ Wv,
    const float* __restrict__ Wo, const float* __restrict__ W1,
    const float* __restrict__ W2, short* __restrict__ out) {
  const int NQ = 262144, NB = 1048576, TOT = 4 * 262144 + 2 * 1048576;
  for (int i = blockIdx.x * 256 + threadIdx.x; i < TOT; i += gridDim.x * 256) {
    float v;
    if (i < NQ) v = Wq[i];
    else if (i < 2 * NQ) v = Wk[i - NQ];
    else if (i < 3 * NQ) v = Wv[i - 2 * NQ];
    else if (i < 4 * NQ) v = Wo[i - 3 * NQ];
    else if (i < 4 * NQ + NB) v = W1[i - 4 * NQ];
    else v = W2[i - 4 * NQ - NB];
    out[i] = bfr(v);
  }
}

// ------------------------------------------------- transpose (32x32 tiles)
__global__ __launch_bounds__(256) void transpose_k(const float* __restrict__ in,
    float* __restrict__ out, int R, int C) {
  __shared__ float ls[32][33];
  const int c0 = blockIdx.x * 32, r0 = blockIdx.y * 32;
  const int tx = threadIdx.x & 31, ty = threadIdx.x >> 5;
#pragma unroll
  for (int j = 0; j < 4; ++j) {
    int r = ty + j * 8;
    ls[r][tx] = in[(size_t)(r0 + r) * C + c0 + tx];
  }
  __syncthreads();
#pragma unroll
  for (int j = 0; j < 4; ++j) {
    int cc = ty + j * 8;
    out[(size_t)(c0 + cc) * R + r0 + tx] = ls[tx][cc];
  }
}

// ------------- conv1 weight transpose -> bf16: WT[r][co][ci] = w[co][ci][r]
__global__ __launch_bounds__(256) void wtr_k(const float* __restrict__ w,
                                             short* __restrict__ wt) {
  const int e = blockIdx.x * 256 + threadIdx.x;   // < 9*128*256 = 294912
  const int r = e >> 15;
  const int rem = e & 32767;
  const int co = rem >> 8, ci = rem & 255;
  wt[e] = bfr(w[((size_t)co * 256 + ci) * 9 + r]);
}

// -------- conv1 as direct tap-GEMM: grid (2, 98, 3), z = ky; bf16 weights
__global__ __launch_bounds__(256) void conv1_k(const float* __restrict__ X,
    const short* __restrict__ WT, float* __restrict__ P) {
  __shared__ __align__(16) short As[32][40];
  __shared__ __align__(16) short Bs[64][40];
  const int n0 = blockIdx.x * 64;
  const int m0 = blockIdx.y * 32;
  const int ky = blockIdx.z;
  const int t = threadIdx.x;
  const int w = t >> 6, l = t & 63;
  const int g = l >> 4, c = l & 15;
  const int wr = w >> 1, wc = w & 1;
  const int sr = t >> 2, seg = t & 3;
  const int p = m0 + (sr & 31);
  const int y = p / 56, x = p - y * 56;
  const int yy = y + ky - 1;
  f32x4 acc[2] = {};
  for (int kx = 0; kx < 3; ++kx) {
    const int xx = x + kx - 1;
    const bool valid = (t < 128) && ((unsigned)yy < 56u) && ((unsigned)xx < 56u);
    const float* Ap = X + (size_t)(yy * 56 + xx) * CD + seg * 8;
    const short* Bp = WT + ((size_t)(ky * 3 + kx) * 128 + n0 + sr) * CD + seg * 8;
    for (int k0 = 0; k0 < CD; k0 += 32) {
      float4 a1 = make_float4(0.f, 0.f, 0.f, 0.f), a2 = a1;
      if (valid) { a1 = *(const float4*)(Ap + k0); a2 = *(const float4*)(Ap + k0 + 4); }
      const short8v bv = *(const short8v*)(Bp + k0);
      __syncthreads();
      if (t < 128) *(short8v*)&As[sr][seg * 8] = cvt8(a1, a2);
      *(short8v*)&Bs[sr][seg * 8] = bv;
      __syncthreads();
      const short8v af = *(const short8v*)&As[wr * 16 + c][g * 8];
      const short8v bf0 = *(const short8v*)&Bs[wc * 32 + c][g * 8];
      const short8v bf1 = *(const short8v*)&Bs[wc * 32 + 16 + c][g * 8];
      acc[0] = __builtin_amdgcn_mfma_f32_16x16x32_bf16(af, bf0, acc[0], 0, 0, 0);
      acc[1] = __builtin_amdgcn_mfma_f32_16x16x32_bf16(af, bf1, acc[1], 0, 0, 0);
    }
  }
#pragma unroll
  for (int ni = 0; ni < 2; ++ni) {
    const int col = n0 + wc * 32 + ni * 16 + c;
#pragma unroll
    for (int q = 0; q < 4; ++q) {
      const int m = m0 + wr * 16 + g * 4 + q;
      P[((size_t)ky * N_TOK + m) * 128 + col] = acc[ni][q];
    }
  }
}

// ----------------------- reduce conv1 tap partials + bias + relu -> T1
__global__ __launch_bounds__(256) void convred_k(const float* __restrict__ P,
    const float* __restrict__ b, float* __restrict__ T1) {
  const int e = blockIdx.x * 256 + threadIdx.x;   // < 3136*128
  const float v = P[e] + P[401408 + e] + P[802816 + e] + b[e & 127];
  T1[e] = fmaxf(v, 0.f);
}

// ---- 32x64-tile bf16 MFMA GEMM NT; A16: A already bf16; O16: bf16 out.
template <int RELU, int A16, int O16>
__global__ __launch_bounds__(256) void gemm32_k(const void* __restrict__ Av,
    const short* __restrict__ Bw, const float* __restrict__ bias,
    void* __restrict__ Cv, int N, int K) {
  __shared__ __align__(16) short As[32][40];
  __shared__ __align__(16) short Bs[64][40];
  const int n0 = blockIdx.x * 64;
  const int m0 = blockIdx.y * 32;
  const int t = threadIdx.x;
  const int w = t >> 6, l = t & 63;
  const int g = l >> 4, c = l & 15;
  const int wr = w >> 1, wc = w & 1;
  const int sr = t >> 2, seg = t & 3;
  const float* Apf = (const float*)Av + (size_t)(m0 + (sr & 31)) * K + seg * 8;
  const short* Aps = (const short*)Av + (size_t)(m0 + (sr & 31)) * K + seg * 8;
  const short* Bp = Bw + (size_t)(n0 + sr) * K + seg * 8;
  f32x4 acc[2] = {};
  for (int k0 = 0; k0 < K; k0 += 32) {
    short8v a8;
    if (A16) {
      if (t < 128) a8 = *(const short8v*)(Aps + k0);
    } else {
      float4 a1 = make_float4(0.f, 0.f, 0.f, 0.f), a2 = a1;
      if (t < 128) { a1 = *(const float4*)(Apf + k0); a2 = *(const float4*)(Apf + k0 + 4); }
      a8 = cvt8(a1, a2);
    }
    const short8v bv = *(const short8v*)(Bp + k0);
    __syncthreads();
    if (t < 128) *(short8v*)&As[sr][seg * 8] = a8;
    *(short8v*)&Bs[sr][seg * 8] = bv;
    __syncthreads();
    const short8v af = *(const short8v*)&As[wr * 16 + c][g * 8];
    const short8v bf0 = *(const short8v*)&Bs[wc * 32 + c][g * 8];
    const short8v bf1 = *(const short8v*)&Bs[wc * 32 + 16 + c][g * 8];
    acc[0] = __builtin_amdgcn_mfma_f32_16x16x32_bf16(af, bf0, acc[0], 0, 0, 0);
    acc[1] = __builtin_amdgcn_mfma_f32_16x16x32_bf16(af, bf1, acc[1], 0, 0, 0);
  }
#pragma unroll
  for (int ni = 0; ni < 2; ++ni) {
    const int col = n0 + wc * 32 + ni * 16 + c;
    const float bb = bias ? bias[col] : 0.f;
#pragma unroll
    for (int q = 0; q < 4; ++q) {
      const int m = m0 + wr * 16 + g * 4 + q;
      float v = acc[ni][q] + bb;
      if (RELU) v = fmaxf(v, 0.f);
      if (O16) ((short*)Cv)[(size_t)m * N + col] = bfr(v);
      else ((float*)Cv)[(size_t)m * N + col] = v;
    }
  }
}

// ---------------- fused Q/K/V projections, bf16 weights, bf16 outputs
__global__ __launch_bounds__(256) void proj32_k(const float* __restrict__ QKIN,
    const float* __restrict__ X, const short* __restrict__ Wq,
    const short* __restrict__ Wk, const short* __restrict__ Wv,
    const float* __restrict__ bq, const float* __restrict__ bk,
    const float* __restrict__ bv, short* __restrict__ QB,
    short* __restrict__ KB, short* __restrict__ VT) {
  __shared__ __align__(16) short As[32][40];
  __shared__ __align__(16) short Bs[64][40];
  const int sel = blockIdx.z;
  const int n0 = blockIdx.x * 64;
  const int m0 = blockIdx.y * 32;
  const float* A = (sel < 2) ? QKIN : X;
  const short* B = (sel == 0) ? Wq : (sel == 1) ? Wk : Wv;
  const float* bias = (sel == 0) ? bq : (sel == 1) ? bk : bv;
  const int t = threadIdx.x;
  const int w = t >> 6, l = t & 63;
  const int g = l >> 4, c = l & 15;
  const int wr = w >> 1, wc = w & 1;
  const int sr = t >> 2, seg = t & 3;
  const float* Ap = A + (size_t)(m0 + (sr & 31)) * CD + seg * 8;
  const short* Bp = B + (size_t)(n0 + sr) * CD + seg * 8;
  f32x4 acc[2] = {};
  for (int k0 = 0; k0 < CD; k0 += 32) {
    float4 a1 = make_float4(0.f, 0.f, 0.f, 0.f), a2 = a1;
    if (t < 128) { a1 = *(const float4*)(Ap + k0); a2 = *(const float4*)(Ap + k0 + 4); }
    const short8v bv8 = *(const short8v*)(Bp + k0);
    __syncthreads();
    if (t < 128) *(short8v*)&As[sr][seg * 8] = cvt8(a1, a2);
    *(short8v*)&Bs[sr][seg * 8] = bv8;
    __syncthreads();
    const short8v af = *(const short8v*)&As[wr * 16 + c][g * 8];
    const short8v bf0 = *(const short8v*)&Bs[wc * 32 + c][g * 8];
    const short8v bf1 = *(const short8v*)&Bs[wc * 32 + 16 + c][g * 8];
    acc[0] = __builtin_amdgcn_mfma_f32_16x16x32_bf16(af, bf0, acc[0], 0, 0, 0);
    acc[1] = __builtin_amdgcn_mfma_f32_16x16x32_bf16(af, bf1, acc[1], 0, 0, 0);
  }
#pragma unroll
  for (int ni = 0; ni < 2; ++ni) {
    const int col = n0 + wc * 32 + ni * 16 + c;
    const float bb = bias[col];
    if (sel == 2) {
      const int mb = m0 + wr * 16 + g * 4;
      const int pidx = (mb & ~31) + ((mb >> 4) & 1) * 4 + ((mb >> 2) & 3) * 8;
      uint2 pk;
      const float v0 = acc[ni][0] + bb, v1 = acc[ni][1] + bb;
      const float v2 = acc[ni][2] + bb, v3 = acc[ni][3] + bb;
      pk.x = (unsigned)(unsigned short)bfr(v0) | ((unsigned)(unsigned short)bfr(v1) << 16);
      pk.y = (unsigned)(unsigned short)bfr(v2) | ((unsigned)(unsigned short)bfr(v3) << 16);
      *(uint2*)&VT[(size_t)col * N_TOK + pidx] = pk;
    } else {
      short* Ct = (sel == 0) ? QB : KB;
      const float qs = (sel == 0) ? QSC : 1.f;
      const int hh = col >> 5, dd = col & 31;
#pragma unroll
      for (int q = 0; q < 4; ++q) {
        const int m = m0 + wr * 16 + g * 4 + q;
        Ct[((size_t)hh * N_TOK + m) * 32 + dd] = bfr((acc[ni][q] + bb) * qs);
      }
    }
  }
}

// --------------- X -> bf16 hi/lo planes + row ||x||^2 (prologue only)
__global__ __launch_bounds__(256) void xsplit_k(const float* __restrict__ X,
    short* __restrict__ XH, short* __restrict__ XL, float* __restrict__ sq) {
  __shared__ float red[4];
  const int i = blockIdx.x, t = threadIdx.x;
  const size_t e = (size_t)i * CD + t;
  const float v = X[e];
  const unsigned ui = __float_as_uint(v);
  XH[e] = (short)(ui >> 16);
  const float hf = __uint_as_float(ui & 0xffff0000u);
  XL[e] = (short)(__float_as_uint(v - hf) >> 16);
  float s = v * v;
#pragma unroll
  for (int m = 1; m < 64; m <<= 1) s += __shfl_xor(s, m, 64);
  if ((t & 63) == 0) red[t >> 6] = s;
  __syncthreads();
  if (t == 0) sq[i] = red[0] + red[1] + red[2] + red[3];
}

// ---- Gram, key-fused: mirror via LDS transpose (coalesced stores).
// Keys bit-identical to scattered-write version: v is bit-symmetric (same
// k-order, commutative products) and mirror formula (sq[col]-2v)+sq[row].
__global__ __launch_bounds__(256) void gemm_syr4_k(const short* __restrict__ XH,
    const short* __restrict__ XL, const float* __restrict__ SQ,
    unsigned* __restrict__ Ck) {
  __shared__ __align__(16) short sbuf[4][64][40];   // staging; reused as tb
  short (*AsH)[40] = sbuf[0];
  short (*AsL)[40] = sbuf[1];
  short (*BsH)[40] = sbuf[2];
  short (*BsL)[40] = sbuf[3];
  int bid = blockIdx.x;
  int bi = (int)((sqrtf(8.f * (float)bid + 1.f) - 1.f) * 0.5f);
  while ((bi + 1) * (bi + 2) / 2 <= bid) ++bi;
  while (bi * (bi + 1) / 2 > bid) --bi;
  const int bj = bid - bi * (bi + 1) / 2;
  const int m0 = bi * 64, n0 = bj * 64;
  const int t = threadIdx.x;
  const int w = t >> 6, l = t & 63;
  const int g = l >> 4, c = l & 15;
  const int wr = w >> 1, wc = w & 1;
  const int sr = t >> 2, seg = t & 3;
  const size_t arow = (size_t)(m0 + sr) * CD + seg * 8;
  const size_t brow = (size_t)(n0 + sr) * CD + seg * 8;
  f32x4 acc[2][2] = {};
  for (int k0 = 0; k0 < CD; k0 += 32) {
    const short8v ah = *(const short8v*)&XH[arow + k0];
    const short8v al = *(const short8v*)&XL[arow + k0];
    const short8v bh = *(const short8v*)&XH[brow + k0];
    const short8v bl = *(const short8v*)&XL[brow + k0];
    __syncthreads();
    *(short8v*)&AsH[sr][seg * 8] = ah;
    *(short8v*)&AsL[sr][seg * 8] = al;
    *(short8v*)&BsH[sr][seg * 8] = bh;
    *(short8v*)&BsL[sr][seg * 8] = bl;
    __syncthreads();
    short8v afH[2], afL[2], bfH[2], bfL[2];
#pragma unroll
    for (int mi = 0; mi < 2; ++mi) {
      afH[mi] = *(const short8v*)&AsH[wr * 32 + mi * 16 + c][g * 8];
      afL[mi] = *(const short8v*)&AsL[wr * 32 + mi * 16 + c][g * 8];
    }
#pragma unroll
    for (int ni = 0; ni < 2; ++ni) {
      bfH[ni] = *(const short8v*)&BsH[wc * 32 + ni * 16 + c][g * 8];
      bfL[ni] = *(const short8v*)&BsL[wc * 32 + ni * 16 + c][g * 8];
    }
#pragma unroll
    for (int mi = 0; mi < 2; ++mi)
#pragma unroll
      for (int ni = 0; ni < 2; ++ni) {
        acc[mi][ni] = __builtin_amdgcn_mfma_f32_16x16x32_bf16(afH[mi], bfH[ni], acc[mi][ni], 0, 0, 0);
        acc[mi][ni] = __builtin_amdgcn_mfma_f32_16x16x32_bf16(afH[mi], bfL[ni], acc[mi][ni], 0, 0, 0);
        acc[mi][ni] = __builtin_amdgcn_mfma_f32_16x16x32_bf16(afL[mi], bfH[ni], acc[mi][ni], 0, 0, 0);
      }
  }
  // ---- epilogue: direct (coalesced) stores + raw tile transposed to LDS
  __syncthreads();                                  // all staging reads done
  float (*tb)[65] = (float(*)[65])&sbuf[0][0][0];   // 64*65*4 = 16640B < 20480B
#pragma unroll
  for (int mi = 0; mi < 2; ++mi)
#pragma unroll
    for (int ni = 0; ni < 2; ++ni) {
      const int cl = wc * 32 + ni * 16 + c;         // local col
      const float sqc = SQ[n0 + cl];
#pragma unroll
      for (int q = 0; q < 4; ++q) {
        const int ml = wr * 32 + mi * 16 + g * 4 + q;  // local row
        const float v = acc[mi][ni][q];
        Ck[(size_t)(m0 + ml) * N_TOK + n0 + cl] = f2mono((SQ[m0 + ml] - 2.f * v) + sqc);
        tb[cl][ml] = v;
      }
    }
  __syncthreads();
  // ---- mirror pass: fully coalesced (64 consecutive cols per wave)
  const int mr = t >> 6;          // wave id -> row offset within group of 4
  const int mc = t & 63;          // lane -> col
#pragma unroll
  for (int rr = 0; rr < 16; ++rr) {
    const int row = rr * 4 + mr;                    // mirror row (tile col)
    const float v = tb[row][mc];
    Ck[(size_t)(n0 + row) * N_TOK + m0 + mc] =
        f2mono((SQ[n0 + row] - 2.f * v) + SQ[m0 + mc]);
  }
}

// ------------------- conv2 (8ch) -> writes gpT [8][N_TOK] * log2e directly
__global__ __launch_bounds__(256) void conv2_k(const float* __restrict__ t1,
    const float* __restrict__ w, const float* __restrict__ b,
    float* __restrict__ gpT) {
  __shared__ float ws3[9 * 8 * 132];
  const int t = threadIdx.x;
  for (int e = t; e < 9216; e += 256) {
    int r = e >> 10;
    int rem = e & 1023;
    int co = rem >> 7;
    int ci = rem & 127;
    ws3[(r * 8 + co) * 132 + ci] = w[((size_t)co * 128 + ci) * 9 + r];
  }
  __syncthreads();
  const int pix = blockIdx.x * 32 + (t >> 3);
  const int co = t & 7;
  const int y = pix / 56, x = pix - y * 56;
  float acc = b[co];
  for (int ky = 0; ky < 3; ++ky) {
    int yy = y + ky - 1;
    if (yy < 0 || yy >= 56) continue;
    for (int kx = 0; kx < 3; ++kx) {
      int xx = x + kx - 1;
      if (xx < 0 || xx >= 56) continue;
      const float4* tp = (const float4*)&t1[(size_t)(yy * 56 + xx) * 128];
      const float* wp = &ws3[((ky * 3 + kx) * 8 + co) * 132];
#pragma unroll
      for (int c4 = 0; c4 < 32; ++c4) {
        const float4 tv = tp[c4];
        const float4 wv = *(const float4*)&wp[c4 * 4];
        acc += tv.x * wv.x + tv.y * wv.y + tv.z * wv.z + tv.w * wv.w;
      }
    }
  }
  gpT[co * N_TOK + pix] = LOG2E / (1.f + expf(-acc));
}

// ---- top-16 NN + in-degree, v7: one wave/row, per-lane TOP-4 cache over
// precomputed mono keys; rare refill. Bit-exact lex top_k.
__global__ __launch_bounds__(64) void topk_k(const unsigned* __restrict__ Gk,
    int* __restrict__ near) {
  const int i = blockIdx.x;
  const int t = threadIdx.x;            // lane 0..63
  const unsigned* __restrict__ Krow = Gk + (size_t)i * N_TOK;
  unsigned cv0 = 0xffffffffu, cv1 = 0xffffffffu, cv2 = 0xffffffffu, cv3 = 0xffffffffu;
  int ce0 = 0, ce1 = 0, ce2 = 0, ce3 = 0;
#pragma unroll
  for (int e = 0; e < 49; ++e) {
    const unsigned v = Krow[t + (e << 6)];    // 49*64 = 3136 exactly
    const bool i0 = v < cv0, i1 = v < cv1, i2 = v < cv2, i3 = v < cv3;
    cv3 = i2 ? cv2 : (i3 ? v : cv3);  ce3 = i2 ? ce2 : (i3 ? e : ce3);
    cv2 = i1 ? cv1 : (i2 ? v : cv2);  ce2 = i1 ? ce1 : (i2 ? e : ce2);
    cv1 = i0 ? cv0 : (i1 ? v : cv1);  ce1 = i0 ? ce0 : (i1 ? e : ce1);
    cv0 = i0 ? v : cv0;               ce0 = i0 ? e : ce0;
  }
  unsigned long long killed = 0ull;
#pragma unroll 1
  for (int r = 0; r < 16; ++r) {
    const unsigned long long mine =
        ((unsigned long long)cv0 << 32) | (unsigned)(t + (ce0 << 6));
    unsigned long long best = mine;
#pragma unroll
    for (int m = 1; m < 64; m <<= 1) {
      const unsigned long long o = sx64(best, m);
      best = (o < best) ? o : best;
    }
    if (t == 0) atomicAdd(&near[(unsigned)(best & 0xffffffffu)], 1);
    if (mine == best && r < 15) {
      killed |= 1ull << ce0;
      cv0 = cv1; ce0 = ce1;
      cv1 = cv2; ce1 = ce2;
      cv2 = cv3; ce2 = ce3;
      cv3 = 0xffffffffu; ce3 = 0;
      if (cv0 == 0xffffffffu) {
#pragma unroll
        for (int e = 0; e < 49; ++e) {
          unsigned v = Krow[t + (e << 6)];
          v = (((killed >> e) & 1ull) != 0ull) ? 0xffffffffu : v;
          const bool i0 = v < cv0, i1 = v < cv1, i2 = v < cv2, i3 = v < cv3;
          cv3 = i2 ? cv2 : (i3 ? v : cv3);  ce3 = i2 ? ce2 : (i3 ? e : ce3);
          cv2 = i1 ? cv1 : (i2 ? v : cv2);  ce2 = i1 ? ce1 : (i2 ? e : ce2);
          cv1 = i0 ? cv0 : (i1 ? v : cv1);  ce1 = i0 ? ce0 : (i1 ? e : ce1);
          cv0 = i0 ? v : cv0;               ce0 = i0 ? e : ce0;
        }
      }
    }
  }
}

// ------------- fused max(near) + qk_in = x + emb[ni(near)] (one row/block)
__global__ __launch_bounds__(256) void nearqk_k(const float* __restrict__ x,
    const int* __restrict__ near, const float* __restrict__ emb,
    float* __restrict__ qkin) {
  __shared__ int sm[4];
  const int i = blockIdx.x, t = threadIdx.x;
  int m = 0;
  for (int j = t; j < N_TOK; j += 256) m = max(m, near[j]);
#pragma unroll
  for (int s = 1; s < 64; s <<= 1) m = max(m, __shfl_xor(m, s, 64));
  if ((t & 63) == 0) sm[t >> 6] = m;
  __syncthreads();
  const int mv = max(max(sm[0], sm[1]), max(sm[2], sm[3]));
  const int ni = (int)((float)near[i] / (float)mv * 9.0f);
  qkin[(size_t)i * CD + t] = x[(size_t)i * CD + t] + emb[ni * CD + t];
}

// ---- flash attention v8: 8 waves/block (512 thr), 64 queries/wave,
// j-eighths per wave; per-head Q/K layout; in-block 8-way combine.
__global__ __launch_bounds__(512) void attn_v8_k(const short* __restrict__ Qb,
    const short* __restrict__ Kb, const short* __restrict__ Vt,
    const float* __restrict__ gpT, float* __restrict__ O1) {
  __shared__ float o_l[8][64][36];
  __shared__ float ml_l[8][64][2];
  const int h = blockIdx.y;
  const int qb = blockIdx.x * 64;
  const int t = threadIdx.x;
  const int w = t >> 6, l = t & 63;
  const int g = l >> 4, c = l & 15;
  const size_t hR = (size_t)h * N_TOK;      // per-head row base (Q/K/gpT)
  const size_t hoff = (size_t)h * DH;       // VT d-row base
  short8v qf[4];
  float gpi[4];
#pragma unroll
  for (int gr = 0; gr < 4; ++gr) {
    qf[gr] = *(const short8v*)&Qb[(hR + qb + gr * 16 + c) * 32 + g * 8];
    gpi[gr] = gpT[hR + qb + gr * 16 + c];
  }
  const int jt0 = w ? (7 + 6 * (w - 1)) : 0;   // {7,6,6,6,6,6,6,6} = 49
  const int jt1 = jt0 + (w ? 6 : 7);
  float mr[4] = {-INFINITY, -INFINITY, -INFINITY, -INFINITY};
  float lp[4] = {0.f, 0.f, 0.f, 0.f};
  f32x4 oa[4][2] = {};
  const f32x4 zz = {0.f, 0.f, 0.f, 0.f};

#pragma unroll 1
  for (int jt = jt0; jt < jt1; ++jt) {
    const int j0 = jt * 64;
    short8v kf[4], vf[4];
    float4 gj[4];
#pragma unroll
    for (int sub = 0; sub < 4; ++sub)
      kf[sub] = *(const short8v*)&Kb[(hR + j0 + sub * 16 + c) * 32 + g * 8];
#pragma unroll
    for (int ch = 0; ch < 2; ++ch)
#pragma unroll
      for (int ds = 0; ds < 2; ++ds)
        vf[ch * 2 + ds] = *(const short8v*)&Vt[(hoff + ds * 16 + c) * (size_t)N_TOK + j0 + ch * 32 + g * 8];
#pragma unroll
    for (int sub = 0; sub < 4; ++sub)
      gj[sub] = *(const float4*)&gpT[hR + j0 + sub * 16 + g * 4];
#pragma unroll
    for (int gr = 0; gr < 4; ++gr) {
      f32x4 sacc[4];
#pragma unroll
      for (int sub = 0; sub < 4; ++sub)
        sacc[sub] = __builtin_amdgcn_mfma_f32_16x16x32_bf16(kf[sub], qf[gr], zz, 0, 0, 0);
      float sv[16];
#pragma unroll
      for (int sub = 0; sub < 4; ++sub) {
        sv[sub * 4 + 0] = sacc[sub][0] + fabsf(gpi[gr] - gj[sub].x);
        sv[sub * 4 + 1] = sacc[sub][1] + fabsf(gpi[gr] - gj[sub].y);
        sv[sub * 4 + 2] = sacc[sub][2] + fabsf(gpi[gr] - gj[sub].z);
        sv[sub * 4 + 3] = sacc[sub][3] + fabsf(gpi[gr] - gj[sub].w);
      }
      float a0 = fmaxf(sv[0], sv[1]),  a1 = fmaxf(sv[2], sv[3]);
      float a2 = fmaxf(sv[4], sv[5]),  a3 = fmaxf(sv[6], sv[7]);
      float a4 = fmaxf(sv[8], sv[9]),  a5 = fmaxf(sv[10], sv[11]);
      float a6 = fmaxf(sv[12], sv[13]), a7 = fmaxf(sv[14], sv[15]);
      const float mx = fmaxf(fmaxf(fmaxf(a0, a1), fmaxf(a2, a3)),
                             fmaxf(fmaxf(a4, a5), fmaxf(a6, a7)));
      if (!__all(mx - mr[gr] <= 11.f)) {
        float mn = mx;
        mn = fmaxf(mn, __shfl_xor(mn, 16, 64));
        mn = fmaxf(mn, __shfl_xor(mn, 32, 64));
        mn = fmaxf(mn, mr[gr]);
        const float sc = __builtin_amdgcn_exp2f(mr[gr] - mn);
        oa[gr][0][0] *= sc; oa[gr][0][1] *= sc; oa[gr][0][2] *= sc; oa[gr][0][3] *= sc;
        oa[gr][1][0] *= sc; oa[gr][1][1] *= sc; oa[gr][1][2] *= sc; oa[gr][1][3] *= sc;
        lp[gr] *= sc;
        mr[gr] = mn;
      }
      float p[16];
#pragma unroll
      for (int e = 0; e < 16; ++e) p[e] = __builtin_amdgcn_exp2f(sv[e] - mr[gr]);
      const float ps0 = (p[0] + p[1]) + (p[2] + p[3]);
      const float ps1 = (p[4] + p[5]) + (p[6] + p[7]);
      const float ps2 = (p[8] + p[9]) + (p[10] + p[11]);
      const float ps3 = (p[12] + p[13]) + (p[14] + p[15]);
      lp[gr] += (ps0 + ps1) + (ps2 + ps3);
      union { unsigned u[4]; short8v s; } pf0, pf1;
#pragma unroll
      for (int sub = 0; sub < 2; ++sub) {
        pf0.u[2 * sub + 0] = __builtin_amdgcn_perm(__float_as_uint(p[4 * sub + 1]),
                                                   __float_as_uint(p[4 * sub + 0]), 0x07060302u);
        pf0.u[2 * sub + 1] = __builtin_amdgcn_perm(__float_as_uint(p[4 * sub + 3]),
                                                   __float_as_uint(p[4 * sub + 2]), 0x07060302u);
        pf1.u[2 * sub + 0] = __builtin_amdgcn_perm(__float_as_uint(p[8 + 4 * sub + 1]),
                                                   __float_as_uint(p[8 + 4 * sub + 0]), 0x07060302u);
        pf1.u[2 * sub + 1] = __builtin_amdgcn_perm(__float_as_uint(p[8 + 4 * sub + 3]),
                                                   __float_as_uint(p[8 + 4 * sub + 2]), 0x07060302u);
      }
      oa[gr][0] = __builtin_amdgcn_mfma_f32_16x16x32_bf16(vf[0], pf0.s, oa[gr][0], 0, 0, 0);
      oa[gr][1] = __builtin_amdgcn_mfma_f32_16x16x32_bf16(vf[1], pf0.s, oa[gr][1], 0, 0, 0);
      oa[gr][0] = __builtin_amdgcn_mfma_f32_16x16x32_bf16(vf[2], pf1.s, oa[gr][0], 0, 0, 0);
      oa[gr][1] = __builtin_amdgcn_mfma_f32_16x16x32_bf16(vf[3], pf1.s, oa[gr][1], 0, 0, 0);
    }
  }
#pragma unroll
  for (int gr = 0; gr < 4; ++gr) {
    lp[gr] += __shfl_xor(lp[gr], 16, 64);
    lp[gr] += __shfl_xor(lp[gr], 32, 64);
#pragma unroll
    for (int ds = 0; ds < 2; ++ds)
      *(f32x4*)&o_l[w][gr * 16 + c][ds * 16 + g * 4] = oa[gr][ds];
    if (g == 0) {
      ml_l[w][gr * 16 + c][0] = mr[gr];
      ml_l[w][gr * 16 + c][1] = lp[gr];
    }
  }
  __syncthreads();
  // ---- combine 8 partials: thread -> (q = t>>3, d0 = (t&7)*4)
  const int q = t >> 3, d0 = (t & 7) * 4;
  float M = -INFINITY;
#pragma unroll
  for (int sp = 0; sp < 8; ++sp) M = fmaxf(M, ml_l[sp][q][0]);
  float den = 0.f;
  f32x4 num = {0.f, 0.f, 0.f, 0.f};
#pragma unroll
  for (int sp = 0; sp < 8; ++sp) {
    const float wg = __builtin_amdgcn_exp2f(ml_l[sp][q][0] - M);
    den += wg * ml_l[sp][q][1];
    const f32x4 ov = *(const f32x4*)&o_l[sp][q][d0];
    num[0] += wg * ov[0]; num[1] += wg * ov[1];
    num[2] += wg * ov[2]; num[3] += wg * ov[3];
  }
  const float inv = 1.f / den;
  f32x4 r = {num[0] * inv, num[1] * inv, num[2] * inv, num[3] * inv};
  *(f32x4*)&O1[(size_t)(qb + q) * CD + hoff + d0] = r;
}

// ------ LayerNorm (+residual); SPLIT=1 also emits XH/XL planes + row-sq
template <int SPLIT>
__global__ __launch_bounds__(256) void ln_k(const float* __restrict__ xin,
    const float* __restrict__ add, const float* __restrict__ g,
    const float* __restrict__ b, float* __restrict__ xout,
    float* __restrict__ sqout, short* __restrict__ XH, short* __restrict__ XL) {
  __shared__ float red1[4];
  __shared__ float red2[4];
  const int i = blockIdx.x, t = threadIdx.x;
  const size_t e = (size_t)i * CD + t;
  float v = xin[e];
  if (add) v += add[e];
  float s = v;
#pragma unroll
  for (int m = 1; m < 64; m <<= 1) s += __shfl_xor(s, m, 64);
  if ((t & 63) == 0) red1[t >> 6] = s;
  __syncthreads();
  const float mean = (red1[0] + red1[1] + red1[2] + red1[3]) * (1.f / 256.f);
  const float d = v - mean;
  float s2 = d * d;
#pragma unroll
  for (int m = 1; m < 64; m <<= 1) s2 += __shfl_xor(s2, m, 64);
  if ((t & 63) == 0) red2[t >> 6] = s2;
  __syncthreads();
  const float var = (red2[0] + red2[1] + red2[2] + red2[3]) * (1.f / 256.f);
  const float xo = d * rsqrtf(var + 1e-5f) * g[t] + b[t];
  xout[e] = xo;
  if (SPLIT) {
    const unsigned ui = __float_as_uint(xo);
    XH[e] = (short)(ui >> 16);
    const float hf = __uint_as_float(ui & 0xffff0000u);
    XL[e] = (short)(__float_as_uint(xo - hf) >> 16);
    float s3 = xo * xo;
#pragma unroll
    for (int m = 1; m < 64; m <<= 1) s3 += __shfl_xor(s3, m, 64);
    __syncthreads();
    if ((t & 63) == 0) red1[t >> 6] = s3;
    __syncthreads();
    if (t == 0) sqout[i] = red1[0] + red1[1] + red1[2] + red1[3];
  }
}

// ---------------------------------------------------------------- launch
extern "C" void kernel_launch(void* const* d_in, const int* in_sizes, int n_in,
                              void* d_out, int out_size, void* d_ws, size_t ws_size,
                              hipStream_t stream) {
  const float* src  = (const float*)d_in[0];
  const float* c1w  = (const float*)d_in[1];
  const float* c1b  = (const float*)d_in[2];
  const float* c2w  = (const float*)d_in[3];
  const float* c2b  = (const float*)d_in[4];
  const float* nemb = (const float*)d_in[5];
  const float* Wq   = (const float*)d_in[6];
  const float* bq   = (const float*)d_in[7];
  const float* Wk   = (const float*)d_in[8];
  const float* bk   = (const float*)d_in[9];
  const float* Wv   = (const float*)d_in[10];
  const float* bv   = (const float*)d_in[11];
  const float* Wo   = (const float*)d_in[12];
  const float* bo   = (const float*)d_in[13];
  const float* W1   = (const float*)d_in[14];
  const float* b1   = (const float*)d_in[15];
  const float* W2   = (const float*)d_in[16];
  const float* b2   = (const float*)d_in[17];
  const float* ln1g = (const float*)d_in[18];
  const float* ln1b = (const float*)d_in[19];
  const float* ln2g = (const float*)d_in[20];
  const float* ln2b = (const float*)d_in[21];
  const float* ng   = (const float*)d_in[22];
  const float* nb   = (const float*)d_in[23];

  float* ws = (float*)d_ws;
  const size_t NC = (size_t)N_TOK * CD;          // 802816
  float* X    = ws;
  float* QKIN = X + NC;
  float* O1   = QKIN + NC;
  float* TMP  = O1 + NC;
  float* FF1  = TMP + NC;                        // bf16 FF1 lives here (short*)
  float* G    = FF1 + (size_t)N_TOK * DFFD;      // 3136*3136 (keys / conv1 partials)
  float* T1   = G + (size_t)N_TOK * N_TOK;       // 3136*128
  float* GPT  = T1 + (size_t)N_TOK * 128;        // 8*3136
  float* SQF  = GPT + (size_t)N_TOK * NHD;       // 3136
  short* QB16 = (short*)(SQF + N_TOK);
  short* KB16 = QB16 + NC;
  short* VT16 = KB16 + NC;
  short* XH   = VT16 + NC;                       // bf16 hi plane
  short* XL   = XH + NC;                         // bf16 lo plane
  short* WTC  = XL + NC;                         // conv1 wt bf16: 294912
  short* WARN = WTC + 294912;                    // bf16 weight arena (contiguous)
  short* WQ16 = WARN;                            // 4*65536
  short* WK16 = WQ16 + 262144;
  short* WV16 = WK16 + 262144;
  short* WO16 = WV16 + 262144;
  short* W116 = WO16 + 262144;                   // 4*262144
  short* W216 = W116 + 1048576;
  int*   NEAR = (int*)(W216 + 1048576);          // 4 * 3136 ints
  short* FF1B = (short*)FF1;                     // bf16 FF1 view

  // prologue: all weights -> bf16 in one dispatch
  cvtall_k<<<4096, 256, 0, stream>>>(Wq, Wk, Wv, Wo, W1, W2, WARN);

  // tokens + conv positional encoder (direct conv, no im2col)
  transpose_k<<<dim3(98, 8), 256, 0, stream>>>(src, X, 256, N_TOK);
  wtr_k<<<1152, 256, 0, stream>>>(c1w, WTC);
  conv1_k<<<dim3(2, 98, 3), 256, 0, stream>>>(X, WTC, G);
  convred_k<<<1568, 256, 0, stream>>>(G, c1b, T1);
  conv2_k<<<98, 256, 0, stream>>>(T1, c2w, c2b, GPT);
  xsplit_k<<<N_TOK, 256, 0, stream>>>(X, XH, XL, SQF);
  (void)hipMemsetAsync(NEAR, 0, 4 * N_TOK * sizeof(int), stream);

  for (int l = 0; l < 4; ++l) {
    int* NEAR_l = NEAR + l * N_TOK;
    // ---- kNN graph -> near counts (key-fused Gram, coalesced mirror)
    gemm_syr4_k<<<1225, 256, 0, stream>>>(XH, XL, SQF, (unsigned*)G);
    topk_k<<<N_TOK, 64, 0, stream>>>((const unsigned*)G, NEAR_l);
    nearqk_k<<<N_TOK, 256, 0, stream>>>(X, NEAR_l, nemb, QKIN);
    // ---- fused Q/K/V projections (bf16 weights)
    proj32_k<<<dim3(4, 98, 3), 256, 0, stream>>>(QKIN, X,
        WQ16 + (size_t)l * 65536, WK16 + (size_t)l * 65536, WV16 + (size_t)l * 65536,
        bq + l * 256, bk + l * 256, bv + l * 256, QB16, KB16, VT16);
    // ---- attention (8 waves/block, j-eighths, in-block combine)
    attn_v8_k<<<dim3(49, 8), 512, 0, stream>>>(QB16, KB16, VT16, GPT, O1);
    gemm32_k<0, 0, 0><<<dim3(4, 98), 256, 0, stream>>>(O1, WO16 + (size_t)l * 65536, bo + l * 256, TMP, 256, 256);
    ln_k<0><<<N_TOK, 256, 0, stream>>>(X, TMP, ln1g + l * 256, ln1b + l * 256, X, nullptr, nullptr, nullptr);
    // ---- FFN (bf16 weights; bf16 intermediate)
    gemm32_k<1, 0, 1><<<dim3(16, 98), 256, 0, stream>>>(X, W116 + (size_t)l * 262144, b1 + l * 1024, FF1B, 1024, 256);
    gemm32_k<0, 1, 0><<<dim3(4, 98), 256, 0, stream>>>(FF1B, W216 + (size_t)l * 262144, b2 + l * 256, TMP, 256, 1024);
    // ln2 fused with X hi/lo split + row-sq (feeds next layer's Gram/topk)
    ln_k<1><<<N_TOK, 256, 0, stream>>>(X, TMP, ln2g + l * 256, ln2b + l * 256, X, SQF, XH, XL);
  }
  // final LN + transpose to [1,C,H,W]
  ln_k<0><<<N_TOK, 256, 0, stream>>>(X, nullptr, ng, nb, TMP, nullptr, nullptr, nullptr);
  transpose_k<<<dim3(8, 98), 256, 0, stream>>>(TMP, (float*)d_out, N_TOK, 256);
}

// Round 22
// 586.285 us; speedup vs baseline: 2.2915x; 1.0005x over previous
//
#include <hip/hip_runtime.h>
#include <math.h>

#define N_TOK 3136
#define CD    256
#define NHD   8
#define DH    32
#define DFFD  1024
#define SCALE 0.17677669529663687f  /* 32^-0.5 */
#define LOG2E 1.4426950408889634f
#define QSC   (SCALE * LOG2E)

typedef __attribute__((ext_vector_type(8))) short short8v;
typedef __attribute__((ext_vector_type(4))) float f32x4;

// ---------------------------------------------------------------- utils
__device__ __forceinline__ unsigned long long sx64(unsigned long long v, int m) {
  unsigned lo = (unsigned)__shfl_xor((int)(unsigned)(v & 0xffffffffull), m, 64);
  unsigned hi = (unsigned)__shfl_xor((int)(unsigned)(v >> 32), m, 64);
  return ((unsigned long long)hi << 32) | lo;
}

__device__ __forceinline__ unsigned f2mono(float v) {
  unsigned b = __float_as_uint(v);
  return (b & 0x80000000u) ? ~b : (b | 0x80000000u);
}

// fp32 -> bf16 round-to-nearest-even
__device__ __forceinline__ short bfr(float f) {
  unsigned u = __float_as_uint(f);
  unsigned r = (u + 0x7fffu + ((u >> 16) & 1u)) >> 16;
  return (short)r;
}

__device__ __forceinline__ short8v cvt8(float4 a, float4 b) {
  short8v r;
  r[0] = bfr(a.x); r[1] = bfr(a.y); r[2] = bfr(a.z); r[3] = bfr(a.w);
  r[4] = bfr(b.x); r[5] = bfr(b.y); r[6] = bfr(b.z); r[7] = bfr(b.w);
  return r;
}

// ------------- all weights -> bf16 in one dispatch (contiguous arena)
__global__ __launch_bounds__(256) void cvtall_k(const float* __restrict__ Wq,
    const float* __restrict__ Wk, const float* __restrict__ Wv,
    const float* __restrict__ Wo, const float* __restrict__ W1,
    const float* __restrict__ W2, short* __restrict__ out) {
  const int NQ = 262144, NB = 1048576, TOT = 4 * 262144 + 2 * 1048576;
  for (int i = blockIdx.x * 256 + threadIdx.x; i < TOT; i += gridDim.x * 256) {
    float v;
    if (i < NQ) v = Wq[i];
    else if (i < 2 * NQ) v = Wk[i - NQ];
    else if (i < 3 * NQ) v = Wv[i - 2 * NQ];
    else if (i < 4 * NQ) v = Wo[i - 3 * NQ];
    else if (i < 4 * NQ + NB) v = W1[i - 4 * NQ];
    else v = W2[i - 4 * NQ - NB];
    out[i] = bfr(v);
  }
}

// ------------------------------------------------- transpose (32x32 tiles)
__global__ __launch_bounds__(256) void transpose_k(const float* __restrict__ in,
    float* __restrict__ out, int R, int C) {
  __shared__ float ls[32][33];
  const int c0 = blockIdx.x * 32, r0 = blockIdx.y * 32;
  const int tx = threadIdx.x & 31, ty = threadIdx.x >> 5;
#pragma unroll
  for (int j = 0; j < 4; ++j) {
    int r = ty + j * 8;
    ls[r][tx] = in[(size_t)(r0 + r) * C + c0 + tx];
  }
  __syncthreads();
#pragma unroll
  for (int j = 0; j < 4; ++j) {
    int cc = ty + j * 8;
    out[(size_t)(c0 + cc) * R + r0 + tx] = ls[tx][cc];
  }
}

// ------------- conv1 weight transpose -> bf16: WT[r][co][ci] = w[co][ci][r]
__global__ __launch_bounds__(256) void wtr_k(const float* __restrict__ w,
                                             short* __restrict__ wt) {
  const int e = blockIdx.x * 256 + threadIdx.x;   // < 9*128*256 = 294912
  const int r = e >> 15;
  const int rem = e & 32767;
  const int co = rem >> 8, ci = rem & 255;
  wt[e] = bfr(w[((size_t)co * 256 + ci) * 9 + r]);
}

// -------- conv1 as direct tap-GEMM: grid (2, 98, 3), z = ky; bf16 weights
__global__ __launch_bounds__(256) void conv1_k(const float* __restrict__ X,
    const short* __restrict__ WT, float* __restrict__ P) {
  __shared__ __align__(16) short As[32][40];
  __shared__ __align__(16) short Bs[64][40];
  const int n0 = blockIdx.x * 64;
  const int m0 = blockIdx.y * 32;
  const int ky = blockIdx.z;
  const int t = threadIdx.x;
  const int w = t >> 6, l = t & 63;
  const int g = l >> 4, c = l & 15;
  const int wr = w >> 1, wc = w & 1;
  const int sr = t >> 2, seg = t & 3;
  const int p = m0 + (sr & 31);
  const int y = p / 56, x = p - y * 56;
  const int yy = y + ky - 1;
  f32x4 acc[2] = {};
  for (int kx = 0; kx < 3; ++kx) {
    const int xx = x + kx - 1;
    const bool valid = (t < 128) && ((unsigned)yy < 56u) && ((unsigned)xx < 56u);
    const float* Ap = X + (size_t)(yy * 56 + xx) * CD + seg * 8;
    const short* Bp = WT + ((size_t)(ky * 3 + kx) * 128 + n0 + sr) * CD + seg * 8;
    for (int k0 = 0; k0 < CD; k0 += 32) {
      float4 a1 = make_float4(0.f, 0.f, 0.f, 0.f), a2 = a1;
      if (valid) { a1 = *(const float4*)(Ap + k0); a2 = *(const float4*)(Ap + k0 + 4); }
      const short8v bv = *(const short8v*)(Bp + k0);
      __syncthreads();
      if (t < 128) *(short8v*)&As[sr][seg * 8] = cvt8(a1, a2);
      *(short8v*)&Bs[sr][seg * 8] = bv;
      __syncthreads();
      const short8v af = *(const short8v*)&As[wr * 16 + c][g * 8];
      const short8v bf0 = *(const short8v*)&Bs[wc * 32 + c][g * 8];
      const short8v bf1 = *(const short8v*)&Bs[wc * 32 + 16 + c][g * 8];
      acc[0] = __builtin_amdgcn_mfma_f32_16x16x32_bf16(af, bf0, acc[0], 0, 0, 0);
      acc[1] = __builtin_amdgcn_mfma_f32_16x16x32_bf16(af, bf1, acc[1], 0, 0, 0);
    }
  }
#pragma unroll
  for (int ni = 0; ni < 2; ++ni) {
    const int col = n0 + wc * 32 + ni * 16 + c;
#pragma unroll
    for (int q = 0; q < 4; ++q) {
      const int m = m0 + wr * 16 + g * 4 + q;
      P[((size_t)ky * N_TOK + m) * 128 + col] = acc[ni][q];
    }
  }
}

// ----------------------- reduce conv1 tap partials + bias + relu -> T1
__global__ __launch_bounds__(256) void convred_k(const float* __restrict__ P,
    const float* __restrict__ b, float* __restrict__ T1) {
  const int e = blockIdx.x * 256 + threadIdx.x;   // < 3136*128
  const float v = P[e] + P[401408 + e] + P[802816 + e] + b[e & 127];
  T1[e] = fmaxf(v, 0.f);
}

// ---- 32x64-tile bf16 MFMA GEMM NT; A16: A already bf16; O16: bf16 out.
template <int RELU, int A16, int O16>
__global__ __launch_bounds__(256) void gemm32_k(const void* __restrict__ Av,
    const short* __restrict__ Bw, const float* __restrict__ bias,
    void* __restrict__ Cv, int N, int K) {
  __shared__ __align__(16) short As[32][40];
  __shared__ __align__(16) short Bs[64][40];
  const int n0 = blockIdx.x * 64;
  const int m0 = blockIdx.y * 32;
  const int t = threadIdx.x;
  const int w = t >> 6, l = t & 63;
  const int g = l >> 4, c = l & 15;
  const int wr = w >> 1, wc = w & 1;
  const int sr = t >> 2, seg = t & 3;
  const float* Apf = (const float*)Av + (size_t)(m0 + (sr & 31)) * K + seg * 8;
  const short* Aps = (const short*)Av + (size_t)(m0 + (sr & 31)) * K + seg * 8;
  const short* Bp = Bw + (size_t)(n0 + sr) * K + seg * 8;
  f32x4 acc[2] = {};
  for (int k0 = 0; k0 < K; k0 += 32) {
    short8v a8;
    if (A16) {
      if (t < 128) a8 = *(const short8v*)(Aps + k0);
    } else {
      float4 a1 = make_float4(0.f, 0.f, 0.f, 0.f), a2 = a1;
      if (t < 128) { a1 = *(const float4*)(Apf + k0); a2 = *(const float4*)(Apf + k0 + 4); }
      a8 = cvt8(a1, a2);
    }
    const short8v bv = *(const short8v*)(Bp + k0);
    __syncthreads();
    if (t < 128) *(short8v*)&As[sr][seg * 8] = a8;
    *(short8v*)&Bs[sr][seg * 8] = bv;
    __syncthreads();
    const short8v af = *(const short8v*)&As[wr * 16 + c][g * 8];
    const short8v bf0 = *(const short8v*)&Bs[wc * 32 + c][g * 8];
    const short8v bf1 = *(const short8v*)&Bs[wc * 32 + 16 + c][g * 8];
    acc[0] = __builtin_amdgcn_mfma_f32_16x16x32_bf16(af, bf0, acc[0], 0, 0, 0);
    acc[1] = __builtin_amdgcn_mfma_f32_16x16x32_bf16(af, bf1, acc[1], 0, 0, 0);
  }
#pragma unroll
  for (int ni = 0; ni < 2; ++ni) {
    const int col = n0 + wc * 32 + ni * 16 + c;
    const float bb = bias ? bias[col] : 0.f;
#pragma unroll
    for (int q = 0; q < 4; ++q) {
      const int m = m0 + wr * 16 + g * 4 + q;
      float v = acc[ni][q] + bb;
      if (RELU) v = fmaxf(v, 0.f);
      if (O16) ((short*)Cv)[(size_t)m * N + col] = bfr(v);
      else ((float*)Cv)[(size_t)m * N + col] = v;
    }
  }
}

// ---------------- fused Q/K/V projections, bf16 weights, bf16 outputs
__global__ __launch_bounds__(256) void proj32_k(const float* __restrict__ QKIN,
    const float* __restrict__ X, const short* __restrict__ Wq,
    const short* __restrict__ Wk, const short* __restrict__ Wv,
    const float* __restrict__ bq, const float* __restrict__ bk,
    const float* __restrict__ bv, short* __restrict__ QB,
    short* __restrict__ KB, short* __restrict__ VT) {
  __shared__ __align__(16) short As[32][40];
  __shared__ __align__(16) short Bs[64][40];
  const int sel = blockIdx.z;
  const int n0 = blockIdx.x * 64;
  const int m0 = blockIdx.y * 32;
  const float* A = (sel < 2) ? QKIN : X;
  const short* B = (sel == 0) ? Wq : (sel == 1) ? Wk : Wv;
  const float* bias = (sel == 0) ? bq : (sel == 1) ? bk : bv;
  const int t = threadIdx.x;
  const int w = t >> 6, l = t & 63;
  const int g = l >> 4, c = l & 15;
  const int wr = w >> 1, wc = w & 1;
  const int sr = t >> 2, seg = t & 3;
  const float* Ap = A + (size_t)(m0 + (sr & 31)) * CD + seg * 8;
  const short* Bp = B + (size_t)(n0 + sr) * CD + seg * 8;
  f32x4 acc[2] = {};
  for (int k0 = 0; k0 < CD; k0 += 32) {
    float4 a1 = make_float4(0.f, 0.f, 0.f, 0.f), a2 = a1;
    if (t < 128) { a1 = *(const float4*)(Ap + k0); a2 = *(const float4*)(Ap + k0 + 4); }
    const short8v bv8 = *(const short8v*)(Bp + k0);
    __syncthreads();
    if (t < 128) *(short8v*)&As[sr][seg * 8] = cvt8(a1, a2);
    *(short8v*)&Bs[sr][seg * 8] = bv8;
    __syncthreads();
    const short8v af = *(const short8v*)&As[wr * 16 + c][g * 8];
    const short8v bf0 = *(const short8v*)&Bs[wc * 32 + c][g * 8];
    const short8v bf1 = *(const short8v*)&Bs[wc * 32 + 16 + c][g * 8];
    acc[0] = __builtin_amdgcn_mfma_f32_16x16x32_bf16(af, bf0, acc[0], 0, 0, 0);
    acc[1] = __builtin_amdgcn_mfma_f32_16x16x32_bf16(af, bf1, acc[1], 0, 0, 0);
  }
#pragma unroll
  for (int ni = 0; ni < 2; ++ni) {
    const int col = n0 + wc * 32 + ni * 16 + c;
    const float bb = bias[col];
    if (sel == 2) {
      const int mb = m0 + wr * 16 + g * 4;
      const int pidx = (mb & ~31) + ((mb >> 4) & 1) * 4 + ((mb >> 2) & 3) * 8;
      uint2 pk;
      const float v0 = acc[ni][0] + bb, v1 = acc[ni][1] + bb;
      const float v2 = acc[ni][2] + bb, v3 = acc[ni][3] + bb;
      pk.x = (unsigned)(unsigned short)bfr(v0) | ((unsigned)(unsigned short)bfr(v1) << 16);
      pk.y = (unsigned)(unsigned short)bfr(v2) | ((unsigned)(unsigned short)bfr(v3) << 16);
      *(uint2*)&VT[(size_t)col * N_TOK + pidx] = pk;
    } else {
      short* Ct = (sel == 0) ? QB : KB;
      const float qs = (sel == 0) ? QSC : 1.f;
      const int hh = col >> 5, dd = col & 31;
#pragma unroll
      for (int q = 0; q < 4; ++q) {
        const int m = m0 + wr * 16 + g * 4 + q;
        Ct[((size_t)hh * N_TOK + m) * 32 + dd] = bfr((acc[ni][q] + bb) * qs);
      }
    }
  }
}

// --------------- X -> bf16 hi/lo planes + row ||x||^2 (prologue only)
__global__ __launch_bounds__(256) void xsplit_k(const float* __restrict__ X,
    short* __restrict__ XH, short* __restrict__ XL, float* __restrict__ sq) {
  __shared__ float red[4];
  const int i = blockIdx.x, t = threadIdx.x;
  const size_t e = (size_t)i * CD + t;
  const float v = X[e];
  const unsigned ui = __float_as_uint(v);
  XH[e] = (short)(ui >> 16);
  const float hf = __uint_as_float(ui & 0xffff0000u);
  XL[e] = (short)(__float_as_uint(v - hf) >> 16);
  float s = v * v;
#pragma unroll
  for (int m = 1; m < 64; m <<= 1) s += __shfl_xor(s, m, 64);
  if ((t & 63) == 0) red[t >> 6] = s;
  __syncthreads();
  if (t == 0) sq[i] = red[0] + red[1] + red[2] + red[3];
}

// ---- Gram, key-fused: mirror via LDS transpose (coalesced stores).
// Keys bit-identical to scattered-write version: v is bit-symmetric (same
// k-order, commutative products) and mirror formula (sq[col]-2v)+sq[row].
__global__ __launch_bounds__(256) void gemm_syr4_k(const short* __restrict__ XH,
    const short* __restrict__ XL, const float* __restrict__ SQ,
    unsigned* __restrict__ Ck) {
  __shared__ __align__(16) short sbuf[4][64][40];   // staging; reused as tb
  short (*AsH)[40] = sbuf[0];
  short (*AsL)[40] = sbuf[1];
  short (*BsH)[40] = sbuf[2];
  short (*BsL)[40] = sbuf[3];
  int bid = blockIdx.x;
  int bi = (int)((sqrtf(8.f * (float)bid + 1.f) - 1.f) * 0.5f);
  while ((bi + 1) * (bi + 2) / 2 <= bid) ++bi;
  while (bi * (bi + 1) / 2 > bid) --bi;
  const int bj = bid - bi * (bi + 1) / 2;
  const int m0 = bi * 64, n0 = bj * 64;
  const int t = threadIdx.x;
  const int w = t >> 6, l = t & 63;
  const int g = l >> 4, c = l & 15;
  const int wr = w >> 1, wc = w & 1;
  const int sr = t >> 2, seg = t & 3;
  const size_t arow = (size_t)(m0 + sr) * CD + seg * 8;
  const size_t brow = (size_t)(n0 + sr) * CD + seg * 8;
  f32x4 acc[2][2] = {};
  for (int k0 = 0; k0 < CD; k0 += 32) {
    const short8v ah = *(const short8v*)&XH[arow + k0];
    const short8v al = *(const short8v*)&XL[arow + k0];
    const short8v bh = *(const short8v*)&XH[brow + k0];
    const short8v bl = *(const short8v*)&XL[brow + k0];
    __syncthreads();
    *(short8v*)&AsH[sr][seg * 8] = ah;
    *(short8v*)&AsL[sr][seg * 8] = al;
    *(short8v*)&BsH[sr][seg * 8] = bh;
    *(short8v*)&BsL[sr][seg * 8] = bl;
    __syncthreads();
    short8v afH[2], afL[2], bfH[2], bfL[2];
#pragma unroll
    for (int mi = 0; mi < 2; ++mi) {
      afH[mi] = *(const short8v*)&AsH[wr * 32 + mi * 16 + c][g * 8];
      afL[mi] = *(const short8v*)&AsL[wr * 32 + mi * 16 + c][g * 8];
    }
#pragma unroll
    for (int ni = 0; ni < 2; ++ni) {
      bfH[ni] = *(const short8v*)&BsH[wc * 32 + ni * 16 + c][g * 8];
      bfL[ni] = *(const short8v*)&BsL[wc * 32 + ni * 16 + c][g * 8];
    }
#pragma unroll
    for (int mi = 0; mi < 2; ++mi)
#pragma unroll
      for (int ni = 0; ni < 2; ++ni) {
        acc[mi][ni] = __builtin_amdgcn_mfma_f32_16x16x32_bf16(afH[mi], bfH[ni], acc[mi][ni], 0, 0, 0);
        acc[mi][ni] = __builtin_amdgcn_mfma_f32_16x16x32_bf16(afH[mi], bfL[ni], acc[mi][ni], 0, 0, 0);
        acc[mi][ni] = __builtin_amdgcn_mfma_f32_16x16x32_bf16(afL[mi], bfH[ni], acc[mi][ni], 0, 0, 0);
      }
  }
  // ---- epilogue: direct (coalesced) stores + raw tile transposed to LDS
  __syncthreads();                                  // all staging reads done
  float (*tb)[65] = (float(*)[65])&sbuf[0][0][0];   // 64*65*4 = 16640B < 20480B
#pragma unroll
  for (int mi = 0; mi < 2; ++mi)
#pragma unroll
    for (int ni = 0; ni < 2; ++ni) {
      const int cl = wc * 32 + ni * 16 + c;         // local col
      const float sqc = SQ[n0 + cl];
#pragma unroll
      for (int q = 0; q < 4; ++q) {
        const int ml = wr * 32 + mi * 16 + g * 4 + q;  // local row
        const float v = acc[mi][ni][q];
        Ck[(size_t)(m0 + ml) * N_TOK + n0 + cl] = f2mono((SQ[m0 + ml] - 2.f * v) + sqc);
        tb[cl][ml] = v;
      }
    }
  __syncthreads();
  // ---- mirror pass: fully coalesced (64 consecutive cols per wave)
  const int mr = t >> 6;          // wave id -> row offset within group of 4
  const int mc = t & 63;          // lane -> col
#pragma unroll
  for (int rr = 0; rr < 16; ++rr) {
    const int row = rr * 4 + mr;                    // mirror row (tile col)
    const float v = tb[row][mc];
    Ck[(size_t)(n0 + row) * N_TOK + m0 + mc] =
        f2mono((SQ[n0 + row] - 2.f * v) + SQ[m0 + mc]);
  }
}

// ------------------- conv2 (8ch) -> writes gpT [8][N_TOK] * log2e directly
__global__ __launch_bounds__(256) void conv2_k(const float* __restrict__ t1,
    const float* __restrict__ w, const float* __restrict__ b,
    float* __restrict__ gpT) {
  __shared__ float ws3[9 * 8 * 132];
  const int t = threadIdx.x;
  for (int e = t; e < 9216; e += 256) {
    int r = e >> 10;
    int rem = e & 1023;
    int co = rem >> 7;
    int ci = rem & 127;
    ws3[(r * 8 + co) * 132 + ci] = w[((size_t)co * 128 + ci) * 9 + r];
  }
  __syncthreads();
  const int pix = blockIdx.x * 32 + (t >> 3);
  const int co = t & 7;
  const int y = pix / 56, x = pix - y * 56;
  float acc = b[co];
  for (int ky = 0; ky < 3; ++ky) {
    int yy = y + ky - 1;
    if (yy < 0 || yy >= 56) continue;
    for (int kx = 0; kx < 3; ++kx) {
      int xx = x + kx - 1;
      if (xx < 0 || xx >= 56) continue;
      const float4* tp = (const float4*)&t1[(size_t)(yy * 56 + xx) * 128];
      const float* wp = &ws3[((ky * 3 + kx) * 8 + co) * 132];
#pragma unroll
      for (int c4 = 0; c4 < 32; ++c4) {
        const float4 tv = tp[c4];
        const float4 wv = *(const float4*)&wp[c4 * 4];
        acc += tv.x * wv.x + tv.y * wv.y + tv.z * wv.z + tv.w * wv.w;
      }
    }
  }
  gpT[co * N_TOK + pix] = LOG2E / (1.f + expf(-acc));
}

// ---- top-16 NN + in-degree, v7: one wave/row, per-lane TOP-4 cache over
// precomputed mono keys; rare refill. Bit-exact lex top_k.
__global__ __launch_bounds__(64) void topk_k(const unsigned* __restrict__ Gk,
    int* __restrict__ near) {
  const int i = blockIdx.x;
  const int t = threadIdx.x;            // lane 0..63
  const unsigned* __restrict__ Krow = Gk + (size_t)i * N_TOK;
  unsigned cv0 = 0xffffffffu, cv1 = 0xffffffffu, cv2 = 0xffffffffu, cv3 = 0xffffffffu;
  int ce0 = 0, ce1 = 0, ce2 = 0, ce3 = 0;
#pragma unroll
  for (int e = 0; e < 49; ++e) {
    const unsigned v = Krow[t + (e << 6)];    // 49*64 = 3136 exactly
    const bool i0 = v < cv0, i1 = v < cv1, i2 = v < cv2, i3 = v < cv3;
    cv3 = i2 ? cv2 : (i3 ? v : cv3);  ce3 = i2 ? ce2 : (i3 ? e : ce3);
    cv2 = i1 ? cv1 : (i2 ? v : cv2);  ce2 = i1 ? ce1 : (i2 ? e : ce2);
    cv1 = i0 ? cv0 : (i1 ? v : cv1);  ce1 = i0 ? ce0 : (i1 ? e : ce1);
    cv0 = i0 ? v : cv0;               ce0 = i0 ? e : ce0;
  }
  unsigned long long killed = 0ull;
#pragma unroll 1
  for (int r = 0; r < 16; ++r) {
    const unsigned long long mine =
        ((unsigned long long)cv0 << 32) | (unsigned)(t + (ce0 << 6));
    unsigned long long best = mine;
#pragma unroll
    for (int m = 1; m < 64; m <<= 1) {
      const unsigned long long o = sx64(best, m);
      best = (o < best) ? o : best;
    }
    if (t == 0) atomicAdd(&near[(unsigned)(best & 0xffffffffu)], 1);
    if (mine == best && r < 15) {
      killed |= 1ull << ce0;
      cv0 = cv1; ce0 = ce1;
      cv1 = cv2; ce1 = ce2;
      cv2 = cv3; ce2 = ce3;
      cv3 = 0xffffffffu; ce3 = 0;
      if (cv0 == 0xffffffffu) {
#pragma unroll
        for (int e = 0; e < 49; ++e) {
          unsigned v = Krow[t + (e << 6)];
          v = (((killed >> e) & 1ull) != 0ull) ? 0xffffffffu : v;
          const bool i0 = v < cv0, i1 = v < cv1, i2 = v < cv2, i3 = v < cv3;
          cv3 = i2 ? cv2 : (i3 ? v : cv3);  ce3 = i2 ? ce2 : (i3 ? e : ce3);
          cv2 = i1 ? cv1 : (i2 ? v : cv2);  ce2 = i1 ? ce1 : (i2 ? e : ce2);
          cv1 = i0 ? cv0 : (i1 ? v : cv1);  ce1 = i0 ? ce0 : (i1 ? e : ce1);
          cv0 = i0 ? v : cv0;               ce0 = i0 ? e : ce0;
        }
      }
    }
  }
}

// ------------- fused max(near) + qk_in = x + emb[ni(near)] (one row/block)
__global__ __launch_bounds__(256) void nearqk_k(const float* __restrict__ x,
    const int* __restrict__ near, const float* __restrict__ emb,
    float* __restrict__ qkin) {
  __shared__ int sm[4];
  const int i = blockIdx.x, t = threadIdx.x;
  int m = 0;
  for (int j = t; j < N_TOK; j += 256) m = max(m, near[j]);
#pragma unroll
  for (int s = 1; s < 64; s <<= 1) m = max(m, __shfl_xor(m, s, 64));
  if ((t & 63) == 0) sm[t >> 6] = m;
  __syncthreads();
  const int mv = max(max(sm[0], sm[1]), max(sm[2], sm[3]));
  const int ni = (int)((float)near[i] / (float)mv * 9.0f);
  qkin[(size_t)i * CD + t] = x[(size_t)i * CD + t] + emb[ni * CD + t];
}

// ---- flash attention v8: 8 waves/block (512 thr), 64 queries/wave,
// j-eighths per wave; per-head Q/K layout; in-block 8-way combine.
__global__ __launch_bounds__(512) void attn_v8_k(const short* __restrict__ Qb,
    const short* __restrict__ Kb, const short* __restrict__ Vt,
    const float* __restrict__ gpT, float* __restrict__ O1) {
  __shared__ float o_l[8][64][36];
  __shared__ float ml_l[8][64][2];
  const int h = blockIdx.y;
  const int qb = blockIdx.x * 64;
  const int t = threadIdx.x;
  const int w = t >> 6, l = t & 63;
  const int g = l >> 4, c = l & 15;
  const size_t hR = (size_t)h * N_TOK;      // per-head row base (Q/K/gpT)
  const size_t hoff = (size_t)h * DH;       // VT d-row base
  short8v qf[4];
  float gpi[4];
#pragma unroll
  for (int gr = 0; gr < 4; ++gr) {
    qf[gr] = *(const short8v*)&Qb[(hR + qb + gr * 16 + c) * 32 + g * 8];
    gpi[gr] = gpT[hR + qb + gr * 16 + c];
  }
  const int jt0 = w ? (7 + 6 * (w - 1)) : 0;   // {7,6,6,6,6,6,6,6} = 49
  const int jt1 = jt0 + (w ? 6 : 7);
  float mr[4] = {-INFINITY, -INFINITY, -INFINITY, -INFINITY};
  float lp[4] = {0.f, 0.f, 0.f, 0.f};
  f32x4 oa[4][2] = {};
  const f32x4 zz = {0.f, 0.f, 0.f, 0.f};

#pragma unroll 1
  for (int jt = jt0; jt < jt1; ++jt) {
    const int j0 = jt * 64;
    short8v kf[4], vf[4];
    float4 gj[4];
#pragma unroll
    for (int sub = 0; sub < 4; ++sub)
      kf[sub] = *(const short8v*)&Kb[(hR + j0 + sub * 16 + c) * 32 + g * 8];
#pragma unroll
    for (int ch = 0; ch < 2; ++ch)
#pragma unroll
      for (int ds = 0; ds < 2; ++ds)
        vf[ch * 2 + ds] = *(const short8v*)&Vt[(hoff + ds * 16 + c) * (size_t)N_TOK + j0 + ch * 32 + g * 8];
#pragma unroll
    for (int sub = 0; sub < 4; ++sub)
      gj[sub] = *(const float4*)&gpT[hR + j0 + sub * 16 + g * 4];
#pragma unroll
    for (int gr = 0; gr < 4; ++gr) {
      f32x4 sacc[4];
#pragma unroll
      for (int sub = 0; sub < 4; ++sub)
        sacc[sub] = __builtin_amdgcn_mfma_f32_16x16x32_bf16(kf[sub], qf[gr], zz, 0, 0, 0);
      float sv[16];
#pragma unroll
      for (int sub = 0; sub < 4; ++sub) {
        sv[sub * 4 + 0] = sacc[sub][0] + fabsf(gpi[gr] - gj[sub].x);
        sv[sub * 4 + 1] = sacc[sub][1] + fabsf(gpi[gr] - gj[sub].y);
        sv[sub * 4 + 2] = sacc[sub][2] + fabsf(gpi[gr] - gj[sub].z);
        sv[sub * 4 + 3] = sacc[sub][3] + fabsf(gpi[gr] - gj[sub].w);
      }
      float a0 = fmaxf(sv[0], sv[1]),  a1 = fmaxf(sv[2], sv[3]);
      float a2 = fmaxf(sv[4], sv[5]),  a3 = fmaxf(sv[6], sv[7]);
      float a4 = fmaxf(sv[8], sv[9]),  a5 = fmaxf(sv[10], sv[11]);
      float a6 = fmaxf(sv[12], sv[13]), a7 = fmaxf(sv[14], sv[15]);
      const float mx = fmaxf(fmaxf(fmaxf(a0, a1), fmaxf(a2, a3)),
                             fmaxf(fmaxf(a4, a5), fmaxf(a6, a7)));
      if (!__all(mx - mr[gr] <= 11.f)) {
        float mn = mx;
        mn = fmaxf(mn, __shfl_xor(mn, 16, 64));
        mn = fmaxf(mn, __shfl_xor(mn, 32, 64));
        mn = fmaxf(mn, mr[gr]);
        const float sc = __builtin_amdgcn_exp2f(mr[gr] - mn);
        oa[gr][0][0] *= sc; oa[gr][0][1] *= sc; oa[gr][0][2] *= sc; oa[gr][0][3] *= sc;
        oa[gr][1][0] *= sc; oa[gr][1][1] *= sc; oa[gr][1][2] *= sc; oa[gr][1][3] *= sc;
        lp[gr] *= sc;
        mr[gr] = mn;
      }
      float p[16];
#pragma unroll
      for (int e = 0; e < 16; ++e) p[e] = __builtin_amdgcn_exp2f(sv[e] - mr[gr]);
      const float ps0 = (p[0] + p[1]) + (p[2] + p[3]);
      const float ps1 = (p[4] + p[5]) + (p[6] + p[7]);
      const float ps2 = (p[8] + p[9]) + (p[10] + p[11]);
      const float ps3 = (p[12] + p[13]) + (p[14] + p[15]);
      lp[gr] += (ps0 + ps1) + (ps2 + ps3);
      union { unsigned u[4]; short8v s; } pf0, pf1;
#pragma unroll
      for (int sub = 0; sub < 2; ++sub) {
        pf0.u[2 * sub + 0] = __builtin_amdgcn_perm(__float_as_uint(p[4 * sub + 1]),
                                                   __float_as_uint(p[4 * sub + 0]), 0x07060302u);
        pf0.u[2 * sub + 1] = __builtin_amdgcn_perm(__float_as_uint(p[4 * sub + 3]),
                                                   __float_as_uint(p[4 * sub + 2]), 0x07060302u);
        pf1.u[2 * sub + 0] = __builtin_amdgcn_perm(__float_as_uint(p[8 + 4 * sub + 1]),
                                                   __float_as_uint(p[8 + 4 * sub + 0]), 0x07060302u);
        pf1.u[2 * sub + 1] = __builtin_amdgcn_perm(__float_as_uint(p[8 + 4 * sub + 3]),
                                                   __float_as_uint(p[8 + 4 * sub + 2]), 0x07060302u);
      }
      oa[gr][0] = __builtin_amdgcn_mfma_f32_16x16x32_bf16(vf[0], pf0.s, oa[gr][0], 0, 0, 0);
      oa[gr][1] = __builtin_amdgcn_mfma_f32_16x16x32_bf16(vf[1], pf0.s, oa[gr][1], 0, 0, 0);
      oa[gr][0] = __builtin_amdgcn_mfma_f32_16x16x32_bf16(vf[2], pf1.s, oa[gr][0], 0, 0, 0);
      oa[gr][1] = __builtin_amdgcn_mfma_f32_16x16x32_bf16(vf[3], pf1.s, oa[gr][1], 0, 0, 0);
    }
  }
#pragma unroll
  for (int gr = 0; gr < 4; ++gr) {
    lp[gr] += __shfl_xor(lp[gr], 16, 64);
    lp[gr] += __shfl_xor(lp[gr], 32, 64);
#pragma unroll
    for (int ds = 0; ds < 2; ++ds)
      *(f32x4*)&o_l[w][gr * 16 + c][ds * 16 + g * 4] = oa[gr][ds];
    if (g == 0) {
      ml_l[w][gr * 16 + c][0] = mr[gr];
      ml_l[w][gr * 16 + c][1] = lp[gr];
    }
  }
  __syncthreads();
  // ---- combine 8 partials: thread -> (q = t>>3, d0 = (t&7)*4)
  const int q = t >> 3, d0 = (t & 7) * 4;
  float M = -INFINITY;
#pragma unroll
  for (int sp = 0; sp < 8; ++sp) M = fmaxf(M, ml_l[sp][q][0]);
  float den = 0.f;
  f32x4 num = {0.f, 0.f, 0.f, 0.f};
#pragma unroll
  for (int sp = 0; sp < 8; ++sp) {
    const float wg = __builtin_amdgcn_exp2f(ml_l[sp][q][0] - M);
    den += wg * ml_l[sp][q][1];
    const f32x4 ov = *(const f32x4*)&o_l[sp][q][d0];
    num[0] += wg * ov[0]; num[1] += wg * ov[1];
    num[2] += wg * ov[2]; num[3] += wg * ov[3];
  }
  const float inv = 1.f / den;
  f32x4 r = {num[0] * inv, num[1] * inv, num[2] * inv, num[3] * inv};
  *(f32x4*)&O1[(size_t)(qb + q) * CD + hoff + d0] = r;
}

// ------ LayerNorm (+residual); SPLIT=1 also emits XH/XL planes + row-sq
template <int SPLIT>
__global__ __launch_bounds__(256) void ln_k(const float* __restrict__ xin,
    const float* __restrict__ add, const float* __restrict__ g,
    const float* __restrict__ b, float* __restrict__ xout,
    float* __restrict__ sqout, short* __restrict__ XH, short* __restrict__ XL) {
  __shared__ float red1[4];
  __shared__ float red2[4];
  const int i = blockIdx.x, t = threadIdx.x;
  const size_t e = (size_t)i * CD + t;
  float v = xin[e];
  if (add) v += add[e];
  float s = v;
#pragma unroll
  for (int m = 1; m < 64; m <<= 1) s += __shfl_xor(s, m, 64);
  if ((t & 63) == 0) red1[t >> 6] = s;
  __syncthreads();
  const float mean = (red1[0] + red1[1] + red1[2] + red1[3]) * (1.f / 256.f);
  const float d = v - mean;
  float s2 = d * d;
#pragma unroll
  for (int m = 1; m < 64; m <<= 1) s2 += __shfl_xor(s2, m, 64);
  if ((t & 63) == 0) red2[t >> 6] = s2;
  __syncthreads();
  const float var = (red2[0] + red2[1] + red2[2] + red2[3]) * (1.f / 256.f);
  const float xo = d * rsqrtf(var + 1e-5f) * g[t] + b[t];
  xout[e] = xo;
  if (SPLIT) {
    const unsigned ui = __float_as_uint(xo);
    XH[e] = (short)(ui >> 16);
    const float hf = __uint_as_float(ui & 0xffff0000u);
    XL[e] = (short)(__float_as_uint(xo - hf) >> 16);
    float s3 = xo * xo;
#pragma unroll
    for (int m = 1; m < 64; m <<= 1) s3 += __shfl_xor(s3, m, 64);
    __syncthreads();
    if ((t & 63) == 0) red1[t >> 6] = s3;
    __syncthreads();
    if (t == 0) sqout[i] = red1[0] + red1[1] + red1[2] + red1[3];
  }
}

// ---------------------------------------------------------------- launch
extern "C" void kernel_launch(void* const* d_in, const int* in_sizes, int n_in,
                              void* d_out, int out_size, void* d_ws, size_t ws_size,
                              hipStream_t stream) {
  const float* src  = (const float*)d_in[0];
  const float* c1w  = (const float*)d_in[1];
  const float* c1b  = (const float*)d_in[2];
  const float* c2w  = (const float*)d_in[3];
  const float* c2b  = (const float*)d_in[4];
  const float* nemb = (const float*)d_in[5];
  const float* Wq   = (const float*)d_in[6];
  const float* bq   = (const float*)d_in[7];
  const float* Wk   = (const float*)d_in[8];
  const float* bk   = (const float*)d_in[9];
  const float* Wv   = (const float*)d_in[10];
  const float* bv   = (const float*)d_in[11];
  const float* Wo   = (const float*)d_in[12];
  const float* bo   = (const float*)d_in[13];
  const float* W1   = (const float*)d_in[14];
  const float* b1   = (const float*)d_in[15];
  const float* W2   = (const float*)d_in[16];
  const float* b2   = (const float*)d_in[17];
  const float* ln1g = (const float*)d_in[18];
  const float* ln1b = (const float*)d_in[19];
  const float* ln2g = (const float*)d_in[20];
  const float* ln2b = (const float*)d_in[21];
  const float* ng   = (const float*)d_in[22];
  const float* nb   = (const float*)d_in[23];

  float* ws = (float*)d_ws;
  const size_t NC = (size_t)N_TOK * CD;          // 802816
  float* X    = ws;
  float* QKIN = X + NC;
  float* O1   = QKIN + NC;
  float* TMP  = O1 + NC;
  float* FF1  = TMP + NC;                        // bf16 FF1 lives here (short*)
  float* G    = FF1 + (size_t)N_TOK * DFFD;      // 3136*3136 (keys / conv1 partials)
  float* T1   = G + (size_t)N_TOK * N_TOK;       // 3136*128
  float* GPT  = T1 + (size_t)N_TOK * 128;        // 8*3136
  float* SQF  = GPT + (size_t)N_TOK * NHD;       // 3136
  short* QB16 = (short*)(SQF + N_TOK);
  short* KB16 = QB16 + NC;
  short* VT16 = KB16 + NC;
  short* XH   = VT16 + NC;                       // bf16 hi plane
  short* XL   = XH + NC;                         // bf16 lo plane
  short* WTC  = XL + NC;                         // conv1 wt bf16: 294912
  short* WARN = WTC + 294912;                    // bf16 weight arena (contiguous)
  short* WQ16 = WARN;                            // 4*65536
  short* WK16 = WQ16 + 262144;
  short* WV16 = WK16 + 262144;
  short* WO16 = WV16 + 262144;
  short* W116 = WO16 + 262144;                   // 4*262144
  short* W216 = W116 + 1048576;
  int*   NEAR = (int*)(W216 + 1048576);          // 4 * 3136 ints
  short* FF1B = (short*)FF1;                     // bf16 FF1 view

  // prologue: all weights -> bf16 in one dispatch
  cvtall_k<<<4096, 256, 0, stream>>>(Wq, Wk, Wv, Wo, W1, W2, WARN);

  // tokens + conv positional encoder (direct conv, no im2col)
  transpose_k<<<dim3(98, 8), 256, 0, stream>>>(src, X, 256, N_TOK);
  wtr_k<<<1152, 256, 0, stream>>>(c1w, WTC);
  conv1_k<<<dim3(2, 98, 3), 256, 0, stream>>>(X, WTC, G);
  convred_k<<<1568, 256, 0, stream>>>(G, c1b, T1);
  conv2_k<<<98, 256, 0, stream>>>(T1, c2w, c2b, GPT);
  xsplit_k<<<N_TOK, 256, 0, stream>>>(X, XH, XL, SQF);
  (void)hipMemsetAsync(NEAR, 0, 4 * N_TOK * sizeof(int), stream);

  for (int l = 0; l < 4; ++l) {
    int* NEAR_l = NEAR + l * N_TOK;
    // ---- kNN graph -> near counts (key-fused Gram, coalesced mirror)
    gemm_syr4_k<<<1225, 256, 0, stream>>>(XH, XL, SQF, (unsigned*)G);
    topk_k<<<N_TOK, 64, 0, stream>>>((const unsigned*)G, NEAR_l);
    nearqk_k<<<N_TOK, 256, 0, stream>>>(X, NEAR_l, nemb, QKIN);
    // ---- fused Q/K/V projections (bf16 weights)
    proj32_k<<<dim3(4, 98, 3), 256, 0, stream>>>(QKIN, X,
        WQ16 + (size_t)l * 65536, WK16 + (size_t)l * 65536, WV16 + (size_t)l * 65536,
        bq + l * 256, bk + l * 256, bv + l * 256, QB16, KB16, VT16);
    // ---- attention (8 waves/block, j-eighths, in-block combine)
    attn_v8_k<<<dim3(49, 8), 512, 0, stream>>>(QB16, KB16, VT16, GPT, O1);
    gemm32_k<0, 0, 0><<<dim3(4, 98), 256, 0, stream>>>(O1, WO16 + (size_t)l * 65536, bo + l * 256, TMP, 256, 256);
    ln_k<0><<<N_TOK, 256, 0, stream>>>(X, TMP, ln1g + l * 256, ln1b + l * 256, X, nullptr, nullptr, nullptr);
    // ---- FFN (bf16 weights; bf16 intermediate)
    gemm32_k<1, 0, 1><<<dim3(16, 98), 256, 0, stream>>>(X, W116 + (size_t)l * 262144, b1 + l * 1024, FF1B, 1024, 256);
    gemm32_k<0, 1, 0><<<dim3(4, 98), 256, 0, stream>>>(FF1B, W216 + (size_t)l * 262144, b2 + l * 256, TMP, 256, 1024);
    // ln2 fused with X hi/lo split + row-sq (feeds next layer's Gram/topk)
    ln_k<1><<<N_TOK, 256, 0, stream>>>(X, TMP, ln2g + l * 256, ln2b + l * 256, X, SQF, XH, XL);
  }
  // final LN + transpose to [1,C,H,W]
  ln_k<0><<<N_TOK, 256, 0, stream>>>(X, nullptr, ng, nb, TMP, nullptr, nullptr, nullptr);
  transpose_k<<<dim3(8, 98), 256, 0, stream>>>(TMP, (float*)d_out, N_TOK, 256);
}